// Round 4
// baseline (1000.004 us; speedup 1.0000x reference)
//
#include <hip/hip_runtime.h>

#define N_NODES   100000
#define N_EDGES   3200000
#define N_GRAPHS  1024
#define HID       64

#define SCAN_B    256
#define NUM_SCAN_BLOCKS ((N_NODES + SCAN_B - 1) / SCAN_B)   // 391

// ---------------- CSR build ----------------

__global__ void k_hist(const int* __restrict__ dst, int* __restrict__ deg) {
    int i = blockIdx.x * blockDim.x + threadIdx.x;
    int stride = gridDim.x * blockDim.x;
    for (; i < N_EDGES; i += stride) atomicAdd(&deg[dst[i]], 1);
}

__global__ void k_scanA(const int* __restrict__ deg, int* __restrict__ rp,
                        int* __restrict__ bsum) {
    __shared__ int s[SCAN_B];
    int i = blockIdx.x * SCAN_B + threadIdx.x;
    int v = (i < N_NODES) ? deg[i] : 0;
    s[threadIdx.x] = v;
    __syncthreads();
    for (int off = 1; off < SCAN_B; off <<= 1) {
        int t = (threadIdx.x >= off) ? s[threadIdx.x - off] : 0;
        __syncthreads();
        s[threadIdx.x] += t;
        __syncthreads();
    }
    int incl = s[threadIdx.x];
    if (i < N_NODES) rp[i] = incl - v;                 // exclusive within block
    if (threadIdx.x == SCAN_B - 1) bsum[blockIdx.x] = incl;
}

__global__ void k_scanB(int* __restrict__ bsum) {
    __shared__ int s[512];
    int v = (threadIdx.x < NUM_SCAN_BLOCKS) ? bsum[threadIdx.x] : 0;
    s[threadIdx.x] = v;
    __syncthreads();
    for (int off = 1; off < 512; off <<= 1) {
        int t = (threadIdx.x >= off) ? s[threadIdx.x - off] : 0;
        __syncthreads();
        s[threadIdx.x] += t;
        __syncthreads();
    }
    if (threadIdx.x < NUM_SCAN_BLOCKS) bsum[threadIdx.x] = s[threadIdx.x] - v; // exclusive
}

__global__ void k_scanC(int* __restrict__ rp, const int* __restrict__ bsum,
                        int* __restrict__ cursor) {
    int i = blockIdx.x * blockDim.x + threadIdx.x;
    if (i < N_NODES) {
        int v = rp[i] + bsum[i / SCAN_B];
        rp[i] = v;
        cursor[i] = v;
    }
    if (i == 0) rp[N_NODES] = N_EDGES;
}

__global__ void k_fill(const int* __restrict__ src, const int* __restrict__ dst,
                       int* __restrict__ cursor, int* __restrict__ srcs) {
    int i = blockIdx.x * blockDim.x + threadIdx.x;
    int stride = gridDim.x * blockDim.x;
    for (; i < N_EDGES; i += stride) {
        int d = dst[i];
        int pos = atomicAdd(&cursor[d], 1);
        srcs[pos] = src[i];
    }
}

// ---------------- pad x[N][5] -> x8[N][8] (aligned rows for the gather) ----

__global__ void k_pad(const float* __restrict__ x, float* __restrict__ x8) {
    int i = blockIdx.x * blockDim.x + threadIdx.x;
    int stride = gridDim.x * blockDim.x;
    for (; i < N_NODES * 8; i += stride) {
        int n = i >> 3, j = i & 7;
        x8[i] = (j < 5) ? x[n * 5 + j] : 0.f;
    }
}

// ---------------- Layer 1: agg(x) + MLP1 -> h1 ----------------
// one wave (64 lanes) per node; lane j owns feature j

__global__ void __launch_bounds__(512) k_layer1(
    const float* __restrict__ x8, const int* __restrict__ rp,
    const int* __restrict__ srcs,
    const float* __restrict__ W1a, const float* __restrict__ b1a,
    const float* __restrict__ W1b, const float* __restrict__ b1b,
    float* __restrict__ h1) {
    __shared__ float sWb[HID * HID];
    __shared__ float sWa[5 * HID];
    __shared__ float sba[HID], sbb[HID];
    for (int i = threadIdx.x; i < HID * HID; i += 512) sWb[i] = W1b[i];
    for (int i = threadIdx.x; i < 5 * HID; i += 512) sWa[i] = W1a[i];
    if (threadIdx.x < HID) {
        sba[threadIdx.x] = b1a[threadIdx.x];
        sbb[threadIdx.x] = b1b[threadIdx.x];
    }
    __syncthreads();

    int wave = (blockIdx.x * 512 + threadIdx.x) >> 6;
    int lane = threadIdx.x & 63;
    if (wave >= N_NODES) return;
    int n = wave;
    int e0 = rp[n], e1 = rp[n + 1];

    float a0 = 0.f, a1 = 0.f, a2 = 0.f, a3 = 0.f, a4 = 0.f;
    for (int e = e0 + lane; e < e1; e += 64) {
        const float* xs = x8 + (size_t)srcs[e] * 8;
        const float4 v = *reinterpret_cast<const float4*>(xs);   // 16B aligned
        float v4 = xs[4];
        a0 += v.x; a1 += v.y; a2 += v.z; a3 += v.w; a4 += v4;
    }
#pragma unroll
    for (int m = 1; m < 64; m <<= 1) {
        a0 += __shfl_xor(a0, m, 64);
        a1 += __shfl_xor(a1, m, 64);
        a2 += __shfl_xor(a2, m, 64);
        a3 += __shfl_xor(a3, m, 64);
        a4 += __shfl_xor(a4, m, 64);
    }
    const float* xn = x8 + (size_t)n * 8;
    float z0 = xn[0] + a0, z1 = xn[1] + a1, z2 = xn[2] + a2,
          z3 = xn[3] + a3, z4 = xn[4] + a4;

    int j = lane;
    float h = sba[j] + z0 * sWa[0 * HID + j] + z1 * sWa[1 * HID + j] +
              z2 * sWa[2 * HID + j] + z3 * sWa[3 * HID + j] + z4 * sWa[4 * HID + j];
    h = fmaxf(h, 0.f);

    float o = sbb[j];
#pragma unroll
    for (int f = 0; f < HID; ++f) {
        float v = __shfl(h, f, 64);
        o += v * sWb[f * HID + j];
    }
    h1[n * HID + j] = fmaxf(o, 0.f);   // outer relu of layer 1
}

// ---------------- Layer 2: agg(h1) + MLP2 + pooled-sum ----------------
// quad-gather: wave = 4 groups x 16 lanes; group q loads edge-rows (e0+q, +4, ...)
// as float4 (16 lanes x 16B = 256B coalesced). 4-deep unroll: 16 rows/wave in flight.

__global__ void __launch_bounds__(512) k_layer2(
    const float* __restrict__ h1, const int* __restrict__ rp,
    const int* __restrict__ srcs, const int* __restrict__ batch,
    const float* __restrict__ W2a, const float* __restrict__ b2a,
    const float* __restrict__ W2b, const float* __restrict__ b2b,
    float* __restrict__ sums, float* __restrict__ cnt) {
    __shared__ float sWa[HID * HID];
    __shared__ float sWb[HID * HID];
    __shared__ float sba[HID], sbb[HID];
    for (int i = threadIdx.x; i < HID * HID; i += 512) {
        sWa[i] = W2a[i];
        sWb[i] = W2b[i];
    }
    if (threadIdx.x < HID) {
        sba[threadIdx.x] = b2a[threadIdx.x];
        sbb[threadIdx.x] = b2b[threadIdx.x];
    }
    __syncthreads();

    int wave = (blockIdx.x * 512 + threadIdx.x) >> 6;
    int lane = threadIdx.x & 63;
    if (wave >= N_NODES) return;
    int n = wave;
    int q = lane >> 4;          // edge slot within group-of-4
    int c = lane & 15;          // feature quad
    int e0 = rp[n], e1 = rp[n + 1];

    // hoist self-row + batch loads above the gather loop
    const float4 self = *reinterpret_cast<const float4*>(h1 + (size_t)n * HID + c * 4);
    int g = batch[n];

    float ax = 0.f, ay = 0.f, az = 0.f, aw = 0.f;
    int e = e0 + q;
    // 4-deep: 4 independent rows per lane (16 per wave) in flight
    for (; e + 12 < e1; e += 16) {
        int s0 = srcs[e], s1 = srcs[e + 4], s2 = srcs[e + 8], s3 = srcs[e + 12];
        const float4 v0 = *reinterpret_cast<const float4*>(h1 + (size_t)s0 * HID + c * 4);
        const float4 v1 = *reinterpret_cast<const float4*>(h1 + (size_t)s1 * HID + c * 4);
        const float4 v2 = *reinterpret_cast<const float4*>(h1 + (size_t)s2 * HID + c * 4);
        const float4 v3 = *reinterpret_cast<const float4*>(h1 + (size_t)s3 * HID + c * 4);
        ax += (v0.x + v1.x) + (v2.x + v3.x);
        ay += (v0.y + v1.y) + (v2.y + v3.y);
        az += (v0.z + v1.z) + (v2.z + v3.z);
        aw += (v0.w + v1.w) + (v2.w + v3.w);
    }
    for (; e < e1; e += 4) {
        int s = srcs[e];
        const float4 v = *reinterpret_cast<const float4*>(h1 + (size_t)s * HID + c * 4);
        ax += v.x; ay += v.y; az += v.z; aw += v.w;
    }
    // reduce the 4 edge-slot groups
#pragma unroll
    for (int m = 16; m < 64; m <<= 1) {
        ax += __shfl_xor(ax, m, 64);
        ay += __shfl_xor(ay, m, 64);
        az += __shfl_xor(az, m, 64);
        aw += __shfl_xor(aw, m, 64);
    }
    float zx = ax + self.x, zy = ay + self.y, zz = az + self.z, zw = aw + self.w;

    int j = lane;
    float t = sba[j];
#pragma unroll
    for (int fq = 0; fq < 16; ++fq) {
        float vx = __shfl(zx, fq, 64);
        float vy = __shfl(zy, fq, 64);
        float vz = __shfl(zz, fq, 64);
        float vw = __shfl(zw, fq, 64);
        t += vx * sWa[(fq * 4 + 0) * HID + j];
        t += vy * sWa[(fq * 4 + 1) * HID + j];
        t += vz * sWa[(fq * 4 + 2) * HID + j];
        t += vw * sWa[(fq * 4 + 3) * HID + j];
    }
    t = fmaxf(t, 0.f);

    float u = sbb[j];
#pragma unroll
    for (int f = 0; f < HID; ++f) u += __shfl(t, f, 64) * sWb[f * HID + j];
    u = fmaxf(u, 0.f);                      // outer relu of layer 2

    atomicAdd(&sums[g * HID + j], u);
    if (lane == 0) atomicAdd(&cnt[g], 1.0f);
}

// ---------------- Final: mean pool + classifier ----------------

__global__ void k_final(const float* __restrict__ sums, const float* __restrict__ cnt,
                        const float* __restrict__ Wc, const float* __restrict__ bc,
                        float* __restrict__ out) {
    int g = blockIdx.x;
    int j = threadIdx.x;                    // block of 64
    float c = cnt[g];
    float p = sums[g * HID + j] / fmaxf(c, 1.0f);
    float r0 = p * Wc[j * 2 + 0];
    float r1 = p * Wc[j * 2 + 1];
#pragma unroll
    for (int m = 1; m < 64; m <<= 1) {
        r0 += __shfl_xor(r0, m, 64);
        r1 += __shfl_xor(r1, m, 64);
    }
    if (j == 0) {
        out[g * 2 + 0] = r0 + bc[0];
        out[g * 2 + 1] = r1 + bc[1];
    }
}

// ---------------- launch ----------------

extern "C" void kernel_launch(void* const* d_in, const int* in_sizes, int n_in,
                              void* d_out, int out_size, void* d_ws, size_t ws_size,
                              hipStream_t stream) {
    const float* x   = (const float*)d_in[0];
    const int* ei    = (const int*)d_in[1];
    const int* batch = (const int*)d_in[2];
    const float* W1a = (const float*)d_in[3];
    const float* b1a = (const float*)d_in[4];
    const float* W1b = (const float*)d_in[5];
    const float* b1b = (const float*)d_in[6];
    const float* W2a = (const float*)d_in[7];
    const float* b2a = (const float*)d_in[8];
    const float* W2b = (const float*)d_in[9];
    const float* b2b = (const float*)d_in[10];
    const float* Wc  = (const float*)d_in[11];
    const float* bc  = (const float*)d_in[12];
    float* out = (float*)d_out;

    const int* src = ei;
    const int* dst = ei + N_EDGES;

    // workspace layout (128B aligned chunks)
    char* ws = (char*)d_ws;
    size_t off = 0;
    auto alloc = [&](size_t bytes) {
        char* p = ws + off;
        off += (bytes + 127) & ~size_t(127);
        return p;
    };
    int*   rp     = (int*)alloc((N_NODES + 1) * sizeof(int));
    int*   cursor = (int*)alloc(N_NODES * sizeof(int));       // also deg temp
    int*   bsum   = (int*)alloc(NUM_SCAN_BLOCKS * sizeof(int));
    int*   srcs   = (int*)alloc((size_t)N_EDGES * sizeof(int));
    float* h1     = (float*)alloc((size_t)N_NODES * HID * sizeof(float));
    float* x8     = (float*)alloc((size_t)N_NODES * 8 * sizeof(float));
    float* sums   = (float*)alloc((size_t)(N_GRAPHS * HID + N_GRAPHS) * sizeof(float));
    float* cnt    = sums + (size_t)N_GRAPHS * HID;

    // zero the accumulators (ws is poisoned 0xAA before every timed launch)
    hipMemsetAsync(cursor, 0, N_NODES * sizeof(int), stream);
    hipMemsetAsync(sums, 0, (size_t)(N_GRAPHS * HID + N_GRAPHS) * sizeof(float), stream);

    // CSR build (cursor holds deg, then write cursors) + x padding (independent)
    k_hist<<<2048, 256, 0, stream>>>(dst, cursor);
    k_pad<<<1024, 256, 0, stream>>>(x, x8);
    k_scanA<<<NUM_SCAN_BLOCKS, SCAN_B, 0, stream>>>(cursor, rp, bsum);
    k_scanB<<<1, 512, 0, stream>>>(bsum);
    k_scanC<<<NUM_SCAN_BLOCKS, SCAN_B, 0, stream>>>(rp, bsum, cursor);
    k_fill<<<2048, 256, 0, stream>>>(src, dst, cursor, srcs);

    // layer 1 -> h1 (8 waves / 512-thread block, 1 wave per node)
    int blocks8 = (N_NODES + 7) / 8;
    k_layer1<<<blocks8, 512, 0, stream>>>(x8, rp, srcs, W1a, b1a, W1b, b1b, h1);

    // layer 2 + pooling partial sums
    k_layer2<<<blocks8, 512, 0, stream>>>(h1, rp, srcs, batch,
                                          W2a, b2a, W2b, b2b, sums, cnt);

    // mean pool + classifier
    k_final<<<N_GRAPHS, 64, 0, stream>>>(sums, cnt, Wc, bc, out);
}

// Round 5
// 873.503 us; speedup vs baseline: 1.1448x; 1.1448x over previous
//
#include <hip/hip_runtime.h>

#define N_NODES   100000
#define N_EDGES   3200000
#define N_GRAPHS  1024
#define HID       64

#define SCAN_B    256
#define NUM_SCAN_BLOCKS ((N_NODES + SCAN_B - 1) / SCAN_B)   // 391

// ---------------- CSR build ----------------

__global__ void k_hist(const int* __restrict__ dst, int* __restrict__ deg) {
    int i = blockIdx.x * blockDim.x + threadIdx.x;
    int stride = gridDim.x * blockDim.x;
    for (; i < N_EDGES; i += stride) atomicAdd(&deg[dst[i]], 1);
}

__global__ void k_scanA(const int* __restrict__ deg, int* __restrict__ rp,
                        int* __restrict__ bsum) {
    __shared__ int s[SCAN_B];
    int i = blockIdx.x * SCAN_B + threadIdx.x;
    int v = (i < N_NODES) ? deg[i] : 0;
    s[threadIdx.x] = v;
    __syncthreads();
    for (int off = 1; off < SCAN_B; off <<= 1) {
        int t = (threadIdx.x >= off) ? s[threadIdx.x - off] : 0;
        __syncthreads();
        s[threadIdx.x] += t;
        __syncthreads();
    }
    int incl = s[threadIdx.x];
    if (i < N_NODES) rp[i] = incl - v;                 // exclusive within block
    if (threadIdx.x == SCAN_B - 1) bsum[blockIdx.x] = incl;
}

__global__ void k_scanB(int* __restrict__ bsum) {
    __shared__ int s[512];
    int v = (threadIdx.x < NUM_SCAN_BLOCKS) ? bsum[threadIdx.x] : 0;
    s[threadIdx.x] = v;
    __syncthreads();
    for (int off = 1; off < 512; off <<= 1) {
        int t = (threadIdx.x >= off) ? s[threadIdx.x - off] : 0;
        __syncthreads();
        s[threadIdx.x] += t;
        __syncthreads();
    }
    if (threadIdx.x < NUM_SCAN_BLOCKS) bsum[threadIdx.x] = s[threadIdx.x] - v; // exclusive
}

__global__ void k_scanC(int* __restrict__ rp, const int* __restrict__ bsum,
                        int* __restrict__ cursor) {
    int i = blockIdx.x * blockDim.x + threadIdx.x;
    if (i < N_NODES) {
        int v = rp[i] + bsum[i / SCAN_B];
        rp[i] = v;
        cursor[i] = v;
    }
    if (i == 0) rp[N_NODES] = N_EDGES;
}

__global__ void k_fill(const int* __restrict__ src, const int* __restrict__ dst,
                       int* __restrict__ cursor, int* __restrict__ srcs) {
    int i = blockIdx.x * blockDim.x + threadIdx.x;
    int stride = gridDim.x * blockDim.x;
    for (; i < N_EDGES; i += stride) {
        int d = dst[i];
        int pos = atomicAdd(&cursor[d], 1);
        srcs[pos] = src[i];
    }
}

// ---------------- pad x[N][5] -> x8[N][8] ----------------

__global__ void k_pad(const float* __restrict__ x, float* __restrict__ x8) {
    int i = blockIdx.x * blockDim.x + threadIdx.x;
    int stride = gridDim.x * blockDim.x;
    for (; i < N_NODES * 8; i += stride) {
        int n = i >> 3, j = i & 7;
        x8[i] = (j < 5) ? x[n * 5 + j] : 0.f;
    }
}

// ---------------- Layer 1: agg(x8) + MLP1 -> h1 ----------------
// 4 nodes per wave: group = 16 lanes; lane fq owns output-feature-quad fq.
// Gather: two edges/iter, 8 lanes each (lane reads feature fq&7 of its edge).

__global__ void __launch_bounds__(512) k_layer1(
    const float* __restrict__ x8, const int* __restrict__ rp,
    const int* __restrict__ srcs,
    const float* __restrict__ W1a, const float* __restrict__ b1a,
    const float* __restrict__ W1b, const float* __restrict__ b1b,
    float* __restrict__ h1) {
    __shared__ float sWa[5 * HID];
    __shared__ float sWb[HID * HID];
    __shared__ float sba[HID], sbb[HID];
    for (int i = threadIdx.x; i < HID * HID; i += 512) sWb[i] = W1b[i];
    for (int i = threadIdx.x; i < 5 * HID; i += 512) sWa[i] = W1a[i];
    if (threadIdx.x < HID) {
        sba[threadIdx.x] = b1a[threadIdx.x];
        sbb[threadIdx.x] = b1b[threadIdx.x];
    }
    __syncthreads();

    int wave = (blockIdx.x * 512 + threadIdx.x) >> 6;
    int lane = threadIdx.x & 63;
    int grp  = lane >> 4;       // node slot 0..3
    int fq   = lane & 15;       // feature quad (outputs) / gather role
    int n = wave * 4 + grp;     // 100000 = 3125 blocks * 32 exactly
    int e0 = rp[n], e1 = rp[n + 1];

    // gather: lane handles feature (fq&7) of edge e + (fq>>3); 2 pairs per iter
    float a = 0.f;
    int e = e0;
    while (e < e1) {
        int ei = e + (fq >> 3);
        int ej = ei + 2;
        float v0 = 0.f, v1 = 0.f;
        if (ei < e1) v0 = x8[(size_t)srcs[ei] * 8 + (fq & 7)];
        if (ej < e1) v1 = x8[(size_t)srcs[ej] * 8 + (fq & 7)];
        a += v0 + v1;
        e += 4;
    }
    a += __shfl_xor(a, 8, 16);   // combine the two 8-lane halves

    // z[f] (f=0..4) broadcast within group + self row
    float zf[5];
#pragma unroll
    for (int f = 0; f < 5; ++f)
        zf[f] = __shfl(a, f, 16) + x8[(size_t)n * 8 + f];

    // MLP-A: t-quad (j = 4fq..4fq+3)
    float4 t = *reinterpret_cast<const float4*>(&sba[fq * 4]);
#pragma unroll
    for (int f = 0; f < 5; ++f) {
        const float4 w = *reinterpret_cast<const float4*>(&sWa[f * HID + fq * 4]);
        t.x += zf[f] * w.x; t.y += zf[f] * w.y;
        t.z += zf[f] * w.z; t.w += zf[f] * w.w;
    }
    t.x = fmaxf(t.x, 0.f); t.y = fmaxf(t.y, 0.f);
    t.z = fmaxf(t.z, 0.f); t.w = fmaxf(t.w, 0.f);

    // MLP-B: u-quad = b1b + W1b^T t
    float4 u = *reinterpret_cast<const float4*>(&sbb[fq * 4]);
#pragma unroll
    for (int gq = 0; gq < 16; ++gq) {
        float tx = __shfl(t.x, gq, 16);
        float ty = __shfl(t.y, gq, 16);
        float tz = __shfl(t.z, gq, 16);
        float tw = __shfl(t.w, gq, 16);
        const float4 w0 = *reinterpret_cast<const float4*>(&sWb[(gq * 4 + 0) * HID + fq * 4]);
        const float4 w1 = *reinterpret_cast<const float4*>(&sWb[(gq * 4 + 1) * HID + fq * 4]);
        const float4 w2 = *reinterpret_cast<const float4*>(&sWb[(gq * 4 + 2) * HID + fq * 4]);
        const float4 w3 = *reinterpret_cast<const float4*>(&sWb[(gq * 4 + 3) * HID + fq * 4]);
        u.x += tx * w0.x + ty * w1.x + tz * w2.x + tw * w3.x;
        u.y += tx * w0.y + ty * w1.y + tz * w2.y + tw * w3.y;
        u.z += tx * w0.z + ty * w1.z + tz * w2.z + tw * w3.z;
        u.w += tx * w0.w + ty * w1.w + tz * w2.w + tw * w3.w;
    }
    u.x = fmaxf(u.x, 0.f); u.y = fmaxf(u.y, 0.f);
    u.z = fmaxf(u.z, 0.f); u.w = fmaxf(u.w, 0.f);   // outer relu
    *reinterpret_cast<float4*>(h1 + (size_t)n * HID + fq * 4) = u;
}

// ---------------- Layer 2: agg(h1) + MLP2 + pooled-sum ----------------
// 4 nodes per wave; lane fq accumulates its feature-quad directly (no reduce).
// 2-deep src-index prefetch keeps 8 rows/wave in flight.

__global__ void __launch_bounds__(512) k_layer2(
    const float* __restrict__ h1, const int* __restrict__ rp,
    const int* __restrict__ srcs, const int* __restrict__ batch,
    const float* __restrict__ W2a, const float* __restrict__ b2a,
    const float* __restrict__ W2b, const float* __restrict__ b2b,
    float* __restrict__ sums, float* __restrict__ cnt) {
    __shared__ float sWa[HID * HID];
    __shared__ float sWb[HID * HID];
    __shared__ float sba[HID], sbb[HID];
    for (int i = threadIdx.x; i < HID * HID; i += 512) {
        sWa[i] = W2a[i];
        sWb[i] = W2b[i];
    }
    if (threadIdx.x < HID) {
        sba[threadIdx.x] = b2a[threadIdx.x];
        sbb[threadIdx.x] = b2b[threadIdx.x];
    }
    __syncthreads();

    int wave = (blockIdx.x * 512 + threadIdx.x) >> 6;
    int lane = threadIdx.x & 63;
    int grp  = lane >> 4;
    int fq   = lane & 15;
    int n = wave * 4 + grp;
    int e0 = rp[n], e1 = rp[n + 1];
    int g = batch[n];

    // z-quad starts from self row
    float4 z = *reinterpret_cast<const float4*>(h1 + (size_t)n * HID + fq * 4);

    int e = e0;
    int sA = (e     < e1) ? srcs[e]     : -1;
    int sB = (e + 1 < e1) ? srcs[e + 1] : -1;
    while (e < e1) {
        int sA2 = (e + 2 < e1) ? srcs[e + 2] : -1;
        int sB2 = (e + 3 < e1) ? srcs[e + 3] : -1;
        if (sA >= 0) {
            const float4 v = *reinterpret_cast<const float4*>(h1 + (size_t)sA * HID + fq * 4);
            z.x += v.x; z.y += v.y; z.z += v.z; z.w += v.w;
        }
        if (sB >= 0) {
            const float4 v = *reinterpret_cast<const float4*>(h1 + (size_t)sB * HID + fq * 4);
            z.x += v.x; z.y += v.y; z.z += v.z; z.w += v.w;
        }
        sA = sA2; sB = sB2;
        e += 2;
    }

    // MLP-A: t-quad = relu(b2a + W2a^T z)
    float4 t = *reinterpret_cast<const float4*>(&sba[fq * 4]);
#pragma unroll
    for (int gq = 0; gq < 16; ++gq) {
        float zx = __shfl(z.x, gq, 16);
        float zy = __shfl(z.y, gq, 16);
        float zz = __shfl(z.z, gq, 16);
        float zw = __shfl(z.w, gq, 16);
        const float4 w0 = *reinterpret_cast<const float4*>(&sWa[(gq * 4 + 0) * HID + fq * 4]);
        const float4 w1 = *reinterpret_cast<const float4*>(&sWa[(gq * 4 + 1) * HID + fq * 4]);
        const float4 w2 = *reinterpret_cast<const float4*>(&sWa[(gq * 4 + 2) * HID + fq * 4]);
        const float4 w3 = *reinterpret_cast<const float4*>(&sWa[(gq * 4 + 3) * HID + fq * 4]);
        t.x += zx * w0.x + zy * w1.x + zz * w2.x + zw * w3.x;
        t.y += zx * w0.y + zy * w1.y + zz * w2.y + zw * w3.y;
        t.z += zx * w0.z + zy * w1.z + zz * w2.z + zw * w3.z;
        t.w += zx * w0.w + zy * w1.w + zz * w2.w + zw * w3.w;
    }
    t.x = fmaxf(t.x, 0.f); t.y = fmaxf(t.y, 0.f);
    t.z = fmaxf(t.z, 0.f); t.w = fmaxf(t.w, 0.f);

    // MLP-B: u-quad = relu(b2b + W2b^T t)
    float4 u = *reinterpret_cast<const float4*>(&sbb[fq * 4]);
#pragma unroll
    for (int gq = 0; gq < 16; ++gq) {
        float tx = __shfl(t.x, gq, 16);
        float ty = __shfl(t.y, gq, 16);
        float tz = __shfl(t.z, gq, 16);
        float tw = __shfl(t.w, gq, 16);
        const float4 w0 = *reinterpret_cast<const float4*>(&sWb[(gq * 4 + 0) * HID + fq * 4]);
        const float4 w1 = *reinterpret_cast<const float4*>(&sWb[(gq * 4 + 1) * HID + fq * 4]);
        const float4 w2 = *reinterpret_cast<const float4*>(&sWb[(gq * 4 + 2) * HID + fq * 4]);
        const float4 w3 = *reinterpret_cast<const float4*>(&sWb[(gq * 4 + 3) * HID + fq * 4]);
        u.x += tx * w0.x + ty * w1.x + tz * w2.x + tw * w3.x;
        u.y += tx * w0.y + ty * w1.y + tz * w2.y + tw * w3.y;
        u.z += tx * w0.z + ty * w1.z + tz * w2.z + tw * w3.z;
        u.w += tx * w0.w + ty * w1.w + tz * w2.w + tw * w3.w;
    }
    u.x = fmaxf(u.x, 0.f); u.y = fmaxf(u.y, 0.f);
    u.z = fmaxf(u.z, 0.f); u.w = fmaxf(u.w, 0.f);   // outer relu

    float* sg = sums + (size_t)g * HID + fq * 4;
    atomicAdd(sg + 0, u.x);
    atomicAdd(sg + 1, u.y);
    atomicAdd(sg + 2, u.z);
    atomicAdd(sg + 3, u.w);
    if (fq == 0) atomicAdd(&cnt[g], 1.0f);
}

// ---------------- Final: mean pool + classifier ----------------

__global__ void k_final(const float* __restrict__ sums, const float* __restrict__ cnt,
                        const float* __restrict__ Wc, const float* __restrict__ bc,
                        float* __restrict__ out) {
    int g = blockIdx.x;
    int j = threadIdx.x;                    // block of 64
    float c = cnt[g];
    float p = sums[g * HID + j] / fmaxf(c, 1.0f);
    float r0 = p * Wc[j * 2 + 0];
    float r1 = p * Wc[j * 2 + 1];
#pragma unroll
    for (int m = 1; m < 64; m <<= 1) {
        r0 += __shfl_xor(r0, m, 64);
        r1 += __shfl_xor(r1, m, 64);
    }
    if (j == 0) {
        out[g * 2 + 0] = r0 + bc[0];
        out[g * 2 + 1] = r1 + bc[1];
    }
}

// ---------------- launch ----------------

extern "C" void kernel_launch(void* const* d_in, const int* in_sizes, int n_in,
                              void* d_out, int out_size, void* d_ws, size_t ws_size,
                              hipStream_t stream) {
    const float* x   = (const float*)d_in[0];
    const int* ei    = (const int*)d_in[1];
    const int* batch = (const int*)d_in[2];
    const float* W1a = (const float*)d_in[3];
    const float* b1a = (const float*)d_in[4];
    const float* W1b = (const float*)d_in[5];
    const float* b1b = (const float*)d_in[6];
    const float* W2a = (const float*)d_in[7];
    const float* b2a = (const float*)d_in[8];
    const float* W2b = (const float*)d_in[9];
    const float* b2b = (const float*)d_in[10];
    const float* Wc  = (const float*)d_in[11];
    const float* bc  = (const float*)d_in[12];
    float* out = (float*)d_out;

    const int* src = ei;
    const int* dst = ei + N_EDGES;

    char* ws = (char*)d_ws;
    size_t off = 0;
    auto alloc = [&](size_t bytes) {
        char* p = ws + off;
        off += (bytes + 127) & ~size_t(127);
        return p;
    };
    int*   rp     = (int*)alloc((N_NODES + 1) * sizeof(int));
    int*   cursor = (int*)alloc(N_NODES * sizeof(int));       // also deg temp
    int*   bsum   = (int*)alloc(NUM_SCAN_BLOCKS * sizeof(int));
    int*   srcs   = (int*)alloc((size_t)N_EDGES * sizeof(int));
    float* h1     = (float*)alloc((size_t)N_NODES * HID * sizeof(float));
    float* x8     = (float*)alloc((size_t)N_NODES * 8 * sizeof(float));
    float* sums   = (float*)alloc((size_t)(N_GRAPHS * HID + N_GRAPHS) * sizeof(float));
    float* cnt    = sums + (size_t)N_GRAPHS * HID;

    hipMemsetAsync(cursor, 0, N_NODES * sizeof(int), stream);
    hipMemsetAsync(sums, 0, (size_t)(N_GRAPHS * HID + N_GRAPHS) * sizeof(float), stream);

    // CSR build + x padding
    k_hist<<<2048, 256, 0, stream>>>(dst, cursor);
    k_pad<<<1024, 256, 0, stream>>>(x, x8);
    k_scanA<<<NUM_SCAN_BLOCKS, SCAN_B, 0, stream>>>(cursor, rp, bsum);
    k_scanB<<<1, 512, 0, stream>>>(bsum);
    k_scanC<<<NUM_SCAN_BLOCKS, SCAN_B, 0, stream>>>(rp, bsum, cursor);
    k_fill<<<2048, 256, 0, stream>>>(src, dst, cursor, srcs);

    // 4 nodes per wave -> 32 nodes per 512-thread block; 100000/32 = 3125 exact
    int blocks = N_NODES / 32;
    k_layer1<<<blocks, 512, 0, stream>>>(x8, rp, srcs, W1a, b1a, W1b, b1b, h1);
    k_layer2<<<blocks, 512, 0, stream>>>(h1, rp, srcs, batch,
                                         W2a, b2a, W2b, b2b, sums, cnt);

    k_final<<<N_GRAPHS, 64, 0, stream>>>(sums, cnt, Wc, bc, out);
}

// Round 6
// 851.943 us; speedup vs baseline: 1.1738x; 1.0253x over previous
//
#include <hip/hip_runtime.h>

#define N_NODES   100000
#define N_EDGES   3200000
#define N_GRAPHS  1024
#define HID       64

#define SCAN_B    256
#define NUM_SCAN_BLOCKS ((N_NODES + SCAN_B - 1) / SCAN_B)   // 391

using bf16x8 = __attribute__((ext_vector_type(8))) short;
using f32x4  = __attribute__((ext_vector_type(4))) float;

// ---------------- CSR build ----------------

__global__ void k_hist(const int* __restrict__ dst, int* __restrict__ deg) {
    int i = blockIdx.x * blockDim.x + threadIdx.x;
    int stride = gridDim.x * blockDim.x;
    for (; i < N_EDGES; i += stride) atomicAdd(&deg[dst[i]], 1);
}

__global__ void k_scanA(const int* __restrict__ deg, int* __restrict__ rp,
                        int* __restrict__ bsum) {
    __shared__ int s[SCAN_B];
    int i = blockIdx.x * SCAN_B + threadIdx.x;
    int v = (i < N_NODES) ? deg[i] : 0;
    s[threadIdx.x] = v;
    __syncthreads();
    for (int off = 1; off < SCAN_B; off <<= 1) {
        int t = (threadIdx.x >= off) ? s[threadIdx.x - off] : 0;
        __syncthreads();
        s[threadIdx.x] += t;
        __syncthreads();
    }
    int incl = s[threadIdx.x];
    if (i < N_NODES) rp[i] = incl - v;                 // exclusive within block
    if (threadIdx.x == SCAN_B - 1) bsum[blockIdx.x] = incl;
}

__global__ void k_scanB(int* __restrict__ bsum) {
    __shared__ int s[512];
    int v = (threadIdx.x < NUM_SCAN_BLOCKS) ? bsum[threadIdx.x] : 0;
    s[threadIdx.x] = v;
    __syncthreads();
    for (int off = 1; off < 512; off <<= 1) {
        int t = (threadIdx.x >= off) ? s[threadIdx.x - off] : 0;
        __syncthreads();
        s[threadIdx.x] += t;
        __syncthreads();
    }
    if (threadIdx.x < NUM_SCAN_BLOCKS) bsum[threadIdx.x] = s[threadIdx.x] - v; // exclusive
}

__global__ void k_scanC(int* __restrict__ rp, const int* __restrict__ bsum,
                        int* __restrict__ cursor) {
    int i = blockIdx.x * blockDim.x + threadIdx.x;
    if (i < N_NODES) {
        int v = rp[i] + bsum[i / SCAN_B];
        rp[i] = v;
        cursor[i] = v;
    }
    if (i == 0) rp[N_NODES] = N_EDGES;
}

__global__ void k_fill(const int* __restrict__ src, const int* __restrict__ dst,
                       int* __restrict__ cursor, int* __restrict__ srcs) {
    int i = blockIdx.x * blockDim.x + threadIdx.x;
    int stride = gridDim.x * blockDim.x;
    for (; i < N_EDGES; i += stride) {
        int d = dst[i];
        int pos = atomicAdd(&cursor[d], 1);
        srcs[pos] = src[i];
    }
}

// ---------------- pad x[N][5] -> x8[N][8] ----------------

__global__ void k_pad(const float* __restrict__ x, float* __restrict__ x8) {
    int i = blockIdx.x * blockDim.x + threadIdx.x;
    int stride = gridDim.x * blockDim.x;
    for (; i < N_NODES * 8; i += stride) {
        int n = i >> 3, j = i & 7;
        x8[i] = (j < 5) ? x[n * 5 + j] : 0.f;
    }
}

// ---------------- weight pre-pack: f32 W[64][64] -> split-bf16 B-fragments ----
// frag id f: hi -> ks*4 + t ; lo -> 8 + ks*4 + t. Element j of lane l in frag f:
// W[ks*32 + (l>>4)*8 + j][t*16 + (l&15)]. 4096 threads per weight matrix.

__global__ void k_wconv(const float* __restrict__ W, unsigned short* __restrict__ pack) {
    int i = blockIdx.x * blockDim.x + threadIdx.x;
    if (i >= 4096) return;
    int j    = i & 7;
    int lane = (i >> 3) & 63;
    int t    = (i >> 9) & 3;
    int ks   = (i >> 11) & 1;
    int k   = ks * 32 + (lane >> 4) * 8 + j;
    int col = t * 16 + (lane & 15);
    float w = W[k * HID + col];
    unsigned b = __float_as_uint(w);
    unsigned short hi = (unsigned short)(b >> 16);
    float lf = w - __uint_as_float(b & 0xFFFF0000u);
    unsigned short lo = (unsigned short)(__float_as_uint(lf) >> 16);
    pack[(((ks * 4 + t)) * 64 + lane) * 8 + j]     = hi;
    pack[((8 + ks * 4 + t) * 64 + lane) * 8 + j]   = lo;
}

// ---------------- split-bf16 helper ----------------

__device__ __forceinline__ void split8(const float* v, bf16x8& hi, bf16x8& lo) {
#pragma unroll
    for (int j = 0; j < 8; ++j) {
        unsigned b = __float_as_uint(v[j]);
        hi[j] = (short)(b >> 16);
        float lf = v[j] - __uint_as_float(b & 0xFFFF0000u);
        lo[j] = (short)(__float_as_uint(lf) >> 16);
    }
}

// ---------------- k_g1: gather(x8) + MLP-A (5->64) -> t1 ----------------
// 4 nodes/wave, 16-lane groups; lane fq owns output-quad fq of its node.

__global__ void __launch_bounds__(512) k_g1(
    const float* __restrict__ x8, const int* __restrict__ rp,
    const int* __restrict__ srcs, const float* __restrict__ W1a,
    const float* __restrict__ b1a, float* __restrict__ t1) {
    __shared__ float sWa[5 * HID];
    __shared__ float sba[HID];
    for (int i = threadIdx.x; i < 5 * HID; i += 512) sWa[i] = W1a[i];
    if (threadIdx.x < HID) sba[threadIdx.x] = b1a[threadIdx.x];
    __syncthreads();

    int wave = (blockIdx.x * 512 + threadIdx.x) >> 6;
    int lane = threadIdx.x & 63;
    int grp = lane >> 4, fq = lane & 15;
    int n = wave * 4 + grp;
    int e0 = rp[n], e1 = rp[n + 1];

    float a = 0.f;
    for (int e = e0; e < e1; e += 4) {
        int ei = e + (fq >> 3);
        int ej = ei + 2;
        float v0 = 0.f, v1 = 0.f;
        if (ei < e1) v0 = x8[(size_t)srcs[ei] * 8 + (fq & 7)];
        if (ej < e1) v1 = x8[(size_t)srcs[ej] * 8 + (fq & 7)];
        a += v0 + v1;
    }
    a += __shfl_xor(a, 8, 16);

    float zf[5];
#pragma unroll
    for (int f = 0; f < 5; ++f)
        zf[f] = __shfl(a, f, 16) + x8[(size_t)n * 8 + f];

    float4 t = *reinterpret_cast<const float4*>(&sba[fq * 4]);
#pragma unroll
    for (int f = 0; f < 5; ++f) {
        const float4 w = *reinterpret_cast<const float4*>(&sWa[f * HID + fq * 4]);
        t.x += zf[f] * w.x; t.y += zf[f] * w.y;
        t.z += zf[f] * w.z; t.w += zf[f] * w.w;
    }
    t.x = fmaxf(t.x, 0.f); t.y = fmaxf(t.y, 0.f);
    t.z = fmaxf(t.z, 0.f); t.w = fmaxf(t.w, 0.f);
    *reinterpret_cast<float4*>(t1 + (size_t)n * HID + fq * 4) = t;
}

// ---------------- k_mm1: h1 = relu(t1 @ W1b + b1b), MFMA split-bf16 ----------
// wave = 16 nodes; A row = lane&15 (node), k = (lane>>4)*8+j; D row=(lane>>4)*4+r, col=lane&15(+16t)

__global__ void __launch_bounds__(256) k_mm1(
    const float* __restrict__ t1, const unsigned short* __restrict__ packB,
    const float* __restrict__ bias, float* __restrict__ h1) {
    int wave = threadIdx.x >> 6, lane = threadIdx.x & 63;
    int q = lane >> 4;
    int n0 = blockIdx.x * 64 + wave * 16;
    int arow = n0 + (lane & 15);
    if (arow >= N_NODES) arow = N_NODES - 1;
    const float* ar = t1 + (size_t)arow * HID + q * 8;
    alignas(16) float a0[8], a1[8];
    *reinterpret_cast<float4*>(a0)     = *reinterpret_cast<const float4*>(ar);
    *reinterpret_cast<float4*>(a0 + 4) = *reinterpret_cast<const float4*>(ar + 4);
    *reinterpret_cast<float4*>(a1)     = *reinterpret_cast<const float4*>(ar + 32);
    *reinterpret_cast<float4*>(a1 + 4) = *reinterpret_cast<const float4*>(ar + 36);
    bf16x8 Ah0, Al0, Ah1, Al1;
    split8(a0, Ah0, Al0);
    split8(a1, Ah1, Al1);
    const bf16x8* bp = reinterpret_cast<const bf16x8*>(packB);
#pragma unroll
    for (int t = 0; t < 4; ++t) {
        bf16x8 Bh0 = bp[(t) * 64 + lane];
        bf16x8 Bh1 = bp[(4 + t) * 64 + lane];
        bf16x8 Bl0 = bp[(8 + t) * 64 + lane];
        bf16x8 Bl1 = bp[(12 + t) * 64 + lane];
        f32x4 acc = {0.f, 0.f, 0.f, 0.f};
        acc = __builtin_amdgcn_mfma_f32_16x16x32_bf16(Ah0, Bh0, acc, 0, 0, 0);
        acc = __builtin_amdgcn_mfma_f32_16x16x32_bf16(Ah1, Bh1, acc, 0, 0, 0);
        acc = __builtin_amdgcn_mfma_f32_16x16x32_bf16(Al0, Bh0, acc, 0, 0, 0);
        acc = __builtin_amdgcn_mfma_f32_16x16x32_bf16(Al1, Bh1, acc, 0, 0, 0);
        acc = __builtin_amdgcn_mfma_f32_16x16x32_bf16(Ah0, Bl0, acc, 0, 0, 0);
        acc = __builtin_amdgcn_mfma_f32_16x16x32_bf16(Ah1, Bl1, acc, 0, 0, 0);
        int col = (lane & 15) + 16 * t;
        float bv = bias[col];
#pragma unroll
        for (int r = 0; r < 4; ++r) {
            int node = n0 + q * 4 + r;
            if (node < N_NODES)
                h1[(size_t)node * HID + col] = fmaxf(acc[r] + bv, 0.f);
        }
    }
}

// ---------------- k_g2: z2 = h1 + sum_neighbors(h1) (pure gather, no LDS) ----

__global__ void __launch_bounds__(512) k_g2(
    const float* __restrict__ h1, const int* __restrict__ rp,
    const int* __restrict__ srcs, float* __restrict__ z2) {
    int wave = (blockIdx.x * 512 + threadIdx.x) >> 6;
    int lane = threadIdx.x & 63;
    int grp = lane >> 4, fq = lane & 15;
    int n = wave * 4 + grp;
    int e0 = rp[n], e1 = rp[n + 1];

    float4 z = *reinterpret_cast<const float4*>(h1 + (size_t)n * HID + fq * 4);
    int e = e0;
    int sA = (e < e1) ? srcs[e] : -1;
    int sB = (e + 1 < e1) ? srcs[e + 1] : -1;
    while (e < e1) {
        int sA2 = (e + 2 < e1) ? srcs[e + 2] : -1;
        int sB2 = (e + 3 < e1) ? srcs[e + 3] : -1;
        if (sA >= 0) {
            const float4 v = *reinterpret_cast<const float4*>(h1 + (size_t)sA * HID + fq * 4);
            z.x += v.x; z.y += v.y; z.z += v.z; z.w += v.w;
        }
        if (sB >= 0) {
            const float4 v = *reinterpret_cast<const float4*>(h1 + (size_t)sB * HID + fq * 4);
            z.x += v.x; z.y += v.y; z.z += v.z; z.w += v.w;
        }
        sA = sA2; sB = sB2;
        e += 2;
    }
    *reinterpret_cast<float4*>(z2 + (size_t)n * HID + fq * 4) = z;
}

// ---------------- k_mm2: u = relu(relu(z2@W2a+b2a)@W2b+b2b); pool atomics ----

__global__ void __launch_bounds__(256) k_mm2(
    const float* __restrict__ z2, const unsigned short* __restrict__ packA,
    const unsigned short* __restrict__ packB, const float* __restrict__ b2a,
    const float* __restrict__ b2b, const int* __restrict__ batch,
    float* __restrict__ sums, float* __restrict__ cnt) {
    __shared__ __align__(16) float tm[4][16][68];
    int wave = threadIdx.x >> 6, lane = threadIdx.x & 63;
    int q = lane >> 4;
    int n0 = blockIdx.x * 64 + wave * 16;
    int arow = n0 + (lane & 15);
    if (arow >= N_NODES) arow = N_NODES - 1;

    {   // GEMV1: t = relu(z2 @ W2a + b2a) -> tm (per-wave LDS tile)
        const float* ar = z2 + (size_t)arow * HID + q * 8;
        alignas(16) float a0[8], a1[8];
        *reinterpret_cast<float4*>(a0)     = *reinterpret_cast<const float4*>(ar);
        *reinterpret_cast<float4*>(a0 + 4) = *reinterpret_cast<const float4*>(ar + 4);
        *reinterpret_cast<float4*>(a1)     = *reinterpret_cast<const float4*>(ar + 32);
        *reinterpret_cast<float4*>(a1 + 4) = *reinterpret_cast<const float4*>(ar + 36);
        bf16x8 Ah0, Al0, Ah1, Al1;
        split8(a0, Ah0, Al0);
        split8(a1, Ah1, Al1);
        const bf16x8* bp = reinterpret_cast<const bf16x8*>(packA);
#pragma unroll
        for (int t = 0; t < 4; ++t) {
            bf16x8 Bh0 = bp[(t) * 64 + lane];
            bf16x8 Bh1 = bp[(4 + t) * 64 + lane];
            bf16x8 Bl0 = bp[(8 + t) * 64 + lane];
            bf16x8 Bl1 = bp[(12 + t) * 64 + lane];
            f32x4 acc = {0.f, 0.f, 0.f, 0.f};
            acc = __builtin_amdgcn_mfma_f32_16x16x32_bf16(Ah0, Bh0, acc, 0, 0, 0);
            acc = __builtin_amdgcn_mfma_f32_16x16x32_bf16(Ah1, Bh1, acc, 0, 0, 0);
            acc = __builtin_amdgcn_mfma_f32_16x16x32_bf16(Al0, Bh0, acc, 0, 0, 0);
            acc = __builtin_amdgcn_mfma_f32_16x16x32_bf16(Al1, Bh1, acc, 0, 0, 0);
            acc = __builtin_amdgcn_mfma_f32_16x16x32_bf16(Ah0, Bl0, acc, 0, 0, 0);
            acc = __builtin_amdgcn_mfma_f32_16x16x32_bf16(Ah1, Bl1, acc, 0, 0, 0);
            int col = (lane & 15) + 16 * t;
            float bv = b2a[col];
#pragma unroll
            for (int r = 0; r < 4; ++r)
                tm[wave][q * 4 + r][col] = fmaxf(acc[r] + bv, 0.f);
        }
    }

    // GEMV2: u = relu(t @ W2b + b2b); A re-read from tm (compiler orders via lgkmcnt)
    const float* tr = &tm[wave][lane & 15][0];
    alignas(16) float c0[8], c1[8];
    *reinterpret_cast<float4*>(c0)     = *reinterpret_cast<const float4*>(tr + q * 8);
    *reinterpret_cast<float4*>(c0 + 4) = *reinterpret_cast<const float4*>(tr + q * 8 + 4);
    *reinterpret_cast<float4*>(c1)     = *reinterpret_cast<const float4*>(tr + 32 + q * 8);
    *reinterpret_cast<float4*>(c1 + 4) = *reinterpret_cast<const float4*>(tr + 36 + q * 8);
    bf16x8 Ch0, Cl0, Ch1, Cl1;
    split8(c0, Ch0, Cl0);
    split8(c1, Ch1, Cl1);

    int gg[4];
#pragma unroll
    for (int r = 0; r < 4; ++r) {
        int node = n0 + q * 4 + r;
        gg[r] = batch[node < N_NODES ? node : N_NODES - 1];
    }

    const bf16x8* bp = reinterpret_cast<const bf16x8*>(packB);
#pragma unroll
    for (int t = 0; t < 4; ++t) {
        bf16x8 Bh0 = bp[(t) * 64 + lane];
        bf16x8 Bh1 = bp[(4 + t) * 64 + lane];
        bf16x8 Bl0 = bp[(8 + t) * 64 + lane];
        bf16x8 Bl1 = bp[(12 + t) * 64 + lane];
        f32x4 acc = {0.f, 0.f, 0.f, 0.f};
        acc = __builtin_amdgcn_mfma_f32_16x16x32_bf16(Ch0, Bh0, acc, 0, 0, 0);
        acc = __builtin_amdgcn_mfma_f32_16x16x32_bf16(Ch1, Bh1, acc, 0, 0, 0);
        acc = __builtin_amdgcn_mfma_f32_16x16x32_bf16(Cl0, Bh0, acc, 0, 0, 0);
        acc = __builtin_amdgcn_mfma_f32_16x16x32_bf16(Cl1, Bh1, acc, 0, 0, 0);
        acc = __builtin_amdgcn_mfma_f32_16x16x32_bf16(Ch0, Bl0, acc, 0, 0, 0);
        acc = __builtin_amdgcn_mfma_f32_16x16x32_bf16(Ch1, Bl1, acc, 0, 0, 0);
        int col = (lane & 15) + 16 * t;
        float bv = b2b[col];
#pragma unroll
        for (int r = 0; r < 4; ++r) {
            int node = n0 + q * 4 + r;
            if (node < N_NODES)
                atomicAdd(&sums[gg[r] * HID + col], fmaxf(acc[r] + bv, 0.f));
        }
    }
    if (lane < 16 && n0 + lane < N_NODES)
        atomicAdd(&cnt[batch[n0 + lane]], 1.0f);
}

// ---------------- Final: mean pool + classifier ----------------

__global__ void k_final(const float* __restrict__ sums, const float* __restrict__ cnt,
                        const float* __restrict__ Wc, const float* __restrict__ bc,
                        float* __restrict__ out) {
    int g = blockIdx.x;
    int j = threadIdx.x;                    // block of 64
    float c = cnt[g];
    float p = sums[g * HID + j] / fmaxf(c, 1.0f);
    float r0 = p * Wc[j * 2 + 0];
    float r1 = p * Wc[j * 2 + 1];
#pragma unroll
    for (int m = 1; m < 64; m <<= 1) {
        r0 += __shfl_xor(r0, m, 64);
        r1 += __shfl_xor(r1, m, 64);
    }
    if (j == 0) {
        out[g * 2 + 0] = r0 + bc[0];
        out[g * 2 + 1] = r1 + bc[1];
    }
}

// ---------------- launch ----------------

extern "C" void kernel_launch(void* const* d_in, const int* in_sizes, int n_in,
                              void* d_out, int out_size, void* d_ws, size_t ws_size,
                              hipStream_t stream) {
    const float* x   = (const float*)d_in[0];
    const int* ei    = (const int*)d_in[1];
    const int* batch = (const int*)d_in[2];
    const float* W1a = (const float*)d_in[3];
    const float* b1a = (const float*)d_in[4];
    const float* W1b = (const float*)d_in[5];
    const float* b1b = (const float*)d_in[6];
    const float* W2a = (const float*)d_in[7];
    const float* b2a = (const float*)d_in[8];
    const float* W2b = (const float*)d_in[9];
    const float* b2b = (const float*)d_in[10];
    const float* Wc  = (const float*)d_in[11];
    const float* bc  = (const float*)d_in[12];
    float* out = (float*)d_out;

    const int* src = ei;
    const int* dst = ei + N_EDGES;

    char* ws = (char*)d_ws;
    size_t off = 0;
    auto alloc = [&](size_t bytes) {
        char* p = ws + off;
        off += (bytes + 127) & ~size_t(127);
        return p;
    };
    int*   rp     = (int*)alloc((N_NODES + 1) * sizeof(int));
    int*   cursor = (int*)alloc(N_NODES * sizeof(int));       // also deg temp
    int*   bsum   = (int*)alloc(NUM_SCAN_BLOCKS * sizeof(int));
    int*   srcs   = (int*)alloc((size_t)N_EDGES * sizeof(int));
    float* h1     = (float*)alloc((size_t)N_NODES * HID * sizeof(float));
    float* t1     = (float*)alloc((size_t)N_NODES * HID * sizeof(float));
    float* z2     = (float*)alloc((size_t)N_NODES * HID * sizeof(float));
    float* x8     = (float*)alloc((size_t)N_NODES * 8 * sizeof(float));
    unsigned short* pk1b = (unsigned short*)alloc(8192 * sizeof(unsigned short));
    unsigned short* pk2a = (unsigned short*)alloc(8192 * sizeof(unsigned short));
    unsigned short* pk2b = (unsigned short*)alloc(8192 * sizeof(unsigned short));
    float* sums   = (float*)alloc((size_t)(N_GRAPHS * HID + N_GRAPHS) * sizeof(float));
    float* cnt    = sums + (size_t)N_GRAPHS * HID;

    hipMemsetAsync(cursor, 0, N_NODES * sizeof(int), stream);
    hipMemsetAsync(sums, 0, (size_t)(N_GRAPHS * HID + N_GRAPHS) * sizeof(float), stream);

    // CSR build + x padding + weight packing
    k_hist<<<2048, 256, 0, stream>>>(dst, cursor);
    k_pad<<<1024, 256, 0, stream>>>(x, x8);
    k_wconv<<<16, 256, 0, stream>>>(W1b, pk1b);
    k_wconv<<<16, 256, 0, stream>>>(W2a, pk2a);
    k_wconv<<<16, 256, 0, stream>>>(W2b, pk2b);
    k_scanA<<<NUM_SCAN_BLOCKS, SCAN_B, 0, stream>>>(cursor, rp, bsum);
    k_scanB<<<1, 512, 0, stream>>>(bsum);
    k_scanC<<<NUM_SCAN_BLOCKS, SCAN_B, 0, stream>>>(rp, bsum, cursor);
    k_fill<<<2048, 256, 0, stream>>>(src, dst, cursor, srcs);

    int gblocks = N_NODES / 32;              // 3125, exact (4 nodes/wave, 8 waves)
    int mblocks = (N_NODES + 63) / 64;       // 1563 (16 nodes/wave, 4 waves)

    k_g1 <<<gblocks, 512, 0, stream>>>(x8, rp, srcs, W1a, b1a, t1);
    k_mm1<<<mblocks, 256, 0, stream>>>(t1, pk1b, b1b, h1);
    k_g2 <<<gblocks, 512, 0, stream>>>(h1, rp, srcs, z2);
    k_mm2<<<mblocks, 256, 0, stream>>>(z2, pk2a, pk2b, b2a, b2b, batch, sums, cnt);

    k_final<<<N_GRAPHS, 64, 0, stream>>>(sums, cnt, Wc, bc, out);
}

// Round 7
// 520.430 us; speedup vs baseline: 1.9215x; 1.6370x over previous
//
#include <hip/hip_runtime.h>

#define N_NODES   100000
#define N_EDGES   3200000
#define N_GRAPHS  1024
#define HID       64

#define NPB   128                          // nodes per bucket (dst >> 7)
#define NB    782                          // ceil(100000/128)
#define NBLK  256                          // blocks in p1/p3
#define EPB   (N_EDGES / NBLK)             // 12500 edges per block (exact)
#define CAP   6144                         // srcs staging per bucket (mean 4093, sigma 64)

using bf16x8 = __attribute__((ext_vector_type(8))) short;
using f32x4  = __attribute__((ext_vector_type(4))) float;

// ============ bucketed CSR build (no global atomics, coalesced writes) ======

__global__ void __launch_bounds__(256) k_p1(const int* __restrict__ dst,
                                            int* __restrict__ cnt) {   // cnt[NBLK][NB]
    __shared__ int h[NB];
    for (int i = threadIdx.x; i < NB; i += 256) h[i] = 0;
    __syncthreads();
    int base = blockIdx.x * EPB;
    for (int i = threadIdx.x; i < EPB; i += 256)
        atomicAdd(&h[dst[base + i] >> 7], 1);
    __syncthreads();
    for (int i = threadIdx.x; i < NB; i += 256)
        cnt[blockIdx.x * NB + i] = h[i];
}

// per-bucket exclusive scan across the 256 blocks -> excT[b][blk]; totals -> btot
__global__ void __launch_bounds__(256) k_p2(const int* __restrict__ cnt,
                                            int* __restrict__ excT,
                                            int* __restrict__ btot) {
    __shared__ int wsum[4];
    int b = blockIdx.x, t = threadIdx.x;
    int v = cnt[t * NB + b];
    int incl = v;
#pragma unroll
    for (int off = 1; off < 64; off <<= 1) {
        int u = __shfl_up(incl, off, 64);
        if ((t & 63) >= off) incl += u;
    }
    if ((t & 63) == 63) wsum[t >> 6] = incl;
    __syncthreads();
    int woff = 0;
    for (int w = 0; w < (t >> 6); ++w) woff += wsum[w];
    excT[b * NBLK + t] = woff + incl - v;
    if (t == 255) btot[b] = woff + incl;
}

__global__ void __launch_bounds__(1024) k_p2b(const int* __restrict__ btot,
                                              int* __restrict__ bbase,
                                              int* __restrict__ rp) {
    __shared__ int s[1024];
    int t = threadIdx.x;
    int v = (t < NB) ? btot[t] : 0;
    s[t] = v;
    __syncthreads();
    for (int off = 1; off < 1024; off <<= 1) {
        int u = (t >= off) ? s[t - off] : 0;
        __syncthreads();
        s[t] += u;
        __syncthreads();
    }
    if (t < NB) bbase[t] = s[t] - v;
    if (t == 0) { bbase[NB] = N_EDGES; rp[N_NODES] = N_EDGES; }
}

// scatter packed (loc7|src17) into bucket-grouped order; LDS cursors only
__global__ void __launch_bounds__(256) k_p3(const int* __restrict__ src,
                                            const int* __restrict__ dst,
                                            const int* __restrict__ excT,
                                            const int* __restrict__ bbase,
                                            unsigned int* __restrict__ packed) {
    __shared__ int cur[NB];
    int blk = blockIdx.x;
    for (int i = threadIdx.x; i < NB; i += 256)
        cur[i] = bbase[i] + excT[i * NBLK + blk];
    __syncthreads();
    int base = blk * EPB;
    for (int i = threadIdx.x; i < EPB; i += 256) {
        int d = dst[base + i];
        int pos = atomicAdd(&cur[d >> 7], 1);    // LDS atomic
        packed[pos] = ((unsigned)(d & 127) << 17) | (unsigned)src[base + i];
    }
}

// per-bucket fine CSR: LDS hist over 128 nodes, LDS-staged coalesced srcs dump
__global__ void __launch_bounds__(256) k_p4(const unsigned int* __restrict__ packed,
                                            const int* __restrict__ bbase,
                                            int* __restrict__ rp,
                                            int* __restrict__ srcs) {
    __shared__ int hist[NPB + 1];
    __shared__ int stage[CAP];
    int b = blockIdx.x, t = threadIdx.x;
    int lo = bbase[b], hi = bbase[b + 1];
    int n_e = hi - lo;
    if (t < NPB + 1) hist[t] = 0;
    __syncthreads();
    for (int i = t; i < n_e; i += 256)
        atomicAdd(&hist[(packed[lo + i] >> 17) + 1], 1);
    __syncthreads();
    for (int off = 1; off < NPB + 1; off <<= 1) {       // Hillis-Steele scan
        int u = 0;
        if (t < NPB + 1 && t >= off) u = hist[t - off];
        __syncthreads();
        if (t < NPB + 1 && t >= off) hist[t] += u;
        __syncthreads();
    }
    int nbase = b * NPB;
    if (t < NPB && nbase + t < N_NODES) rp[nbase + t] = lo + hist[t];
    __syncthreads();                                    // rp reads done before cursor use
    if (n_e <= CAP) {
        for (int i = t; i < n_e; i += 256) {
            unsigned v = packed[lo + i];
            int pos = atomicAdd(&hist[v >> 17], 1);
            stage[pos] = (int)(v & 0x1FFFFu);
        }
        __syncthreads();
        for (int i = t; i < n_e; i += 256) srcs[lo + i] = stage[i];
    } else {                                            // statistically impossible fallback
        for (int i = t; i < n_e; i += 256) {
            unsigned v = packed[lo + i];
            int pos = atomicAdd(&hist[v >> 17], 1);
            srcs[lo + pos] = (int)(v & 0x1FFFFu);
        }
    }
}

// ============ pad x[N][5] -> x8[N][8] ======================================

__global__ void k_pad(const float* __restrict__ x, float* __restrict__ x8) {
    int i = blockIdx.x * blockDim.x + threadIdx.x;
    int stride = gridDim.x * blockDim.x;
    for (; i < N_NODES * 8; i += stride) {
        int n = i >> 3, j = i & 7;
        x8[i] = (j < 5) ? x[n * 5 + j] : 0.f;
    }
}

// ============ weight pre-pack: f32 W[64][64] -> split-bf16 B-fragments ======

__global__ void k_wconv(const float* __restrict__ W, unsigned short* __restrict__ pack) {
    int i = blockIdx.x * blockDim.x + threadIdx.x;
    if (i >= 4096) return;
    int j    = i & 7;
    int lane = (i >> 3) & 63;
    int t    = (i >> 9) & 3;
    int ks   = (i >> 11) & 1;
    int k   = ks * 32 + (lane >> 4) * 8 + j;
    int col = t * 16 + (lane & 15);
    float w = W[k * HID + col];
    unsigned b = __float_as_uint(w);
    unsigned short hiw = (unsigned short)(b >> 16);
    float lf = w - __uint_as_float(b & 0xFFFF0000u);
    unsigned short low = (unsigned short)(__float_as_uint(lf) >> 16);
    pack[(((ks * 4 + t)) * 64 + lane) * 8 + j]   = hiw;
    pack[((8 + ks * 4 + t) * 64 + lane) * 8 + j] = low;
}

__device__ __forceinline__ void split8(const float* v, bf16x8& hi, bf16x8& lo) {
#pragma unroll
    for (int j = 0; j < 8; ++j) {
        unsigned b = __float_as_uint(v[j]);
        hi[j] = (short)(b >> 16);
        float lf = v[j] - __uint_as_float(b & 0xFFFF0000u);
        lo[j] = (short)(__float_as_uint(lf) >> 16);
    }
}

// ============ k_g1: gather(x8) + MLP-A (5->64) -> t1 ========================

__global__ void __launch_bounds__(512) k_g1(
    const float* __restrict__ x8, const int* __restrict__ rp,
    const int* __restrict__ srcs, const float* __restrict__ W1a,
    const float* __restrict__ b1a, float* __restrict__ t1) {
    __shared__ float sWa[5 * HID];
    __shared__ float sba[HID];
    for (int i = threadIdx.x; i < 5 * HID; i += 512) sWa[i] = W1a[i];
    if (threadIdx.x < HID) sba[threadIdx.x] = b1a[threadIdx.x];
    __syncthreads();

    int wave = (blockIdx.x * 512 + threadIdx.x) >> 6;
    int lane = threadIdx.x & 63;
    int grp = lane >> 4, fq = lane & 15;
    int n = wave * 4 + grp;
    int e0 = rp[n], e1 = rp[n + 1];

    float a = 0.f;
    for (int e = e0; e < e1; e += 4) {
        int ei = e + (fq >> 3);
        int ej = ei + 2;
        float v0 = 0.f, v1 = 0.f;
        if (ei < e1) v0 = x8[(size_t)srcs[ei] * 8 + (fq & 7)];
        if (ej < e1) v1 = x8[(size_t)srcs[ej] * 8 + (fq & 7)];
        a += v0 + v1;
    }
    a += __shfl_xor(a, 8, 16);

    float zf[5];
#pragma unroll
    for (int f = 0; f < 5; ++f)
        zf[f] = __shfl(a, f, 16) + x8[(size_t)n * 8 + f];

    float4 t = *reinterpret_cast<const float4*>(&sba[fq * 4]);
#pragma unroll
    for (int f = 0; f < 5; ++f) {
        const float4 w = *reinterpret_cast<const float4*>(&sWa[f * HID + fq * 4]);
        t.x += zf[f] * w.x; t.y += zf[f] * w.y;
        t.z += zf[f] * w.z; t.w += zf[f] * w.w;
    }
    t.x = fmaxf(t.x, 0.f); t.y = fmaxf(t.y, 0.f);
    t.z = fmaxf(t.z, 0.f); t.w = fmaxf(t.w, 0.f);
    *reinterpret_cast<float4*>(t1 + (size_t)n * HID + fq * 4) = t;
}

// ============ k_mm1: h1 = relu(t1 @ W1b + b1b), split-bf16 MFMA (8-term) ====

__global__ void __launch_bounds__(256) k_mm1(
    const float* __restrict__ t1, const unsigned short* __restrict__ packB,
    const float* __restrict__ bias, float* __restrict__ h1) {
    int wave = threadIdx.x >> 6, lane = threadIdx.x & 63;
    int q = lane >> 4;
    int n0 = blockIdx.x * 64 + wave * 16;
    int arow = n0 + (lane & 15);
    if (arow >= N_NODES) arow = N_NODES - 1;
    const float* ar = t1 + (size_t)arow * HID + q * 8;
    alignas(16) float a0[8], a1[8];
    *reinterpret_cast<float4*>(a0)     = *reinterpret_cast<const float4*>(ar);
    *reinterpret_cast<float4*>(a0 + 4) = *reinterpret_cast<const float4*>(ar + 4);
    *reinterpret_cast<float4*>(a1)     = *reinterpret_cast<const float4*>(ar + 32);
    *reinterpret_cast<float4*>(a1 + 4) = *reinterpret_cast<const float4*>(ar + 36);
    bf16x8 Ah0, Al0, Ah1, Al1;
    split8(a0, Ah0, Al0);
    split8(a1, Ah1, Al1);
    const bf16x8* bp = reinterpret_cast<const bf16x8*>(packB);
#pragma unroll
    for (int t = 0; t < 4; ++t) {
        bf16x8 Bh0 = bp[(t) * 64 + lane];
        bf16x8 Bh1 = bp[(4 + t) * 64 + lane];
        bf16x8 Bl0 = bp[(8 + t) * 64 + lane];
        bf16x8 Bl1 = bp[(12 + t) * 64 + lane];
        f32x4 acc = {0.f, 0.f, 0.f, 0.f};
        acc = __builtin_amdgcn_mfma_f32_16x16x32_bf16(Ah0, Bh0, acc, 0, 0, 0);
        acc = __builtin_amdgcn_mfma_f32_16x16x32_bf16(Ah1, Bh1, acc, 0, 0, 0);
        acc = __builtin_amdgcn_mfma_f32_16x16x32_bf16(Al0, Bh0, acc, 0, 0, 0);
        acc = __builtin_amdgcn_mfma_f32_16x16x32_bf16(Al1, Bh1, acc, 0, 0, 0);
        acc = __builtin_amdgcn_mfma_f32_16x16x32_bf16(Ah0, Bl0, acc, 0, 0, 0);
        acc = __builtin_amdgcn_mfma_f32_16x16x32_bf16(Ah1, Bl1, acc, 0, 0, 0);
        acc = __builtin_amdgcn_mfma_f32_16x16x32_bf16(Al0, Bl0, acc, 0, 0, 0);
        acc = __builtin_amdgcn_mfma_f32_16x16x32_bf16(Al1, Bl1, acc, 0, 0, 0);
        int col = (lane & 15) + 16 * t;
        float bv = bias[col];
#pragma unroll
        for (int r = 0; r < 4; ++r) {
            int node = n0 + q * 4 + r;
            if (node < N_NODES)
                h1[(size_t)node * HID + col] = fmaxf(acc[r] + bv, 0.f);
        }
    }
}

// ============ k_g2: z2 = h1 + sum_neighbors(h1) =============================

__global__ void __launch_bounds__(512) k_g2(
    const float* __restrict__ h1, const int* __restrict__ rp,
    const int* __restrict__ srcs, float* __restrict__ z2) {
    int wave = (blockIdx.x * 512 + threadIdx.x) >> 6;
    int lane = threadIdx.x & 63;
    int grp = lane >> 4, fq = lane & 15;
    int n = wave * 4 + grp;
    int e0 = rp[n], e1 = rp[n + 1];

    float4 z = *reinterpret_cast<const float4*>(h1 + (size_t)n * HID + fq * 4);
    int e = e0;
    int sA = (e < e1) ? srcs[e] : -1;
    int sB = (e + 1 < e1) ? srcs[e + 1] : -1;
    while (e < e1) {
        int sA2 = (e + 2 < e1) ? srcs[e + 2] : -1;
        int sB2 = (e + 3 < e1) ? srcs[e + 3] : -1;
        if (sA >= 0) {
            const float4 v = *reinterpret_cast<const float4*>(h1 + (size_t)sA * HID + fq * 4);
            z.x += v.x; z.y += v.y; z.z += v.z; z.w += v.w;
        }
        if (sB >= 0) {
            const float4 v = *reinterpret_cast<const float4*>(h1 + (size_t)sB * HID + fq * 4);
            z.x += v.x; z.y += v.y; z.z += v.z; z.w += v.w;
        }
        sA = sA2; sB = sB2;
        e += 2;
    }
    *reinterpret_cast<float4*>(z2 + (size_t)n * HID + fq * 4) = z;
}

// ============ k_mm2: u = relu(relu(z2@W2a+b2a)@W2b+b2b); pooled atomics =====

__global__ void __launch_bounds__(256) k_mm2(
    const float* __restrict__ z2, const unsigned short* __restrict__ packA,
    const unsigned short* __restrict__ packB, const float* __restrict__ b2a,
    const float* __restrict__ b2b, const int* __restrict__ batch,
    float* __restrict__ sums, float* __restrict__ cnt) {
    __shared__ __align__(16) float tm[4][16][68];
    int wave = threadIdx.x >> 6, lane = threadIdx.x & 63;
    int q = lane >> 4;
    int n0 = blockIdx.x * 64 + wave * 16;
    int arow = n0 + (lane & 15);
    if (arow >= N_NODES) arow = N_NODES - 1;

    {   // GEMV1: t = relu(z2 @ W2a + b2a) -> tm
        const float* ar = z2 + (size_t)arow * HID + q * 8;
        alignas(16) float a0[8], a1[8];
        *reinterpret_cast<float4*>(a0)     = *reinterpret_cast<const float4*>(ar);
        *reinterpret_cast<float4*>(a0 + 4) = *reinterpret_cast<const float4*>(ar + 4);
        *reinterpret_cast<float4*>(a1)     = *reinterpret_cast<const float4*>(ar + 32);
        *reinterpret_cast<float4*>(a1 + 4) = *reinterpret_cast<const float4*>(ar + 36);
        bf16x8 Ah0, Al0, Ah1, Al1;
        split8(a0, Ah0, Al0);
        split8(a1, Ah1, Al1);
        const bf16x8* bp = reinterpret_cast<const bf16x8*>(packA);
#pragma unroll
        for (int t = 0; t < 4; ++t) {
            bf16x8 Bh0 = bp[(t) * 64 + lane];
            bf16x8 Bh1 = bp[(4 + t) * 64 + lane];
            bf16x8 Bl0 = bp[(8 + t) * 64 + lane];
            bf16x8 Bl1 = bp[(12 + t) * 64 + lane];
            f32x4 acc = {0.f, 0.f, 0.f, 0.f};
            acc = __builtin_amdgcn_mfma_f32_16x16x32_bf16(Ah0, Bh0, acc, 0, 0, 0);
            acc = __builtin_amdgcn_mfma_f32_16x16x32_bf16(Ah1, Bh1, acc, 0, 0, 0);
            acc = __builtin_amdgcn_mfma_f32_16x16x32_bf16(Al0, Bh0, acc, 0, 0, 0);
            acc = __builtin_amdgcn_mfma_f32_16x16x32_bf16(Al1, Bh1, acc, 0, 0, 0);
            acc = __builtin_amdgcn_mfma_f32_16x16x32_bf16(Ah0, Bl0, acc, 0, 0, 0);
            acc = __builtin_amdgcn_mfma_f32_16x16x32_bf16(Ah1, Bl1, acc, 0, 0, 0);
            acc = __builtin_amdgcn_mfma_f32_16x16x32_bf16(Al0, Bl0, acc, 0, 0, 0);
            acc = __builtin_amdgcn_mfma_f32_16x16x32_bf16(Al1, Bl1, acc, 0, 0, 0);
            int col = (lane & 15) + 16 * t;
            float bv = b2a[col];
#pragma unroll
            for (int r = 0; r < 4; ++r)
                tm[wave][q * 4 + r][col] = fmaxf(acc[r] + bv, 0.f);
        }
    }

    // GEMV2
    const float* tr = &tm[wave][lane & 15][0];
    alignas(16) float c0[8], c1[8];
    *reinterpret_cast<float4*>(c0)     = *reinterpret_cast<const float4*>(tr + q * 8);
    *reinterpret_cast<float4*>(c0 + 4) = *reinterpret_cast<const float4*>(tr + q * 8 + 4);
    *reinterpret_cast<float4*>(c1)     = *reinterpret_cast<const float4*>(tr + 32 + q * 8);
    *reinterpret_cast<float4*>(c1 + 4) = *reinterpret_cast<const float4*>(tr + 36 + q * 8);
    bf16x8 Ch0, Cl0, Ch1, Cl1;
    split8(c0, Ch0, Cl0);
    split8(c1, Cl1, Cl1);   // placeholder overwritten below
    split8(c0, Ch0, Cl0);
    split8(c1, Ch1, Cl1);

    int gg[4];
#pragma unroll
    for (int r = 0; r < 4; ++r) {
        int node = n0 + q * 4 + r;
        gg[r] = batch[node < N_NODES ? node : N_NODES - 1];
    }

    const bf16x8* bp = reinterpret_cast<const bf16x8*>(packB);
#pragma unroll
    for (int t = 0; t < 4; ++t) {
        bf16x8 Bh0 = bp[(t) * 64 + lane];
        bf16x8 Bh1 = bp[(4 + t) * 64 + lane];
        bf16x8 Bl0 = bp[(8 + t) * 64 + lane];
        bf16x8 Bl1 = bp[(12 + t) * 64 + lane];
        f32x4 acc = {0.f, 0.f, 0.f, 0.f};
        acc = __builtin_amdgcn_mfma_f32_16x16x32_bf16(Ch0, Bh0, acc, 0, 0, 0);
        acc = __builtin_amdgcn_mfma_f32_16x16x32_bf16(Ch1, Bh1, acc, 0, 0, 0);
        acc = __builtin_amdgcn_mfma_f32_16x16x32_bf16(Cl0, Bh0, acc, 0, 0, 0);
        acc = __builtin_amdgcn_mfma_f32_16x16x32_bf16(Cl1, Bh1, acc, 0, 0, 0);
        acc = __builtin_amdgcn_mfma_f32_16x16x32_bf16(Ch0, Bl0, acc, 0, 0, 0);
        acc = __builtin_amdgcn_mfma_f32_16x16x32_bf16(Ch1, Bl1, acc, 0, 0, 0);
        acc = __builtin_amdgcn_mfma_f32_16x16x32_bf16(Cl0, Bl0, acc, 0, 0, 0);
        acc = __builtin_amdgcn_mfma_f32_16x16x32_bf16(Cl1, Bl1, acc, 0, 0, 0);
        int col = (lane & 15) + 16 * t;
        float bv = b2b[col];
#pragma unroll
        for (int r = 0; r < 4; ++r) {
            int node = n0 + q * 4 + r;
            if (node < N_NODES)
                atomicAdd(&sums[gg[r] * HID + col], fmaxf(acc[r] + bv, 0.f));
        }
    }
    if (lane < 16 && n0 + lane < N_NODES)
        atomicAdd(&cnt[batch[n0 + lane]], 1.0f);
}

// ============ Final: mean pool + classifier =================================

__global__ void k_final(const float* __restrict__ sums, const float* __restrict__ cnt,
                        const float* __restrict__ Wc, const float* __restrict__ bc,
                        float* __restrict__ out) {
    int g = blockIdx.x;
    int j = threadIdx.x;
    float c = cnt[g];
    float p = sums[g * HID + j] / fmaxf(c, 1.0f);
    float r0 = p * Wc[j * 2 + 0];
    float r1 = p * Wc[j * 2 + 1];
#pragma unroll
    for (int m = 1; m < 64; m <<= 1) {
        r0 += __shfl_xor(r0, m, 64);
        r1 += __shfl_xor(r1, m, 64);
    }
    if (j == 0) {
        out[g * 2 + 0] = r0 + bc[0];
        out[g * 2 + 1] = r1 + bc[1];
    }
}

// ============ launch ========================================================

extern "C" void kernel_launch(void* const* d_in, const int* in_sizes, int n_in,
                              void* d_out, int out_size, void* d_ws, size_t ws_size,
                              hipStream_t stream) {
    const float* x   = (const float*)d_in[0];
    const int* ei    = (const int*)d_in[1];
    const int* batch = (const int*)d_in[2];
    const float* W1a = (const float*)d_in[3];
    const float* b1a = (const float*)d_in[4];
    const float* W1b = (const float*)d_in[5];
    const float* b1b = (const float*)d_in[6];
    const float* W2a = (const float*)d_in[7];
    const float* b2a = (const float*)d_in[8];
    const float* W2b = (const float*)d_in[9];
    const float* b2b = (const float*)d_in[10];
    const float* Wc  = (const float*)d_in[11];
    const float* bc  = (const float*)d_in[12];
    float* out = (float*)d_out;

    const int* src = ei;
    const int* dst = ei + N_EDGES;

    char* ws = (char*)d_ws;
    size_t off = 0;
    auto alloc = [&](size_t bytes) {
        char* p = ws + off;
        off += (bytes + 127) & ~size_t(127);
        return p;
    };
    int*   rp    = (int*)alloc((N_NODES + 1) * sizeof(int));
    int*   srcs  = (int*)alloc((size_t)N_EDGES * sizeof(int));
    float* h1    = (float*)alloc((size_t)N_NODES * HID * sizeof(float));
    float* t1    = (float*)alloc((size_t)N_NODES * HID * sizeof(float));
    float* z2    = (float*)alloc((size_t)N_NODES * HID * sizeof(float));
    float* x8    = (float*)alloc((size_t)N_NODES * 8 * sizeof(float));
    int*   btot  = (int*)alloc(NB * sizeof(int));
    int*   bbase = (int*)alloc((NB + 1) * sizeof(int));
    unsigned short* pk1b = (unsigned short*)alloc(8192 * sizeof(unsigned short));
    unsigned short* pk2a = (unsigned short*)alloc(8192 * sizeof(unsigned short));
    unsigned short* pk2b = (unsigned short*)alloc(8192 * sizeof(unsigned short));
    float* sums  = (float*)alloc((size_t)(N_GRAPHS * HID + N_GRAPHS) * sizeof(float));
    float* cnt   = sums + (size_t)N_GRAPHS * HID;

    // aliases: dead before their hosts are written
    int* bcnt = (int*)h1;                       // cnt[NBLK][NB]  (800 KB, h1 written later)
    int* excT = (int*)h1 + NBLK * NB;           // excT[NB][NBLK] (800 KB)
    unsigned int* packed = (unsigned int*)z2;   // 12.8 MB, z2 written later

    hipMemsetAsync(sums, 0, (size_t)(N_GRAPHS * HID + N_GRAPHS) * sizeof(float), stream);

    // CSR build (atomic-free at global scope)
    k_p1 <<<NBLK, 256, 0, stream>>>(dst, bcnt);
    k_pad<<<1024, 256, 0, stream>>>(x, x8);
    k_wconv<<<16, 256, 0, stream>>>(W1b, pk1b);
    k_wconv<<<16, 256, 0, stream>>>(W2a, pk2a);
    k_wconv<<<16, 256, 0, stream>>>(W2b, pk2b);
    k_p2 <<<NB, 256, 0, stream>>>(bcnt, excT, btot);
    k_p2b<<<1, 1024, 0, stream>>>(btot, bbase, rp);
    k_p3 <<<NBLK, 256, 0, stream>>>(src, dst, excT, bbase, packed);
    k_p4 <<<NB, 256, 0, stream>>>(packed, bbase, rp, srcs);

    int gblocks = N_NODES / 32;              // 3125 (4 nodes/wave, 8 waves/block)
    int mblocks = (N_NODES + 63) / 64;       // 1563 (16 nodes/wave, 4 waves/block)

    k_g1 <<<gblocks, 512, 0, stream>>>(x8, rp, srcs, W1a, b1a, t1);
    k_mm1<<<mblocks, 256, 0, stream>>>(t1, pk1b, b1b, h1);
    k_g2 <<<gblocks, 512, 0, stream>>>(h1, rp, srcs, z2);
    k_mm2<<<mblocks, 256, 0, stream>>>(z2, pk2a, pk2b, b2a, b2b, batch, sums, cnt);

    k_final<<<N_GRAPHS, 64, 0, stream>>>(sums, cnt, Wc, bc, out);
}

// Round 8
// 387.972 us; speedup vs baseline: 2.5775x; 1.3414x over previous
//
#include <hip/hip_runtime.h>

#define N_NODES   100000
#define N_EDGES   3200000
#define N_GRAPHS  1024
#define HID       64

#define NPB   128                          // nodes per bucket (dst >> 7)
#define NB    782                          // ceil(100000/128)
#define NBLK  256                          // blocks in p1/p3
#define EPB   (N_EDGES / NBLK)             // 12500 edges per block (exact)
#define CAP   6144                         // srcs staging per bucket

using bf16x8 = __attribute__((ext_vector_type(8))) short;
using f32x4  = __attribute__((ext_vector_type(4))) float;

// ============ bucketed CSR build (no global atomics, coalesced writes) ======

__global__ void __launch_bounds__(256) k_p1(const int* __restrict__ dst,
                                            int* __restrict__ cnt) {   // cnt[NBLK][NB]
    __shared__ int h[NB];
    for (int i = threadIdx.x; i < NB; i += 256) h[i] = 0;
    __syncthreads();
    int base = blockIdx.x * EPB;
    for (int i = threadIdx.x; i < EPB; i += 256)
        atomicAdd(&h[dst[base + i] >> 7], 1);
    __syncthreads();
    for (int i = threadIdx.x; i < NB; i += 256)
        cnt[blockIdx.x * NB + i] = h[i];
}

__global__ void __launch_bounds__(256) k_p2(const int* __restrict__ cnt,
                                            int* __restrict__ excT,
                                            int* __restrict__ btot) {
    __shared__ int wsum[4];
    int b = blockIdx.x, t = threadIdx.x;
    int v = cnt[t * NB + b];
    int incl = v;
#pragma unroll
    for (int off = 1; off < 64; off <<= 1) {
        int u = __shfl_up(incl, off, 64);
        if ((t & 63) >= off) incl += u;
    }
    if ((t & 63) == 63) wsum[t >> 6] = incl;
    __syncthreads();
    int woff = 0;
    for (int w = 0; w < (t >> 6); ++w) woff += wsum[w];
    excT[b * NBLK + t] = woff + incl - v;
    if (t == 255) btot[b] = woff + incl;
}

__global__ void __launch_bounds__(1024) k_p2b(const int* __restrict__ btot,
                                              int* __restrict__ bbase,
                                              int* __restrict__ rp) {
    __shared__ int s[1024];
    int t = threadIdx.x;
    int v = (t < NB) ? btot[t] : 0;
    s[t] = v;
    __syncthreads();
    for (int off = 1; off < 1024; off <<= 1) {
        int u = (t >= off) ? s[t - off] : 0;
        __syncthreads();
        s[t] += u;
        __syncthreads();
    }
    if (t < NB) bbase[t] = s[t] - v;
    if (t == 0) { bbase[NB] = N_EDGES; rp[N_NODES] = N_EDGES; }
}

__global__ void __launch_bounds__(256) k_p3(const int* __restrict__ src,
                                            const int* __restrict__ dst,
                                            const int* __restrict__ excT,
                                            const int* __restrict__ bbase,
                                            unsigned int* __restrict__ packed) {
    __shared__ int cur[NB];
    int blk = blockIdx.x;
    for (int i = threadIdx.x; i < NB; i += 256)
        cur[i] = bbase[i] + excT[i * NBLK + blk];
    __syncthreads();
    int base = blk * EPB;
    for (int i = threadIdx.x; i < EPB; i += 256) {
        int d = dst[base + i];
        int pos = atomicAdd(&cur[d >> 7], 1);    // LDS atomic
        packed[pos] = ((unsigned)(d & 127) << 17) | (unsigned)src[base + i];
    }
}

__global__ void __launch_bounds__(256) k_p4(const unsigned int* __restrict__ packed,
                                            const int* __restrict__ bbase,
                                            int* __restrict__ rp,
                                            int* __restrict__ srcs) {
    __shared__ int hist[NPB + 1];
    __shared__ int stage[CAP];
    int b = blockIdx.x, t = threadIdx.x;
    int lo = bbase[b], hi = bbase[b + 1];
    int n_e = hi - lo;
    if (t < NPB + 1) hist[t] = 0;
    __syncthreads();
    for (int i = t; i < n_e; i += 256)
        atomicAdd(&hist[(packed[lo + i] >> 17) + 1], 1);
    __syncthreads();
    for (int off = 1; off < NPB + 1; off <<= 1) {
        int u = 0;
        if (t < NPB + 1 && t >= off) u = hist[t - off];
        __syncthreads();
        if (t < NPB + 1 && t >= off) hist[t] += u;
        __syncthreads();
    }
    int nbase = b * NPB;
    if (t < NPB && nbase + t < N_NODES) rp[nbase + t] = lo + hist[t];
    __syncthreads();
    if (n_e <= CAP) {
        for (int i = t; i < n_e; i += 256) {
            unsigned v = packed[lo + i];
            int pos = atomicAdd(&hist[v >> 17], 1);
            stage[pos] = (int)(v & 0x1FFFFu);
        }
        __syncthreads();
        for (int i = t; i < n_e; i += 256) srcs[lo + i] = stage[i];
    } else {
        for (int i = t; i < n_e; i += 256) {
            unsigned v = packed[lo + i];
            int pos = atomicAdd(&hist[v >> 17], 1);
            srcs[lo + pos] = (int)(v & 0x1FFFFu);
        }
    }
}

// ============ pad x[N][5] -> x8[N][8] ======================================

__global__ void k_pad(const float* __restrict__ x, float* __restrict__ x8) {
    int i = blockIdx.x * blockDim.x + threadIdx.x;
    int stride = gridDim.x * blockDim.x;
    for (; i < N_NODES * 8; i += stride) {
        int n = i >> 3, j = i & 7;
        x8[i] = (j < 5) ? x[n * 5 + j] : 0.f;
    }
}

// ============ graph boundaries from sorted batch ===========================

__global__ void k_bounds(const int* __restrict__ batch, int* __restrict__ gstart,
                         int* __restrict__ gend) {
    int i = blockIdx.x * blockDim.x + threadIdx.x;
    if (i >= N_NODES) return;
    int g = batch[i];
    if (i == 0 || batch[i - 1] != g) atomicMin(&gstart[g], i);
    if (i == N_NODES - 1 || batch[i + 1] != g) atomicMax(&gend[g], i + 1);
}

// ============ weight pre-pack: f32 W[64][64] -> split-bf16 B-fragments ======

__global__ void k_wconv(const float* __restrict__ W, unsigned short* __restrict__ pack) {
    int i = blockIdx.x * blockDim.x + threadIdx.x;
    if (i >= 4096) return;
    int j    = i & 7;
    int lane = (i >> 3) & 63;
    int t    = (i >> 9) & 3;
    int ks   = (i >> 11) & 1;
    int k   = ks * 32 + (lane >> 4) * 8 + j;
    int col = t * 16 + (lane & 15);
    float w = W[k * HID + col];
    unsigned b = __float_as_uint(w);
    unsigned short hiw = (unsigned short)(b >> 16);
    float lf = w - __uint_as_float(b & 0xFFFF0000u);
    unsigned short low = (unsigned short)(__float_as_uint(lf) >> 16);
    pack[(((ks * 4 + t)) * 64 + lane) * 8 + j]   = hiw;
    pack[((8 + ks * 4 + t) * 64 + lane) * 8 + j] = low;
}

__device__ __forceinline__ void split8(const float* v, bf16x8& hi, bf16x8& lo) {
#pragma unroll
    for (int j = 0; j < 8; ++j) {
        unsigned b = __float_as_uint(v[j]);
        hi[j] = (short)(b >> 16);
        float lf = v[j] - __uint_as_float(b & 0xFFFF0000u);
        lo[j] = (short)(__float_as_uint(lf) >> 16);
    }
}

// ============ k_g1: gather(x8) + MLP-A (5->64) -> t1 ========================

__global__ void __launch_bounds__(512) k_g1(
    const float* __restrict__ x8, const int* __restrict__ rp,
    const int* __restrict__ srcs, const float* __restrict__ W1a,
    const float* __restrict__ b1a, float* __restrict__ t1) {
    __shared__ float sWa[5 * HID];
    __shared__ float sba[HID];
    for (int i = threadIdx.x; i < 5 * HID; i += 512) sWa[i] = W1a[i];
    if (threadIdx.x < HID) sba[threadIdx.x] = b1a[threadIdx.x];
    __syncthreads();

    int wave = (blockIdx.x * 512 + threadIdx.x) >> 6;
    int lane = threadIdx.x & 63;
    int grp = lane >> 4, fq = lane & 15;
    int n = wave * 4 + grp;
    int e0 = rp[n], e1 = rp[n + 1];

    float a = 0.f;
    for (int e = e0; e < e1; e += 4) {
        int ei = e + (fq >> 3);
        int ej = ei + 2;
        float v0 = 0.f, v1 = 0.f;
        if (ei < e1) v0 = x8[(size_t)srcs[ei] * 8 + (fq & 7)];
        if (ej < e1) v1 = x8[(size_t)srcs[ej] * 8 + (fq & 7)];
        a += v0 + v1;
    }
    a += __shfl_xor(a, 8, 16);

    float zf[5];
#pragma unroll
    for (int f = 0; f < 5; ++f)
        zf[f] = __shfl(a, f, 16) + x8[(size_t)n * 8 + f];

    float4 t = *reinterpret_cast<const float4*>(&sba[fq * 4]);
#pragma unroll
    for (int f = 0; f < 5; ++f) {
        const float4 w = *reinterpret_cast<const float4*>(&sWa[f * HID + fq * 4]);
        t.x += zf[f] * w.x; t.y += zf[f] * w.y;
        t.z += zf[f] * w.z; t.w += zf[f] * w.w;
    }
    t.x = fmaxf(t.x, 0.f); t.y = fmaxf(t.y, 0.f);
    t.z = fmaxf(t.z, 0.f); t.w = fmaxf(t.w, 0.f);
    *reinterpret_cast<float4*>(t1 + (size_t)n * HID + fq * 4) = t;
}

// ============ k_mm1: h1 = relu(t1 @ W1b + b1b), split-bf16 MFMA =============

__global__ void __launch_bounds__(256) k_mm1(
    const float* __restrict__ t1, const unsigned short* __restrict__ packB,
    const float* __restrict__ bias, float* __restrict__ h1) {
    int wave = threadIdx.x >> 6, lane = threadIdx.x & 63;
    int q = lane >> 4;
    int n0 = blockIdx.x * 64 + wave * 16;
    int arow = n0 + (lane & 15);
    if (arow >= N_NODES) arow = N_NODES - 1;
    const float* ar = t1 + (size_t)arow * HID + q * 8;
    alignas(16) float a0[8], a1[8];
    *reinterpret_cast<float4*>(a0)     = *reinterpret_cast<const float4*>(ar);
    *reinterpret_cast<float4*>(a0 + 4) = *reinterpret_cast<const float4*>(ar + 4);
    *reinterpret_cast<float4*>(a1)     = *reinterpret_cast<const float4*>(ar + 32);
    *reinterpret_cast<float4*>(a1 + 4) = *reinterpret_cast<const float4*>(ar + 36);
    bf16x8 Ah0, Al0, Ah1, Al1;
    split8(a0, Ah0, Al0);
    split8(a1, Ah1, Al1);
    const bf16x8* bp = reinterpret_cast<const bf16x8*>(packB);
#pragma unroll
    for (int t = 0; t < 4; ++t) {
        bf16x8 Bh0 = bp[(t) * 64 + lane];
        bf16x8 Bh1 = bp[(4 + t) * 64 + lane];
        bf16x8 Bl0 = bp[(8 + t) * 64 + lane];
        bf16x8 Bl1 = bp[(12 + t) * 64 + lane];
        f32x4 acc = {0.f, 0.f, 0.f, 0.f};
        acc = __builtin_amdgcn_mfma_f32_16x16x32_bf16(Ah0, Bh0, acc, 0, 0, 0);
        acc = __builtin_amdgcn_mfma_f32_16x16x32_bf16(Ah1, Bh1, acc, 0, 0, 0);
        acc = __builtin_amdgcn_mfma_f32_16x16x32_bf16(Al0, Bh0, acc, 0, 0, 0);
        acc = __builtin_amdgcn_mfma_f32_16x16x32_bf16(Al1, Bh1, acc, 0, 0, 0);
        acc = __builtin_amdgcn_mfma_f32_16x16x32_bf16(Ah0, Bl0, acc, 0, 0, 0);
        acc = __builtin_amdgcn_mfma_f32_16x16x32_bf16(Ah1, Bl1, acc, 0, 0, 0);
        acc = __builtin_amdgcn_mfma_f32_16x16x32_bf16(Al0, Bl0, acc, 0, 0, 0);
        acc = __builtin_amdgcn_mfma_f32_16x16x32_bf16(Al1, Bl1, acc, 0, 0, 0);
        int col = (lane & 15) + 16 * t;
        float bv = bias[col];
#pragma unroll
        for (int r = 0; r < 4; ++r) {
            int node = n0 + q * 4 + r;
            if (node < N_NODES)
                h1[(size_t)node * HID + col] = fmaxf(acc[r] + bv, 0.f);
        }
    }
}

// ============ k_g2: z2 = h1 + sum_neighbors(h1) =============================

__global__ void __launch_bounds__(512) k_g2(
    const float* __restrict__ h1, const int* __restrict__ rp,
    const int* __restrict__ srcs, float* __restrict__ z2) {
    int wave = (blockIdx.x * 512 + threadIdx.x) >> 6;
    int lane = threadIdx.x & 63;
    int grp = lane >> 4, fq = lane & 15;
    int n = wave * 4 + grp;
    int e0 = rp[n], e1 = rp[n + 1];

    float4 z = *reinterpret_cast<const float4*>(h1 + (size_t)n * HID + fq * 4);
    int e = e0;
    int sA = (e < e1) ? srcs[e] : -1;
    int sB = (e + 1 < e1) ? srcs[e + 1] : -1;
    while (e < e1) {
        int sA2 = (e + 2 < e1) ? srcs[e + 2] : -1;
        int sB2 = (e + 3 < e1) ? srcs[e + 3] : -1;
        if (sA >= 0) {
            const float4 v = *reinterpret_cast<const float4*>(h1 + (size_t)sA * HID + fq * 4);
            z.x += v.x; z.y += v.y; z.z += v.z; z.w += v.w;
        }
        if (sB >= 0) {
            const float4 v = *reinterpret_cast<const float4*>(h1 + (size_t)sB * HID + fq * 4);
            z.x += v.x; z.y += v.y; z.z += v.z; z.w += v.w;
        }
        sA = sA2; sB = sB2;
        e += 2;
    }
    *reinterpret_cast<float4*>(z2 + (size_t)n * HID + fq * 4) = z;
}

// ============ k_mm2: u = relu(relu(z2@W2a+b2a)@W2b+b2b) -> u_out (dense) ====

__global__ void __launch_bounds__(256) k_mm2(
    const float* __restrict__ z2, const unsigned short* __restrict__ packA,
    const unsigned short* __restrict__ packB, const float* __restrict__ b2a,
    const float* __restrict__ b2b, float* __restrict__ u_out) {
    __shared__ __align__(16) float tm[4][16][68];
    int wave = threadIdx.x >> 6, lane = threadIdx.x & 63;
    int q = lane >> 4;
    int n0 = blockIdx.x * 64 + wave * 16;
    int arow = n0 + (lane & 15);
    if (arow >= N_NODES) arow = N_NODES - 1;

    {   // GEMV1: t = relu(z2 @ W2a + b2a) -> tm
        const float* ar = z2 + (size_t)arow * HID + q * 8;
        alignas(16) float a0[8], a1[8];
        *reinterpret_cast<float4*>(a0)     = *reinterpret_cast<const float4*>(ar);
        *reinterpret_cast<float4*>(a0 + 4) = *reinterpret_cast<const float4*>(ar + 4);
        *reinterpret_cast<float4*>(a1)     = *reinterpret_cast<const float4*>(ar + 32);
        *reinterpret_cast<float4*>(a1 + 4) = *reinterpret_cast<const float4*>(ar + 36);
        bf16x8 Ah0, Al0, Ah1, Al1;
        split8(a0, Ah0, Al0);
        split8(a1, Ah1, Al1);
        const bf16x8* bp = reinterpret_cast<const bf16x8*>(packA);
#pragma unroll
        for (int t = 0; t < 4; ++t) {
            bf16x8 Bh0 = bp[(t) * 64 + lane];
            bf16x8 Bh1 = bp[(4 + t) * 64 + lane];
            bf16x8 Bl0 = bp[(8 + t) * 64 + lane];
            bf16x8 Bl1 = bp[(12 + t) * 64 + lane];
            f32x4 acc = {0.f, 0.f, 0.f, 0.f};
            acc = __builtin_amdgcn_mfma_f32_16x16x32_bf16(Ah0, Bh0, acc, 0, 0, 0);
            acc = __builtin_amdgcn_mfma_f32_16x16x32_bf16(Ah1, Bh1, acc, 0, 0, 0);
            acc = __builtin_amdgcn_mfma_f32_16x16x32_bf16(Al0, Bh0, acc, 0, 0, 0);
            acc = __builtin_amdgcn_mfma_f32_16x16x32_bf16(Al1, Bh1, acc, 0, 0, 0);
            acc = __builtin_amdgcn_mfma_f32_16x16x32_bf16(Ah0, Bl0, acc, 0, 0, 0);
            acc = __builtin_amdgcn_mfma_f32_16x16x32_bf16(Ah1, Bl1, acc, 0, 0, 0);
            acc = __builtin_amdgcn_mfma_f32_16x16x32_bf16(Al0, Bl0, acc, 0, 0, 0);
            acc = __builtin_amdgcn_mfma_f32_16x16x32_bf16(Al1, Bl1, acc, 0, 0, 0);
            int col = (lane & 15) + 16 * t;
            float bv = b2a[col];
#pragma unroll
            for (int r = 0; r < 4; ++r)
                tm[wave][q * 4 + r][col] = fmaxf(acc[r] + bv, 0.f);
        }
    }

    // GEMV2: u = relu(t @ W2b + b2b) -> u_out (dense store, no atomics)
    const float* tr = &tm[wave][lane & 15][0];
    alignas(16) float c0[8], c1[8];
    *reinterpret_cast<float4*>(c0)     = *reinterpret_cast<const float4*>(tr + q * 8);
    *reinterpret_cast<float4*>(c0 + 4) = *reinterpret_cast<const float4*>(tr + q * 8 + 4);
    *reinterpret_cast<float4*>(c1)     = *reinterpret_cast<const float4*>(tr + 32 + q * 8);
    *reinterpret_cast<float4*>(c1 + 4) = *reinterpret_cast<const float4*>(tr + 36 + q * 8);
    bf16x8 Ch0, Cl0, Ch1, Cl1;
    split8(c0, Ch0, Cl0);
    split8(c1, Ch1, Cl1);

    const bf16x8* bp = reinterpret_cast<const bf16x8*>(packB);
#pragma unroll
    for (int t = 0; t < 4; ++t) {
        bf16x8 Bh0 = bp[(t) * 64 + lane];
        bf16x8 Bh1 = bp[(4 + t) * 64 + lane];
        bf16x8 Bl0 = bp[(8 + t) * 64 + lane];
        bf16x8 Bl1 = bp[(12 + t) * 64 + lane];
        f32x4 acc = {0.f, 0.f, 0.f, 0.f};
        acc = __builtin_amdgcn_mfma_f32_16x16x32_bf16(Ch0, Bh0, acc, 0, 0, 0);
        acc = __builtin_amdgcn_mfma_f32_16x16x32_bf16(Ch1, Bh1, acc, 0, 0, 0);
        acc = __builtin_amdgcn_mfma_f32_16x16x32_bf16(Cl0, Bh0, acc, 0, 0, 0);
        acc = __builtin_amdgcn_mfma_f32_16x16x32_bf16(Cl1, Bh1, acc, 0, 0, 0);
        acc = __builtin_amdgcn_mfma_f32_16x16x32_bf16(Ch0, Bl0, acc, 0, 0, 0);
        acc = __builtin_amdgcn_mfma_f32_16x16x32_bf16(Ch1, Bl1, acc, 0, 0, 0);
        acc = __builtin_amdgcn_mfma_f32_16x16x32_bf16(Cl0, Bl0, acc, 0, 0, 0);
        acc = __builtin_amdgcn_mfma_f32_16x16x32_bf16(Cl1, Bl1, acc, 0, 0, 0);
        int col = (lane & 15) + 16 * t;
        float bv = b2b[col];
#pragma unroll
        for (int r = 0; r < 4; ++r) {
            int node = n0 + q * 4 + r;
            if (node < N_NODES)
                u_out[(size_t)node * HID + col] = fmaxf(acc[r] + bv, 0.f);
        }
    }
}

// ============ k_final2: segmented mean pool + classifier ====================

__global__ void __launch_bounds__(256) k_final2(
    const float* __restrict__ u, const int* __restrict__ gstart,
    const int* __restrict__ gend, const float* __restrict__ Wc,
    const float* __restrict__ bc, float* __restrict__ out) {
    __shared__ float red[4][64];
    int g = blockIdx.x, t = threadIdx.x;
    int col = t & 63, ch = t >> 6;
    int s = gstart[g], e = gend[g];
    float acc = 0.f;
    for (int i = s + ch; i < e; i += 4)
        acc += u[(size_t)i * HID + col];
    red[ch][col] = acc;
    __syncthreads();
    if (t < 64) {
        float p = red[0][t] + red[1][t] + red[2][t] + red[3][t];
        float count = (float)(e - s);
        p /= fmaxf(count, 1.0f);
        float r0 = p * Wc[t * 2 + 0];
        float r1 = p * Wc[t * 2 + 1];
#pragma unroll
        for (int m = 1; m < 64; m <<= 1) {
            r0 += __shfl_xor(r0, m, 64);
            r1 += __shfl_xor(r1, m, 64);
        }
        if (t == 0) {
            out[g * 2 + 0] = r0 + bc[0];
            out[g * 2 + 1] = r1 + bc[1];
        }
    }
}

// ============ launch ========================================================

extern "C" void kernel_launch(void* const* d_in, const int* in_sizes, int n_in,
                              void* d_out, int out_size, void* d_ws, size_t ws_size,
                              hipStream_t stream) {
    const float* x   = (const float*)d_in[0];
    const int* ei    = (const int*)d_in[1];
    const int* batch = (const int*)d_in[2];
    const float* W1a = (const float*)d_in[3];
    const float* b1a = (const float*)d_in[4];
    const float* W1b = (const float*)d_in[5];
    const float* b1b = (const float*)d_in[6];
    const float* W2a = (const float*)d_in[7];
    const float* b2a = (const float*)d_in[8];
    const float* W2b = (const float*)d_in[9];
    const float* b2b = (const float*)d_in[10];
    const float* Wc  = (const float*)d_in[11];
    const float* bc  = (const float*)d_in[12];
    float* out = (float*)d_out;

    const int* src = ei;
    const int* dst = ei + N_EDGES;

    char* ws = (char*)d_ws;
    size_t off = 0;
    auto alloc = [&](size_t bytes) {
        char* p = ws + off;
        off += (bytes + 127) & ~size_t(127);
        return p;
    };
    int*   rp    = (int*)alloc((N_NODES + 1) * sizeof(int));
    int*   srcs  = (int*)alloc((size_t)N_EDGES * sizeof(int));
    float* h1    = (float*)alloc((size_t)N_NODES * HID * sizeof(float));
    float* t1    = (float*)alloc((size_t)N_NODES * HID * sizeof(float));  // also u_out
    float* z2    = (float*)alloc((size_t)N_NODES * HID * sizeof(float));
    float* x8    = (float*)alloc((size_t)N_NODES * 8 * sizeof(float));
    int*   btot  = (int*)alloc(NB * sizeof(int));
    int*   bbase = (int*)alloc((NB + 1) * sizeof(int));
    int*   gstart= (int*)alloc(N_GRAPHS * sizeof(int));
    int*   gend  = (int*)alloc(N_GRAPHS * sizeof(int));
    unsigned short* pk1b = (unsigned short*)alloc(8192 * sizeof(unsigned short));
    unsigned short* pk2a = (unsigned short*)alloc(8192 * sizeof(unsigned short));
    unsigned short* pk2b = (unsigned short*)alloc(8192 * sizeof(unsigned short));

    // aliases: dead before their hosts are written
    int* bcnt = (int*)h1;                       // cnt[NBLK][NB]
    int* excT = (int*)h1 + NBLK * NB;           // excT[NB][NBLK]
    unsigned int* packed = (unsigned int*)z2;   // 12.8 MB

    hipMemsetAsync(gstart, 0x7F, N_GRAPHS * sizeof(int), stream);  // large sentinel
    hipMemsetAsync(gend, 0, N_GRAPHS * sizeof(int), stream);

    // CSR build (atomic-free at global scope) + prep
    k_p1 <<<NBLK, 256, 0, stream>>>(dst, bcnt);
    k_pad<<<1024, 256, 0, stream>>>(x, x8);
    k_bounds<<<(N_NODES + 255) / 256, 256, 0, stream>>>(batch, gstart, gend);
    k_wconv<<<16, 256, 0, stream>>>(W1b, pk1b);
    k_wconv<<<16, 256, 0, stream>>>(W2a, pk2a);
    k_wconv<<<16, 256, 0, stream>>>(W2b, pk2b);
    k_p2 <<<NB, 256, 0, stream>>>(bcnt, excT, btot);
    k_p2b<<<1, 1024, 0, stream>>>(btot, bbase, rp);
    k_p3 <<<NBLK, 256, 0, stream>>>(src, dst, excT, bbase, packed);
    k_p4 <<<NB, 256, 0, stream>>>(packed, bbase, rp, srcs);

    int gblocks = N_NODES / 32;              // 3125 (4 nodes/wave, 8 waves/block)
    int mblocks = (N_NODES + 63) / 64;       // 1563 (16 nodes/wave, 4 waves/block)

    k_g1 <<<gblocks, 512, 0, stream>>>(x8, rp, srcs, W1a, b1a, t1);
    k_mm1<<<mblocks, 256, 0, stream>>>(t1, pk1b, b1b, h1);
    k_g2 <<<gblocks, 512, 0, stream>>>(h1, rp, srcs, z2);
    k_mm2<<<mblocks, 256, 0, stream>>>(z2, pk2a, pk2b, b2a, b2b, t1);  // u -> t1

    k_final2<<<N_GRAPHS, 256, 0, stream>>>(t1, gstart, gend, Wc, bc, out);
}

// Round 9
// 380.156 us; speedup vs baseline: 2.6305x; 1.0206x over previous
//
#include <hip/hip_runtime.h>

#define N_NODES   100000
#define N_EDGES   3200000
#define N_GRAPHS  1024
#define HID       64

#define NPB   128                          // nodes per bucket (dst >> 7)
#define NB    782                          // ceil(100000/128)
#define NBLK  256                          // blocks in p1/p3
#define EPB   (N_EDGES / NBLK)             // 12500 edges per block (exact)
#define CAP   6144                         // srcs staging per bucket

using bf16x8 = __attribute__((ext_vector_type(8))) short;
using f32x4  = __attribute__((ext_vector_type(4))) float;

// ============ bucketed CSR build (no global atomics, coalesced writes) ======

__global__ void __launch_bounds__(256) k_p1(const int* __restrict__ dst,
                                            int* __restrict__ cnt) {   // cnt[NBLK][NB]
    __shared__ int h[NB];
    for (int i = threadIdx.x; i < NB; i += 256) h[i] = 0;
    __syncthreads();
    int base = blockIdx.x * EPB;
    for (int i = threadIdx.x; i < EPB; i += 256)
        atomicAdd(&h[dst[base + i] >> 7], 1);
    __syncthreads();
    for (int i = threadIdx.x; i < NB; i += 256)
        cnt[blockIdx.x * NB + i] = h[i];
}

__global__ void __launch_bounds__(256) k_p2(const int* __restrict__ cnt,
                                            int* __restrict__ excT,
                                            int* __restrict__ btot) {
    __shared__ int wsum[4];
    int b = blockIdx.x, t = threadIdx.x;
    int v = cnt[t * NB + b];
    int incl = v;
#pragma unroll
    for (int off = 1; off < 64; off <<= 1) {
        int u = __shfl_up(incl, off, 64);
        if ((t & 63) >= off) incl += u;
    }
    if ((t & 63) == 63) wsum[t >> 6] = incl;
    __syncthreads();
    int woff = 0;
    for (int w = 0; w < (t >> 6); ++w) woff += wsum[w];
    excT[b * NBLK + t] = woff + incl - v;
    if (t == 255) btot[b] = woff + incl;
}

__global__ void __launch_bounds__(1024) k_p2b(const int* __restrict__ btot,
                                              int* __restrict__ bbase,
                                              int* __restrict__ rp) {
    __shared__ int s[1024];
    int t = threadIdx.x;
    int v = (t < NB) ? btot[t] : 0;
    s[t] = v;
    __syncthreads();
    for (int off = 1; off < 1024; off <<= 1) {
        int u = (t >= off) ? s[t - off] : 0;
        __syncthreads();
        s[t] += u;
        __syncthreads();
    }
    if (t < NB) bbase[t] = s[t] - v;
    if (t == 0) { bbase[NB] = N_EDGES; rp[N_NODES] = N_EDGES; }
}

__global__ void __launch_bounds__(256) k_p3(const int* __restrict__ src,
                                            const int* __restrict__ dst,
                                            const int* __restrict__ excT,
                                            const int* __restrict__ bbase,
                                            unsigned int* __restrict__ packed) {
    __shared__ int cur[NB];
    int blk = blockIdx.x;
    for (int i = threadIdx.x; i < NB; i += 256)
        cur[i] = bbase[i] + excT[i * NBLK + blk];
    __syncthreads();
    int base = blk * EPB;
    for (int i = threadIdx.x; i < EPB; i += 256) {
        int d = dst[base + i];
        int pos = atomicAdd(&cur[d >> 7], 1);    // LDS atomic
        packed[pos] = ((unsigned)(d & 127) << 17) | (unsigned)src[base + i];
    }
}

__global__ void __launch_bounds__(256) k_p4(const unsigned int* __restrict__ packed,
                                            const int* __restrict__ bbase,
                                            int* __restrict__ rp,
                                            int* __restrict__ srcs) {
    __shared__ int hist[NPB + 1];
    __shared__ int stage[CAP];
    int b = blockIdx.x, t = threadIdx.x;
    int lo = bbase[b], hi = bbase[b + 1];
    int n_e = hi - lo;
    if (t < NPB + 1) hist[t] = 0;
    __syncthreads();
    for (int i = t; i < n_e; i += 256)
        atomicAdd(&hist[(packed[lo + i] >> 17) + 1], 1);
    __syncthreads();
    for (int off = 1; off < NPB + 1; off <<= 1) {
        int u = 0;
        if (t < NPB + 1 && t >= off) u = hist[t - off];
        __syncthreads();
        if (t < NPB + 1 && t >= off) hist[t] += u;
        __syncthreads();
    }
    int nbase = b * NPB;
    if (t < NPB && nbase + t < N_NODES) rp[nbase + t] = lo + hist[t];
    __syncthreads();
    if (n_e <= CAP) {
        for (int i = t; i < n_e; i += 256) {
            unsigned v = packed[lo + i];
            int pos = atomicAdd(&hist[v >> 17], 1);
            stage[pos] = (int)(v & 0x1FFFFu);
        }
        __syncthreads();
        for (int i = t; i < n_e; i += 256) srcs[lo + i] = stage[i];
    } else {
        for (int i = t; i < n_e; i += 256) {
            unsigned v = packed[lo + i];
            int pos = atomicAdd(&hist[v >> 17], 1);
            srcs[lo + pos] = (int)(v & 0x1FFFFu);
        }
    }
}

// ============ pad x[N][5] -> x8[N][8] ======================================

__global__ void k_pad(const float* __restrict__ x, float* __restrict__ x8) {
    int i = blockIdx.x * blockDim.x + threadIdx.x;
    int stride = gridDim.x * blockDim.x;
    for (; i < N_NODES * 8; i += stride) {
        int n = i >> 3, j = i & 7;
        x8[i] = (j < 5) ? x[n * 5 + j] : 0.f;
    }
}

// ============ graph boundaries from sorted batch ===========================

__global__ void k_bounds(const int* __restrict__ batch, int* __restrict__ gstart,
                         int* __restrict__ gend) {
    int i = blockIdx.x * blockDim.x + threadIdx.x;
    if (i >= N_NODES) return;
    int g = batch[i];
    if (i == 0 || batch[i - 1] != g) atomicMin(&gstart[g], i);
    if (i == N_NODES - 1 || batch[i + 1] != g) atomicMax(&gend[g], i + 1);
}

// ============ weight pre-pack: f32 W[64][64] -> split-bf16 B-fragments ======

__global__ void k_wconv(const float* __restrict__ W, unsigned short* __restrict__ pack) {
    int i = blockIdx.x * blockDim.x + threadIdx.x;
    if (i >= 4096) return;
    int j    = i & 7;
    int lane = (i >> 3) & 63;
    int t    = (i >> 9) & 3;
    int ks   = (i >> 11) & 1;
    int k   = ks * 32 + (lane >> 4) * 8 + j;
    int col = t * 16 + (lane & 15);
    float w = W[k * HID + col];
    unsigned b = __float_as_uint(w);
    unsigned short hiw = (unsigned short)(b >> 16);
    float lf = w - __uint_as_float(b & 0xFFFF0000u);
    unsigned short low = (unsigned short)(__float_as_uint(lf) >> 16);
    pack[(((ks * 4 + t)) * 64 + lane) * 8 + j]   = hiw;
    pack[((8 + ks * 4 + t) * 64 + lane) * 8 + j] = low;
}

__device__ __forceinline__ void split8(const float* v, bf16x8& hi, bf16x8& lo) {
#pragma unroll
    for (int j = 0; j < 8; ++j) {
        unsigned b = __float_as_uint(v[j]);
        hi[j] = (short)(b >> 16);
        float lf = v[j] - __uint_as_float(b & 0xFFFF0000u);
        lo[j] = (short)(__float_as_uint(lf) >> 16);
    }
}

// ============ k_g1: gather(x8) + MLP-A (5->64) -> t1 ========================
// 4 nodes/wave, 16-lane groups; lane fq: half=fq>>3 picks edge parity,
// f=fq&7 picks feature. 8 edges per group-iter, 4 independent loads per lane.

__global__ void __launch_bounds__(512) k_g1(
    const float* __restrict__ x8, const int* __restrict__ rp,
    const int* __restrict__ srcs, const float* __restrict__ W1a,
    const float* __restrict__ b1a, float* __restrict__ t1) {
    __shared__ float sWa[5 * HID];
    __shared__ float sba[HID];
    for (int i = threadIdx.x; i < 5 * HID; i += 512) sWa[i] = W1a[i];
    if (threadIdx.x < HID) sba[threadIdx.x] = b1a[threadIdx.x];
    __syncthreads();

    int wave = (blockIdx.x * 512 + threadIdx.x) >> 6;
    int lane = threadIdx.x & 63;
    int grp = lane >> 4, fq = lane & 15;
    int half = fq >> 3, f = fq & 7;
    int n = wave * 4 + grp;
    int e0 = rp[n], e1 = rp[n + 1];

    float a = 0.f;
    int e = e0;
    for (; e + 8 <= e1; e += 8) {
        int i0 = e + half;
        int s0 = srcs[i0], s1 = srcs[i0 + 2], s2 = srcs[i0 + 4], s3 = srcs[i0 + 6];
        float v0 = x8[(size_t)s0 * 8 + f];
        float v1 = x8[(size_t)s1 * 8 + f];
        float v2 = x8[(size_t)s2 * 8 + f];
        float v3 = x8[(size_t)s3 * 8 + f];
        a += (v0 + v1) + (v2 + v3);
    }
    for (; e < e1; e += 2) {
        int i = e + half;
        if (i < e1) a += x8[(size_t)srcs[i] * 8 + f];
    }
    a += __shfl_xor(a, 8, 16);

    float zf[5];
#pragma unroll
    for (int ff = 0; ff < 5; ++ff)
        zf[ff] = __shfl(a, ff, 16) + x8[(size_t)n * 8 + ff];

    float4 t = *reinterpret_cast<const float4*>(&sba[fq * 4]);
#pragma unroll
    for (int ff = 0; ff < 5; ++ff) {
        const float4 w = *reinterpret_cast<const float4*>(&sWa[ff * HID + fq * 4]);
        t.x += zf[ff] * w.x; t.y += zf[ff] * w.y;
        t.z += zf[ff] * w.z; t.w += zf[ff] * w.w;
    }
    t.x = fmaxf(t.x, 0.f); t.y = fmaxf(t.y, 0.f);
    t.z = fmaxf(t.z, 0.f); t.w = fmaxf(t.w, 0.f);
    *reinterpret_cast<float4*>(t1 + (size_t)n * HID + fq * 4) = t;
}

// ============ k_mm1: h1 = relu(t1 @ W1b + b1b), split-bf16 MFMA =============

__global__ void __launch_bounds__(256) k_mm1(
    const float* __restrict__ t1, const unsigned short* __restrict__ packB,
    const float* __restrict__ bias, float* __restrict__ h1) {
    int wave = threadIdx.x >> 6, lane = threadIdx.x & 63;
    int q = lane >> 4;
    int n0 = blockIdx.x * 64 + wave * 16;
    int arow = n0 + (lane & 15);
    if (arow >= N_NODES) arow = N_NODES - 1;
    const float* ar = t1 + (size_t)arow * HID + q * 8;
    alignas(16) float a0[8], a1[8];
    *reinterpret_cast<float4*>(a0)     = *reinterpret_cast<const float4*>(ar);
    *reinterpret_cast<float4*>(a0 + 4) = *reinterpret_cast<const float4*>(ar + 4);
    *reinterpret_cast<float4*>(a1)     = *reinterpret_cast<const float4*>(ar + 32);
    *reinterpret_cast<float4*>(a1 + 4) = *reinterpret_cast<const float4*>(ar + 36);
    bf16x8 Ah0, Al0, Ah1, Al1;
    split8(a0, Ah0, Al0);
    split8(a1, Ah1, Al1);
    const bf16x8* bp = reinterpret_cast<const bf16x8*>(packB);
#pragma unroll
    for (int t = 0; t < 4; ++t) {
        bf16x8 Bh0 = bp[(t) * 64 + lane];
        bf16x8 Bh1 = bp[(4 + t) * 64 + lane];
        bf16x8 Bl0 = bp[(8 + t) * 64 + lane];
        bf16x8 Bl1 = bp[(12 + t) * 64 + lane];
        f32x4 acc = {0.f, 0.f, 0.f, 0.f};
        acc = __builtin_amdgcn_mfma_f32_16x16x32_bf16(Ah0, Bh0, acc, 0, 0, 0);
        acc = __builtin_amdgcn_mfma_f32_16x16x32_bf16(Ah1, Bh1, acc, 0, 0, 0);
        acc = __builtin_amdgcn_mfma_f32_16x16x32_bf16(Al0, Bh0, acc, 0, 0, 0);
        acc = __builtin_amdgcn_mfma_f32_16x16x32_bf16(Al1, Bh1, acc, 0, 0, 0);
        acc = __builtin_amdgcn_mfma_f32_16x16x32_bf16(Ah0, Bl0, acc, 0, 0, 0);
        acc = __builtin_amdgcn_mfma_f32_16x16x32_bf16(Ah1, Bl1, acc, 0, 0, 0);
        acc = __builtin_amdgcn_mfma_f32_16x16x32_bf16(Al0, Bl0, acc, 0, 0, 0);
        acc = __builtin_amdgcn_mfma_f32_16x16x32_bf16(Al1, Bl1, acc, 0, 0, 0);
        int col = (lane & 15) + 16 * t;
        float bv = bias[col];
#pragma unroll
        for (int r = 0; r < 4; ++r) {
            int node = n0 + q * 4 + r;
            if (node < N_NODES)
                h1[(size_t)node * HID + col] = fmaxf(acc[r] + bv, 0.f);
        }
    }
}

// ============ k_g2: z2 = h1 + sum_neighbors(h1), 8-deep ILP =================

__global__ void __launch_bounds__(512) k_g2(
    const float* __restrict__ h1, const int* __restrict__ rp,
    const int* __restrict__ srcs, float* __restrict__ z2) {
    int wave = (blockIdx.x * 512 + threadIdx.x) >> 6;
    int lane = threadIdx.x & 63;
    int grp = lane >> 4, fq = lane & 15;
    int n = wave * 4 + grp;
    int e0 = rp[n], e1 = rp[n + 1];

    const float4* __restrict__ H = reinterpret_cast<const float4*>(h1);
    float4 z = H[(size_t)n * 16 + fq];

    int e = e0;
    for (; e + 8 <= e1; e += 8) {
        int s0 = srcs[e],     s1 = srcs[e + 1], s2 = srcs[e + 2], s3 = srcs[e + 3];
        int s4 = srcs[e + 4], s5 = srcs[e + 5], s6 = srcs[e + 6], s7 = srcs[e + 7];
        float4 v0 = H[(size_t)s0 * 16 + fq];
        float4 v1 = H[(size_t)s1 * 16 + fq];
        float4 v2 = H[(size_t)s2 * 16 + fq];
        float4 v3 = H[(size_t)s3 * 16 + fq];
        float4 v4 = H[(size_t)s4 * 16 + fq];
        float4 v5 = H[(size_t)s5 * 16 + fq];
        float4 v6 = H[(size_t)s6 * 16 + fq];
        float4 v7 = H[(size_t)s7 * 16 + fq];
        z.x += ((v0.x + v1.x) + (v2.x + v3.x)) + ((v4.x + v5.x) + (v6.x + v7.x));
        z.y += ((v0.y + v1.y) + (v2.y + v3.y)) + ((v4.y + v5.y) + (v6.y + v7.y));
        z.z += ((v0.z + v1.z) + (v2.z + v3.z)) + ((v4.z + v5.z) + (v6.z + v7.z));
        z.w += ((v0.w + v1.w) + (v2.w + v3.w)) + ((v4.w + v5.w) + (v6.w + v7.w));
    }
    for (; e < e1; ++e) {
        float4 v = H[(size_t)srcs[e] * 16 + fq];
        z.x += v.x; z.y += v.y; z.z += v.z; z.w += v.w;
    }
    *reinterpret_cast<float4*>(z2 + (size_t)n * HID + fq * 4) = z;
}

// ============ k_mm2: u = relu(relu(z2@W2a+b2a)@W2b+b2b) -> u_out (dense) ====

__global__ void __launch_bounds__(256) k_mm2(
    const float* __restrict__ z2, const unsigned short* __restrict__ packA,
    const unsigned short* __restrict__ packB, const float* __restrict__ b2a,
    const float* __restrict__ b2b, float* __restrict__ u_out) {
    __shared__ __align__(16) float tm[4][16][68];
    int wave = threadIdx.x >> 6, lane = threadIdx.x & 63;
    int q = lane >> 4;
    int n0 = blockIdx.x * 64 + wave * 16;
    int arow = n0 + (lane & 15);
    if (arow >= N_NODES) arow = N_NODES - 1;

    {   // GEMV1: t = relu(z2 @ W2a + b2a) -> tm
        const float* ar = z2 + (size_t)arow * HID + q * 8;
        alignas(16) float a0[8], a1[8];
        *reinterpret_cast<float4*>(a0)     = *reinterpret_cast<const float4*>(ar);
        *reinterpret_cast<float4*>(a0 + 4) = *reinterpret_cast<const float4*>(ar + 4);
        *reinterpret_cast<float4*>(a1)     = *reinterpret_cast<const float4*>(ar + 32);
        *reinterpret_cast<float4*>(a1 + 4) = *reinterpret_cast<const float4*>(ar + 36);
        bf16x8 Ah0, Al0, Ah1, Al1;
        split8(a0, Ah0, Al0);
        split8(a1, Ah1, Al1);
        const bf16x8* bp = reinterpret_cast<const bf16x8*>(packA);
#pragma unroll
        for (int t = 0; t < 4; ++t) {
            bf16x8 Bh0 = bp[(t) * 64 + lane];
            bf16x8 Bh1 = bp[(4 + t) * 64 + lane];
            bf16x8 Bl0 = bp[(8 + t) * 64 + lane];
            bf16x8 Bl1 = bp[(12 + t) * 64 + lane];
            f32x4 acc = {0.f, 0.f, 0.f, 0.f};
            acc = __builtin_amdgcn_mfma_f32_16x16x32_bf16(Ah0, Bh0, acc, 0, 0, 0);
            acc = __builtin_amdgcn_mfma_f32_16x16x32_bf16(Ah1, Bh1, acc, 0, 0, 0);
            acc = __builtin_amdgcn_mfma_f32_16x16x32_bf16(Al0, Bh0, acc, 0, 0, 0);
            acc = __builtin_amdgcn_mfma_f32_16x16x32_bf16(Al1, Bh1, acc, 0, 0, 0);
            acc = __builtin_amdgcn_mfma_f32_16x16x32_bf16(Ah0, Bl0, acc, 0, 0, 0);
            acc = __builtin_amdgcn_mfma_f32_16x16x32_bf16(Ah1, Bl1, acc, 0, 0, 0);
            acc = __builtin_amdgcn_mfma_f32_16x16x32_bf16(Al0, Bl0, acc, 0, 0, 0);
            acc = __builtin_amdgcn_mfma_f32_16x16x32_bf16(Al1, Bl1, acc, 0, 0, 0);
            int col = (lane & 15) + 16 * t;
            float bv = b2a[col];
#pragma unroll
            for (int r = 0; r < 4; ++r)
                tm[wave][q * 4 + r][col] = fmaxf(acc[r] + bv, 0.f);
        }
    }

    // GEMV2: u = relu(t @ W2b + b2b) -> u_out (dense store, no atomics)
    const float* tr = &tm[wave][lane & 15][0];
    alignas(16) float c0[8], c1[8];
    *reinterpret_cast<float4*>(c0)     = *reinterpret_cast<const float4*>(tr + q * 8);
    *reinterpret_cast<float4*>(c0 + 4) = *reinterpret_cast<const float4*>(tr + q * 8 + 4);
    *reinterpret_cast<float4*>(c1)     = *reinterpret_cast<const float4*>(tr + 32 + q * 8);
    *reinterpret_cast<float4*>(c1 + 4) = *reinterpret_cast<const float4*>(tr + 36 + q * 8);
    bf16x8 Ch0, Cl0, Ch1, Cl1;
    split8(c0, Ch0, Cl0);
    split8(c1, Ch1, Cl1);

    const bf16x8* bp = reinterpret_cast<const bf16x8*>(packB);
#pragma unroll
    for (int t = 0; t < 4; ++t) {
        bf16x8 Bh0 = bp[(t) * 64 + lane];
        bf16x8 Bh1 = bp[(4 + t) * 64 + lane];
        bf16x8 Bl0 = bp[(8 + t) * 64 + lane];
        bf16x8 Bl1 = bp[(12 + t) * 64 + lane];
        f32x4 acc = {0.f, 0.f, 0.f, 0.f};
        acc = __builtin_amdgcn_mfma_f32_16x16x32_bf16(Ch0, Bh0, acc, 0, 0, 0);
        acc = __builtin_amdgcn_mfma_f32_16x16x32_bf16(Ch1, Bh1, acc, 0, 0, 0);
        acc = __builtin_amdgcn_mfma_f32_16x16x32_bf16(Cl0, Bh0, acc, 0, 0, 0);
        acc = __builtin_amdgcn_mfma_f32_16x16x32_bf16(Cl1, Bh1, acc, 0, 0, 0);
        acc = __builtin_amdgcn_mfma_f32_16x16x32_bf16(Ch0, Bl0, acc, 0, 0, 0);
        acc = __builtin_amdgcn_mfma_f32_16x16x32_bf16(Ch1, Bl1, acc, 0, 0, 0);
        acc = __builtin_amdgcn_mfma_f32_16x16x32_bf16(Cl0, Bl0, acc, 0, 0, 0);
        acc = __builtin_amdgcn_mfma_f32_16x16x32_bf16(Cl1, Bl1, acc, 0, 0, 0);
        int col = (lane & 15) + 16 * t;
        float bv = b2b[col];
#pragma unroll
        for (int r = 0; r < 4; ++r) {
            int node = n0 + q * 4 + r;
            if (node < N_NODES)
                u_out[(size_t)node * HID + col] = fmaxf(acc[r] + bv, 0.f);
        }
    }
}

// ============ k_final2: segmented mean pool + classifier ====================

__global__ void __launch_bounds__(256) k_final2(
    const float* __restrict__ u, const int* __restrict__ gstart,
    const int* __restrict__ gend, const float* __restrict__ Wc,
    const float* __restrict__ bc, float* __restrict__ out) {
    __shared__ float red[4][64];
    int g = blockIdx.x, t = threadIdx.x;
    int col = t & 63, ch = t >> 6;
    int s = gstart[g], e = gend[g];
    float acc = 0.f;
    for (int i = s + ch; i < e; i += 4)
        acc += u[(size_t)i * HID + col];
    red[ch][col] = acc;
    __syncthreads();
    if (t < 64) {
        float p = red[0][t] + red[1][t] + red[2][t] + red[3][t];
        float count = (float)(e - s);
        p /= fmaxf(count, 1.0f);
        float r0 = p * Wc[t * 2 + 0];
        float r1 = p * Wc[t * 2 + 1];
#pragma unroll
        for (int m = 1; m < 64; m <<= 1) {
            r0 += __shfl_xor(r0, m, 64);
            r1 += __shfl_xor(r1, m, 64);
        }
        if (t == 0) {
            out[g * 2 + 0] = r0 + bc[0];
            out[g * 2 + 1] = r1 + bc[1];
        }
    }
}

// ============ launch ========================================================

extern "C" void kernel_launch(void* const* d_in, const int* in_sizes, int n_in,
                              void* d_out, int out_size, void* d_ws, size_t ws_size,
                              hipStream_t stream) {
    const float* x   = (const float*)d_in[0];
    const int* ei    = (const int*)d_in[1];
    const int* batch = (const int*)d_in[2];
    const float* W1a = (const float*)d_in[3];
    const float* b1a = (const float*)d_in[4];
    const float* W1b = (const float*)d_in[5];
    const float* b1b = (const float*)d_in[6];
    const float* W2a = (const float*)d_in[7];
    const float* b2a = (const float*)d_in[8];
    const float* W2b = (const float*)d_in[9];
    const float* b2b = (const float*)d_in[10];
    const float* Wc  = (const float*)d_in[11];
    const float* bc  = (const float*)d_in[12];
    float* out = (float*)d_out;

    const int* src = ei;
    const int* dst = ei + N_EDGES;

    char* ws = (char*)d_ws;
    size_t off = 0;
    auto alloc = [&](size_t bytes) {
        char* p = ws + off;
        off += (bytes + 127) & ~size_t(127);
        return p;
    };
    int*   rp    = (int*)alloc((N_NODES + 1) * sizeof(int));
    int*   srcs  = (int*)alloc((size_t)N_EDGES * sizeof(int));
    float* h1    = (float*)alloc((size_t)N_NODES * HID * sizeof(float));
    float* t1    = (float*)alloc((size_t)N_NODES * HID * sizeof(float));  // also u_out
    float* z2    = (float*)alloc((size_t)N_NODES * HID * sizeof(float));
    float* x8    = (float*)alloc((size_t)N_NODES * 8 * sizeof(float));
    int*   btot  = (int*)alloc(NB * sizeof(int));
    int*   bbase = (int*)alloc((NB + 1) * sizeof(int));
    int*   gstart= (int*)alloc(N_GRAPHS * sizeof(int));
    int*   gend  = (int*)alloc(N_GRAPHS * sizeof(int));
    unsigned short* pk1b = (unsigned short*)alloc(8192 * sizeof(unsigned short));
    unsigned short* pk2a = (unsigned short*)alloc(8192 * sizeof(unsigned short));
    unsigned short* pk2b = (unsigned short*)alloc(8192 * sizeof(unsigned short));

    // aliases: dead before their hosts are written
    int* bcnt = (int*)h1;                       // cnt[NBLK][NB]
    int* excT = (int*)h1 + NBLK * NB;           // excT[NB][NBLK]
    unsigned int* packed = (unsigned int*)z2;   // 12.8 MB

    hipMemsetAsync(gstart, 0x7F, N_GRAPHS * sizeof(int), stream);  // large sentinel
    hipMemsetAsync(gend, 0, N_GRAPHS * sizeof(int), stream);

    // CSR build (atomic-free at global scope) + prep
    k_p1 <<<NBLK, 256, 0, stream>>>(dst, bcnt);
    k_pad<<<1024, 256, 0, stream>>>(x, x8);
    k_bounds<<<(N_NODES + 255) / 256, 256, 0, stream>>>(batch, gstart, gend);
    k_wconv<<<16, 256, 0, stream>>>(W1b, pk1b);
    k_wconv<<<16, 256, 0, stream>>>(W2a, pk2a);
    k_wconv<<<16, 256, 0, stream>>>(W2b, pk2b);
    k_p2 <<<NB, 256, 0, stream>>>(bcnt, excT, btot);
    k_p2b<<<1, 1024, 0, stream>>>(btot, bbase, rp);
    k_p3 <<<NBLK, 256, 0, stream>>>(src, dst, excT, bbase, packed);
    k_p4 <<<NB, 256, 0, stream>>>(packed, bbase, rp, srcs);

    int gblocks = N_NODES / 32;              // 3125 (4 nodes/wave, 8 waves/block)
    int mblocks = (N_NODES + 63) / 64;       // 1563 (16 nodes/wave, 4 waves/block)

    k_g1 <<<gblocks, 512, 0, stream>>>(x8, rp, srcs, W1a, b1a, t1);
    k_mm1<<<mblocks, 256, 0, stream>>>(t1, pk1b, b1b, h1);
    k_g2 <<<gblocks, 512, 0, stream>>>(h1, rp, srcs, z2);
    k_mm2<<<mblocks, 256, 0, stream>>>(z2, pk2a, pk2b, b2a, b2b, t1);  // u -> t1

    k_final2<<<N_GRAPHS, 256, 0, stream>>>(t1, gstart, gend, Wc, bc, out);
}

// Round 10
// 315.166 us; speedup vs baseline: 3.1729x; 1.2062x over previous
//
#include <hip/hip_runtime.h>

#define N_NODES   100000
#define N_EDGES   3200000
#define N_GRAPHS  1024
#define HID       64

#define NPB   128                          // nodes per bucket (dst >> 7)
#define NB    782                          // ceil(100000/128)
#define NBLK  256                          // blocks in p1/p3
#define EPB   (N_EDGES / NBLK)             // 12500 edges per block (exact)
#define CAP   6144                         // srcs staging per bucket

using bf16x8 = __attribute__((ext_vector_type(8))) short;
using f32x4  = __attribute__((ext_vector_type(4))) float;
using f16x4  = __attribute__((ext_vector_type(4))) _Float16;

// ============ bucketed CSR build (no global atomics, coalesced writes) ======

__global__ void __launch_bounds__(256) k_p1(const int* __restrict__ dst,
                                            int* __restrict__ cnt) {   // cnt[NBLK][NB]
    __shared__ int h[NB];
    for (int i = threadIdx.x; i < NB; i += 256) h[i] = 0;
    __syncthreads();
    int base = blockIdx.x * EPB;
    for (int i = threadIdx.x; i < EPB; i += 256)
        atomicAdd(&h[dst[base + i] >> 7], 1);
    __syncthreads();
    for (int i = threadIdx.x; i < NB; i += 256)
        cnt[blockIdx.x * NB + i] = h[i];
}

__global__ void __launch_bounds__(256) k_p2(const int* __restrict__ cnt,
                                            int* __restrict__ excT,
                                            int* __restrict__ btot) {
    __shared__ int wsum[4];
    int b = blockIdx.x, t = threadIdx.x;
    int v = cnt[t * NB + b];
    int incl = v;
#pragma unroll
    for (int off = 1; off < 64; off <<= 1) {
        int u = __shfl_up(incl, off, 64);
        if ((t & 63) >= off) incl += u;
    }
    if ((t & 63) == 63) wsum[t >> 6] = incl;
    __syncthreads();
    int woff = 0;
    for (int w = 0; w < (t >> 6); ++w) woff += wsum[w];
    excT[b * NBLK + t] = woff + incl - v;
    if (t == 255) btot[b] = woff + incl;
}

__global__ void __launch_bounds__(1024) k_p2b(const int* __restrict__ btot,
                                              int* __restrict__ bbase,
                                              int* __restrict__ rp) {
    __shared__ int s[1024];
    int t = threadIdx.x;
    int v = (t < NB) ? btot[t] : 0;
    s[t] = v;
    __syncthreads();
    for (int off = 1; off < 1024; off <<= 1) {
        int u = (t >= off) ? s[t - off] : 0;
        __syncthreads();
        s[t] += u;
        __syncthreads();
    }
    if (t < NB) bbase[t] = s[t] - v;
    if (t == 0) { bbase[NB] = N_EDGES; rp[N_NODES] = N_EDGES; }
}

__global__ void __launch_bounds__(256) k_p3(const int* __restrict__ src,
                                            const int* __restrict__ dst,
                                            const int* __restrict__ excT,
                                            const int* __restrict__ bbase,
                                            unsigned int* __restrict__ packed) {
    __shared__ int cur[NB];
    int blk = blockIdx.x;
    for (int i = threadIdx.x; i < NB; i += 256)
        cur[i] = bbase[i] + excT[i * NBLK + blk];
    __syncthreads();
    int base = blk * EPB;
    for (int i = threadIdx.x; i < EPB; i += 256) {
        int d = dst[base + i];
        int pos = atomicAdd(&cur[d >> 7], 1);    // LDS atomic
        packed[pos] = ((unsigned)(d & 127) << 17) | (unsigned)src[base + i];
    }
}

__global__ void __launch_bounds__(256) k_p4(const unsigned int* __restrict__ packed,
                                            const int* __restrict__ bbase,
                                            int* __restrict__ rp,
                                            int* __restrict__ srcs) {
    __shared__ int hist[NPB + 1];
    __shared__ int stage[CAP];
    int b = blockIdx.x, t = threadIdx.x;
    int lo = bbase[b], hi = bbase[b + 1];
    int n_e = hi - lo;
    if (t < NPB + 1) hist[t] = 0;
    __syncthreads();
    for (int i = t; i < n_e; i += 256)
        atomicAdd(&hist[(packed[lo + i] >> 17) + 1], 1);
    __syncthreads();
    for (int off = 1; off < NPB + 1; off <<= 1) {
        int u = 0;
        if (t < NPB + 1 && t >= off) u = hist[t - off];
        __syncthreads();
        if (t < NPB + 1 && t >= off) hist[t] += u;
        __syncthreads();
    }
    int nbase = b * NPB;
    if (t < NPB && nbase + t < N_NODES) rp[nbase + t] = lo + hist[t];
    __syncthreads();
    if (n_e <= CAP) {
        for (int i = t; i < n_e; i += 256) {
            unsigned v = packed[lo + i];
            int pos = atomicAdd(&hist[v >> 17], 1);
            stage[pos] = (int)(v & 0x1FFFFu);
        }
        __syncthreads();
        for (int i = t; i < n_e; i += 256) srcs[lo + i] = stage[i];
    } else {
        for (int i = t; i < n_e; i += 256) {
            unsigned v = packed[lo + i];
            int pos = atomicAdd(&hist[v >> 17], 1);
            srcs[lo + pos] = (int)(v & 0x1FFFFu);
        }
    }
}

// ============ fused pad x->x8 + graph bounds ================================

__global__ void __launch_bounds__(256) k_padb(
    const float* __restrict__ x, float* __restrict__ x8,
    const int* __restrict__ batch, int* __restrict__ gstart,
    int* __restrict__ gend) {
    int i = blockIdx.x * 256 + threadIdx.x;      // grid covers N_NODES*8 exactly
    if (i < N_NODES * 8) {
        int n = i >> 3, j = i & 7;
        x8[i] = (j < 5) ? x[n * 5 + j] : 0.f;
    }
    if (i < N_NODES) {
        int g = batch[i];
        if (i == 0 || batch[i - 1] != g) atomicMin(&gstart[g], i);
        if (i == N_NODES - 1 || batch[i + 1] != g) atomicMax(&gend[g], i + 1);
    }
}

// ============ weight pre-pack (3 matrices in one launch) ====================

__global__ void k_wconv3(const float* __restrict__ Wa, const float* __restrict__ Wb,
                         const float* __restrict__ Wc_,
                         unsigned short* __restrict__ pa, unsigned short* __restrict__ pb,
                         unsigned short* __restrict__ pc) {
    int which = blockIdx.x >> 4;
    const float* W = (which == 0) ? Wa : (which == 1) ? Wb : Wc_;
    unsigned short* pack = (which == 0) ? pa : (which == 1) ? pb : pc;
    int i = (blockIdx.x & 15) * 256 + threadIdx.x;
    if (i >= 4096) return;
    int j    = i & 7;
    int lane = (i >> 3) & 63;
    int t    = (i >> 9) & 3;
    int ks   = (i >> 11) & 1;
    int k   = ks * 32 + (lane >> 4) * 8 + j;
    int col = t * 16 + (lane & 15);
    float w = W[k * HID + col];
    unsigned b = __float_as_uint(w);
    unsigned short hiw = (unsigned short)(b >> 16);
    float lf = w - __uint_as_float(b & 0xFFFF0000u);
    unsigned short low = (unsigned short)(__float_as_uint(lf) >> 16);
    pack[(((ks * 4 + t)) * 64 + lane) * 8 + j]   = hiw;
    pack[((8 + ks * 4 + t) * 64 + lane) * 8 + j] = low;
}

__device__ __forceinline__ void split8(const float* v, bf16x8& hi, bf16x8& lo) {
#pragma unroll
    for (int j = 0; j < 8; ++j) {
        unsigned b = __float_as_uint(v[j]);
        hi[j] = (short)(b >> 16);
        float lf = v[j] - __uint_as_float(b & 0xFFFF0000u);
        lo[j] = (short)(__float_as_uint(lf) >> 16);
    }
}

// ============ k_g1: gather(x8) + MLP-A (5->64) -> t1 ========================

__global__ void __launch_bounds__(512) k_g1(
    const float* __restrict__ x8, const int* __restrict__ rp,
    const int* __restrict__ srcs, const float* __restrict__ W1a,
    const float* __restrict__ b1a, float* __restrict__ t1) {
    __shared__ float sWa[5 * HID];
    __shared__ float sba[HID];
    for (int i = threadIdx.x; i < 5 * HID; i += 512) sWa[i] = W1a[i];
    if (threadIdx.x < HID) sba[threadIdx.x] = b1a[threadIdx.x];
    __syncthreads();

    int wave = (blockIdx.x * 512 + threadIdx.x) >> 6;
    int lane = threadIdx.x & 63;
    int grp = lane >> 4, fq = lane & 15;
    int half = fq >> 3, f = fq & 7;
    int n = wave * 4 + grp;
    int e0 = rp[n], e1 = rp[n + 1];

    float a = 0.f;
    int e = e0;
    for (; e + 8 <= e1; e += 8) {
        int i0 = e + half;
        int s0 = srcs[i0], s1 = srcs[i0 + 2], s2 = srcs[i0 + 4], s3 = srcs[i0 + 6];
        float v0 = x8[(size_t)s0 * 8 + f];
        float v1 = x8[(size_t)s1 * 8 + f];
        float v2 = x8[(size_t)s2 * 8 + f];
        float v3 = x8[(size_t)s3 * 8 + f];
        a += (v0 + v1) + (v2 + v3);
    }
    for (; e < e1; e += 2) {
        int i = e + half;
        if (i < e1) a += x8[(size_t)srcs[i] * 8 + f];
    }
    a += __shfl_xor(a, 8, 16);

    float zf[5];
#pragma unroll
    for (int ff = 0; ff < 5; ++ff)
        zf[ff] = __shfl(a, ff, 16) + x8[(size_t)n * 8 + ff];

    float4 t = *reinterpret_cast<const float4*>(&sba[fq * 4]);
#pragma unroll
    for (int ff = 0; ff < 5; ++ff) {
        const float4 w = *reinterpret_cast<const float4*>(&sWa[ff * HID + fq * 4]);
        t.x += zf[ff] * w.x; t.y += zf[ff] * w.y;
        t.z += zf[ff] * w.z; t.w += zf[ff] * w.w;
    }
    t.x = fmaxf(t.x, 0.f); t.y = fmaxf(t.y, 0.f);
    t.z = fmaxf(t.z, 0.f); t.w = fmaxf(t.w, 0.f);
    *reinterpret_cast<float4*>(t1 + (size_t)n * HID + fq * 4) = t;
}

// ============ k_mm1: h1(fp16) = relu(t1 @ W1b + b1b), split-bf16 MFMA =======

__global__ void __launch_bounds__(256) k_mm1(
    const float* __restrict__ t1, const unsigned short* __restrict__ packB,
    const float* __restrict__ bias, _Float16* __restrict__ h1h) {
    int wave = threadIdx.x >> 6, lane = threadIdx.x & 63;
    int q = lane >> 4;
    int n0 = blockIdx.x * 64 + wave * 16;
    int arow = n0 + (lane & 15);
    if (arow >= N_NODES) arow = N_NODES - 1;
    const float* ar = t1 + (size_t)arow * HID + q * 8;
    alignas(16) float a0[8], a1[8];
    *reinterpret_cast<float4*>(a0)     = *reinterpret_cast<const float4*>(ar);
    *reinterpret_cast<float4*>(a0 + 4) = *reinterpret_cast<const float4*>(ar + 4);
    *reinterpret_cast<float4*>(a1)     = *reinterpret_cast<const float4*>(ar + 32);
    *reinterpret_cast<float4*>(a1 + 4) = *reinterpret_cast<const float4*>(ar + 36);
    bf16x8 Ah0, Al0, Ah1, Al1;
    split8(a0, Ah0, Al0);
    split8(a1, Ah1, Al1);
    const bf16x8* bp = reinterpret_cast<const bf16x8*>(packB);
#pragma unroll
    for (int t = 0; t < 4; ++t) {
        bf16x8 Bh0 = bp[(t) * 64 + lane];
        bf16x8 Bh1 = bp[(4 + t) * 64 + lane];
        bf16x8 Bl0 = bp[(8 + t) * 64 + lane];
        bf16x8 Bl1 = bp[(12 + t) * 64 + lane];
        f32x4 acc = {0.f, 0.f, 0.f, 0.f};
        acc = __builtin_amdgcn_mfma_f32_16x16x32_bf16(Ah0, Bh0, acc, 0, 0, 0);
        acc = __builtin_amdgcn_mfma_f32_16x16x32_bf16(Ah1, Bh1, acc, 0, 0, 0);
        acc = __builtin_amdgcn_mfma_f32_16x16x32_bf16(Al0, Bh0, acc, 0, 0, 0);
        acc = __builtin_amdgcn_mfma_f32_16x16x32_bf16(Al1, Bh1, acc, 0, 0, 0);
        acc = __builtin_amdgcn_mfma_f32_16x16x32_bf16(Ah0, Bl0, acc, 0, 0, 0);
        acc = __builtin_amdgcn_mfma_f32_16x16x32_bf16(Ah1, Bl1, acc, 0, 0, 0);
        acc = __builtin_amdgcn_mfma_f32_16x16x32_bf16(Al0, Bl0, acc, 0, 0, 0);
        acc = __builtin_amdgcn_mfma_f32_16x16x32_bf16(Al1, Bl1, acc, 0, 0, 0);
        int col = (lane & 15) + 16 * t;
        float bv = bias[col];
#pragma unroll
        for (int r = 0; r < 4; ++r) {
            int node = n0 + q * 4 + r;
            if (node < N_NODES)
                h1h[(size_t)node * HID + col] = (_Float16)fmaxf(acc[r] + bv, 0.f);
        }
    }
}

// ============ k_g2: z2 = h1 + sum_neighbors(h1), fp16 gather, 8-deep ILP ====

__device__ __forceinline__ void acc4(float4& z, f16x4 r) {
    z.x += (float)r.x; z.y += (float)r.y; z.z += (float)r.z; z.w += (float)r.w;
}

__global__ void __launch_bounds__(512) k_g2(
    const _Float16* __restrict__ h1h, const int* __restrict__ rp,
    const int* __restrict__ srcs, float* __restrict__ z2) {
    int wave = (blockIdx.x * 512 + threadIdx.x) >> 6;
    int lane = threadIdx.x & 63;
    int grp = lane >> 4, fq = lane & 15;
    int n = wave * 4 + grp;
    int e0 = rp[n], e1 = rp[n + 1];

    const f16x4* __restrict__ H = reinterpret_cast<const f16x4*>(h1h);
    f16x4 rs = H[(size_t)n * 16 + fq];
    float4 z = {(float)rs.x, (float)rs.y, (float)rs.z, (float)rs.w};

    int e = e0;
    for (; e + 8 <= e1; e += 8) {
        int s0 = srcs[e],     s1 = srcs[e + 1], s2 = srcs[e + 2], s3 = srcs[e + 3];
        int s4 = srcs[e + 4], s5 = srcs[e + 5], s6 = srcs[e + 6], s7 = srcs[e + 7];
        f16x4 v0 = H[(size_t)s0 * 16 + fq];
        f16x4 v1 = H[(size_t)s1 * 16 + fq];
        f16x4 v2 = H[(size_t)s2 * 16 + fq];
        f16x4 v3 = H[(size_t)s3 * 16 + fq];
        f16x4 v4 = H[(size_t)s4 * 16 + fq];
        f16x4 v5 = H[(size_t)s5 * 16 + fq];
        f16x4 v6 = H[(size_t)s6 * 16 + fq];
        f16x4 v7 = H[(size_t)s7 * 16 + fq];
        acc4(z, v0); acc4(z, v1); acc4(z, v2); acc4(z, v3);
        acc4(z, v4); acc4(z, v5); acc4(z, v6); acc4(z, v7);
    }
    for (; e < e1; ++e) {
        f16x4 v = H[(size_t)srcs[e] * 16 + fq];
        acc4(z, v);
    }
    *reinterpret_cast<float4*>(z2 + (size_t)n * HID + fq * 4) = z;
}

// ============ k_mm2: u = relu(relu(z2@W2a+b2a)@W2b+b2b) -> u_out (dense) ====

__global__ void __launch_bounds__(256) k_mm2(
    const float* __restrict__ z2, const unsigned short* __restrict__ packA,
    const unsigned short* __restrict__ packB, const float* __restrict__ b2a,
    const float* __restrict__ b2b, float* __restrict__ u_out) {
    __shared__ __align__(16) float tm[4][16][68];
    int wave = threadIdx.x >> 6, lane = threadIdx.x & 63;
    int q = lane >> 4;
    int n0 = blockIdx.x * 64 + wave * 16;
    int arow = n0 + (lane & 15);
    if (arow >= N_NODES) arow = N_NODES - 1;

    {   // GEMV1: t = relu(z2 @ W2a + b2a) -> tm
        const float* ar = z2 + (size_t)arow * HID + q * 8;
        alignas(16) float a0[8], a1[8];
        *reinterpret_cast<float4*>(a0)     = *reinterpret_cast<const float4*>(ar);
        *reinterpret_cast<float4*>(a0 + 4) = *reinterpret_cast<const float4*>(ar + 4);
        *reinterpret_cast<float4*>(a1)     = *reinterpret_cast<const float4*>(ar + 32);
        *reinterpret_cast<float4*>(a1 + 4) = *reinterpret_cast<const float4*>(ar + 36);
        bf16x8 Ah0, Al0, Ah1, Al1;
        split8(a0, Ah0, Al0);
        split8(a1, Ah1, Al1);
        const bf16x8* bp = reinterpret_cast<const bf16x8*>(packA);
#pragma unroll
        for (int t = 0; t < 4; ++t) {
            bf16x8 Bh0 = bp[(t) * 64 + lane];
            bf16x8 Bh1 = bp[(4 + t) * 64 + lane];
            bf16x8 Bl0 = bp[(8 + t) * 64 + lane];
            bf16x8 Bl1 = bp[(12 + t) * 64 + lane];
            f32x4 acc = {0.f, 0.f, 0.f, 0.f};
            acc = __builtin_amdgcn_mfma_f32_16x16x32_bf16(Ah0, Bh0, acc, 0, 0, 0);
            acc = __builtin_amdgcn_mfma_f32_16x16x32_bf16(Ah1, Bh1, acc, 0, 0, 0);
            acc = __builtin_amdgcn_mfma_f32_16x16x32_bf16(Al0, Bh0, acc, 0, 0, 0);
            acc = __builtin_amdgcn_mfma_f32_16x16x32_bf16(Al1, Bh1, acc, 0, 0, 0);
            acc = __builtin_amdgcn_mfma_f32_16x16x32_bf16(Ah0, Bl0, acc, 0, 0, 0);
            acc = __builtin_amdgcn_mfma_f32_16x16x32_bf16(Ah1, Bl1, acc, 0, 0, 0);
            acc = __builtin_amdgcn_mfma_f32_16x16x32_bf16(Al0, Bl0, acc, 0, 0, 0);
            acc = __builtin_amdgcn_mfma_f32_16x16x32_bf16(Al1, Bl1, acc, 0, 0, 0);
            int col = (lane & 15) + 16 * t;
            float bv = b2a[col];
#pragma unroll
            for (int r = 0; r < 4; ++r)
                tm[wave][q * 4 + r][col] = fmaxf(acc[r] + bv, 0.f);
        }
    }

    // GEMV2: u = relu(t @ W2b + b2b) -> u_out (dense store, no atomics)
    const float* tr = &tm[wave][lane & 15][0];
    alignas(16) float c0[8], c1[8];
    *reinterpret_cast<float4*>(c0)     = *reinterpret_cast<const float4*>(tr + q * 8);
    *reinterpret_cast<float4*>(c0 + 4) = *reinterpret_cast<const float4*>(tr + q * 8 + 4);
    *reinterpret_cast<float4*>(c1)     = *reinterpret_cast<const float4*>(tr + 32 + q * 8);
    *reinterpret_cast<float4*>(c1 + 4) = *reinterpret_cast<const float4*>(tr + 36 + q * 8);
    bf16x8 Ch0, Cl0, Ch1, Cl1;
    split8(c0, Ch0, Cl0);
    split8(c1, Ch1, Cl1);

    const bf16x8* bp = reinterpret_cast<const bf16x8*>(packB);
#pragma unroll
    for (int t = 0; t < 4; ++t) {
        bf16x8 Bh0 = bp[(t) * 64 + lane];
        bf16x8 Bh1 = bp[(4 + t) * 64 + lane];
        bf16x8 Bl0 = bp[(8 + t) * 64 + lane];
        bf16x8 Bl1 = bp[(12 + t) * 64 + lane];
        f32x4 acc = {0.f, 0.f, 0.f, 0.f};
        acc = __builtin_amdgcn_mfma_f32_16x16x32_bf16(Ch0, Bh0, acc, 0, 0, 0);
        acc = __builtin_amdgcn_mfma_f32_16x16x32_bf16(Ch1, Bh1, acc, 0, 0, 0);
        acc = __builtin_amdgcn_mfma_f32_16x16x32_bf16(Cl0, Bh0, acc, 0, 0, 0);
        acc = __builtin_amdgcn_mfma_f32_16x16x32_bf16(Cl1, Bh1, acc, 0, 0, 0);
        acc = __builtin_amdgcn_mfma_f32_16x16x32_bf16(Ch0, Bl0, acc, 0, 0, 0);
        acc = __builtin_amdgcn_mfma_f32_16x16x32_bf16(Ch1, Bl1, acc, 0, 0, 0);
        acc = __builtin_amdgcn_mfma_f32_16x16x32_bf16(Cl0, Bl0, acc, 0, 0, 0);
        acc = __builtin_amdgcn_mfma_f32_16x16x32_bf16(Cl1, Bl1, acc, 0, 0, 0);
        int col = (lane & 15) + 16 * t;
        float bv = b2b[col];
#pragma unroll
        for (int r = 0; r < 4; ++r) {
            int node = n0 + q * 4 + r;
            if (node < N_NODES)
                u_out[(size_t)node * HID + col] = fmaxf(acc[r] + bv, 0.f);
        }
    }
}

// ============ k_final2: segmented mean pool + classifier ====================

__global__ void __launch_bounds__(256) k_final2(
    const float* __restrict__ u, const int* __restrict__ gstart,
    const int* __restrict__ gend, const float* __restrict__ Wc,
    const float* __restrict__ bc, float* __restrict__ out) {
    __shared__ float red[4][64];
    int g = blockIdx.x, t = threadIdx.x;
    int col = t & 63, ch = t >> 6;
    int s = gstart[g], e = gend[g];
    float acc = 0.f;
    for (int i = s + ch; i < e; i += 4)
        acc += u[(size_t)i * HID + col];
    red[ch][col] = acc;
    __syncthreads();
    if (t < 64) {
        float p = red[0][t] + red[1][t] + red[2][t] + red[3][t];
        float count = (float)(e - s);
        p /= fmaxf(count, 1.0f);
        float r0 = p * Wc[t * 2 + 0];
        float r1 = p * Wc[t * 2 + 1];
#pragma unroll
        for (int m = 1; m < 64; m <<= 1) {
            r0 += __shfl_xor(r0, m, 64);
            r1 += __shfl_xor(r1, m, 64);
        }
        if (t == 0) {
            out[g * 2 + 0] = r0 + bc[0];
            out[g * 2 + 1] = r1 + bc[1];
        }
    }
}

// ============ launch ========================================================

extern "C" void kernel_launch(void* const* d_in, const int* in_sizes, int n_in,
                              void* d_out, int out_size, void* d_ws, size_t ws_size,
                              hipStream_t stream) {
    const float* x   = (const float*)d_in[0];
    const int* ei    = (const int*)d_in[1];
    const int* batch = (const int*)d_in[2];
    const float* W1a = (const float*)d_in[3];
    const float* b1a = (const float*)d_in[4];
    const float* W1b = (const float*)d_in[5];
    const float* b1b = (const float*)d_in[6];
    const float* W2a = (const float*)d_in[7];
    const float* b2a = (const float*)d_in[8];
    const float* W2b = (const float*)d_in[9];
    const float* b2b = (const float*)d_in[10];
    const float* Wc  = (const float*)d_in[11];
    const float* bc  = (const float*)d_in[12];
    float* out = (float*)d_out;

    const int* src = ei;
    const int* dst = ei + N_EDGES;

    char* ws = (char*)d_ws;
    size_t off = 0;
    auto alloc = [&](size_t bytes) {
        char* p = ws + off;
        off += (bytes + 127) & ~size_t(127);
        return p;
    };
    int*   rp    = (int*)alloc((N_NODES + 1) * sizeof(int));
    int*   srcs  = (int*)alloc((size_t)N_EDGES * sizeof(int));
    _Float16* h1h = (_Float16*)alloc((size_t)N_NODES * HID * sizeof(_Float16));
    float* t1    = (float*)alloc((size_t)N_NODES * HID * sizeof(float));  // also u_out
    float* z2    = (float*)alloc((size_t)N_NODES * HID * sizeof(float));
    float* x8    = (float*)alloc((size_t)N_NODES * 8 * sizeof(float));
    int*   btot  = (int*)alloc(NB * sizeof(int));
    int*   bbase = (int*)alloc((NB + 1) * sizeof(int));
    int*   gstart= (int*)alloc(N_GRAPHS * sizeof(int));
    int*   gend  = (int*)alloc(N_GRAPHS * sizeof(int));
    unsigned short* pk1b = (unsigned short*)alloc(8192 * sizeof(unsigned short));
    unsigned short* pk2a = (unsigned short*)alloc(8192 * sizeof(unsigned short));
    unsigned short* pk2b = (unsigned short*)alloc(8192 * sizeof(unsigned short));

    // aliases: dead before their hosts are written
    int* bcnt = (int*)t1;                       // cnt[NBLK][NB]  (t1 written later)
    int* excT = (int*)t1 + NBLK * NB;           // excT[NB][NBLK]
    unsigned int* packed = (unsigned int*)z2;   // 12.8 MB (z2 written later)

    hipMemsetAsync(gstart, 0x7F, N_GRAPHS * sizeof(int), stream);  // large sentinel
    hipMemsetAsync(gend, 0, N_GRAPHS * sizeof(int), stream);

    // CSR build (atomic-free at global scope) + prep
    k_p1 <<<NBLK, 256, 0, stream>>>(dst, bcnt);
    k_padb<<<(N_NODES * 8) / 256, 256, 0, stream>>>(x, x8, batch, gstart, gend);
    k_wconv3<<<48, 256, 0, stream>>>(W1b, W2a, W2b, pk1b, pk2a, pk2b);
    k_p2 <<<NB, 256, 0, stream>>>(bcnt, excT, btot);
    k_p2b<<<1, 1024, 0, stream>>>(btot, bbase, rp);
    k_p3 <<<NBLK, 256, 0, stream>>>(src, dst, excT, bbase, packed);
    k_p4 <<<NB, 256, 0, stream>>>(packed, bbase, rp, srcs);

    int gblocks = N_NODES / 32;              // 3125 (4 nodes/wave, 8 waves/block)
    int mblocks = (N_NODES + 63) / 64;       // 1563 (16 nodes/wave, 4 waves/block)

    k_g1 <<<gblocks, 512, 0, stream>>>(x8, rp, srcs, W1a, b1a, t1);
    k_mm1<<<mblocks, 256, 0, stream>>>(t1, pk1b, b1b, h1h);
    k_g2 <<<gblocks, 512, 0, stream>>>(h1h, rp, srcs, z2);
    k_mm2<<<mblocks, 256, 0, stream>>>(z2, pk2a, pk2b, b2a, b2b, t1);  // u -> t1

    k_final2<<<N_GRAPHS, 256, 0, stream>>>(t1, gstart, gend, Wc, bc, out);
}

// Round 11
// 294.815 us; speedup vs baseline: 3.3920x; 1.0690x over previous
//
#include <hip/hip_runtime.h>

#define N_NODES   100000
#define N_EDGES   3200000
#define N_GRAPHS  1024
#define HID       64

#define NPB   128                          // nodes per bucket (dst >> 7)
#define NB    782                          // ceil(100000/128)
#define NBLK  1024                         // blocks in p1/p3
#define EPB   (N_EDGES / NBLK)             // 3125 edges per block (exact)
#define CAP   6144                         // srcs staging per bucket

using bf16x8 = __attribute__((ext_vector_type(8))) short;
using f32x4  = __attribute__((ext_vector_type(4))) float;
using f16x4  = __attribute__((ext_vector_type(4))) _Float16;

// ============ bucketed CSR build (no global atomics, coalesced writes) ======

__global__ void __launch_bounds__(256) k_p1(const int* __restrict__ dst,
                                            int* __restrict__ cnt) {   // cnt[NBLK][NB]
    __shared__ int h[NB];
    for (int i = threadIdx.x; i < NB; i += 256) h[i] = 0;
    __syncthreads();
    int base = blockIdx.x * EPB;
    for (int i = threadIdx.x; i < EPB; i += 256)
        atomicAdd(&h[dst[base + i] >> 7], 1);
    __syncthreads();
    for (int i = threadIdx.x; i < NB; i += 256)
        cnt[blockIdx.x * NB + i] = h[i];
}

// per-bucket exclusive scan across the 1024 blocks -> excT[b][blk]; totals -> btot
__global__ void __launch_bounds__(1024) k_p2(const int* __restrict__ cnt,
                                             int* __restrict__ excT,
                                             int* __restrict__ btot) {
    __shared__ int wsum[16];
    int b = blockIdx.x, t = threadIdx.x;
    int v = cnt[t * NB + b];
    int incl = v;
#pragma unroll
    for (int off = 1; off < 64; off <<= 1) {
        int u = __shfl_up(incl, off, 64);
        if ((t & 63) >= off) incl += u;
    }
    if ((t & 63) == 63) wsum[t >> 6] = incl;
    __syncthreads();
    int woff = 0;
    for (int w = 0; w < (t >> 6); ++w) woff += wsum[w];
    excT[b * NBLK + t] = woff + incl - v;
    if (t == 1023) btot[b] = woff + incl;
}

__global__ void __launch_bounds__(1024) k_p2b(const int* __restrict__ btot,
                                              int* __restrict__ bbase,
                                              int* __restrict__ rp) {
    __shared__ int s[1024];
    int t = threadIdx.x;
    int v = (t < NB) ? btot[t] : 0;
    s[t] = v;
    __syncthreads();
    for (int off = 1; off < 1024; off <<= 1) {
        int u = (t >= off) ? s[t - off] : 0;
        __syncthreads();
        s[t] += u;
        __syncthreads();
    }
    if (t < NB) bbase[t] = s[t] - v;
    if (t == 0) { bbase[NB] = N_EDGES; rp[N_NODES] = N_EDGES; }
}

// scatter packed (loc7|src17) into bucket-grouped order; LDS cursors only
__global__ void __launch_bounds__(256) k_p3(const int* __restrict__ src,
                                            const int* __restrict__ dst,
                                            const int* __restrict__ excT,
                                            const int* __restrict__ bbase,
                                            unsigned int* __restrict__ packed) {
    __shared__ int cur[NB];
    int blk = blockIdx.x;
    for (int i = threadIdx.x; i < NB; i += 256)
        cur[i] = bbase[i] + excT[i * NBLK + blk];
    __syncthreads();
    int base = blk * EPB;
    for (int i = threadIdx.x; i < EPB; i += 256) {
        int d = dst[base + i];
        int pos = atomicAdd(&cur[d >> 7], 1);    // LDS atomic
        packed[pos] = ((unsigned)(d & 127) << 17) | (unsigned)src[base + i];
    }
}

// per-bucket fine CSR: LDS hist over 128 nodes, LDS-staged coalesced srcs dump
__global__ void __launch_bounds__(512) k_p4(const unsigned int* __restrict__ packed,
                                            const int* __restrict__ bbase,
                                            int* __restrict__ rp,
                                            int* __restrict__ srcs) {
    __shared__ int hist[NPB + 1];
    __shared__ int stage[CAP];
    int b = blockIdx.x, t = threadIdx.x;
    int lo = bbase[b], hi = bbase[b + 1];
    int n_e = hi - lo;
    if (t < NPB + 1) hist[t] = 0;
    __syncthreads();
    for (int i = t; i < n_e; i += 512)
        atomicAdd(&hist[(packed[lo + i] >> 17) + 1], 1);
    __syncthreads();
    for (int off = 1; off < NPB + 1; off <<= 1) {       // Hillis-Steele scan
        int u = 0;
        if (t < NPB + 1 && t >= off) u = hist[t - off];
        __syncthreads();
        if (t < NPB + 1 && t >= off) hist[t] += u;
        __syncthreads();
    }
    int nbase = b * NPB;
    if (t < NPB && nbase + t < N_NODES) rp[nbase + t] = lo + hist[t];
    __syncthreads();
    if (n_e <= CAP) {
        for (int i = t; i < n_e; i += 512) {
            unsigned v = packed[lo + i];
            int pos = atomicAdd(&hist[v >> 17], 1);
            stage[pos] = (int)(v & 0x1FFFFu);
        }
        __syncthreads();
        for (int i = t; i < n_e; i += 512) srcs[lo + i] = stage[i];
    } else {
        for (int i = t; i < n_e; i += 512) {
            unsigned v = packed[lo + i];
            int pos = atomicAdd(&hist[v >> 17], 1);
            srcs[lo + pos] = (int)(v & 0x1FFFFu);
        }
    }
}

// ============ fused pad x->x8 + graph bounds ================================

__global__ void __launch_bounds__(256) k_padb(
    const float* __restrict__ x, float* __restrict__ x8,
    const int* __restrict__ batch, int* __restrict__ gstart,
    int* __restrict__ gend) {
    int i = blockIdx.x * 256 + threadIdx.x;      // grid covers N_NODES*8 exactly
    if (i < N_NODES * 8) {
        int n = i >> 3, j = i & 7;
        x8[i] = (j < 5) ? x[n * 5 + j] : 0.f;
    }
    if (i < N_NODES) {
        int g = batch[i];
        if (i == 0 || batch[i - 1] != g) atomicMin(&gstart[g], i);
        if (i == N_NODES - 1 || batch[i + 1] != g) atomicMax(&gend[g], i + 1);
    }
}

// ============ weight pre-pack (3 matrices in one launch) ====================

__global__ void k_wconv3(const float* __restrict__ Wa, const float* __restrict__ Wb,
                         const float* __restrict__ Wc_,
                         unsigned short* __restrict__ pa, unsigned short* __restrict__ pb,
                         unsigned short* __restrict__ pc) {
    int which = blockIdx.x >> 4;
    const float* W = (which == 0) ? Wa : (which == 1) ? Wb : Wc_;
    unsigned short* pack = (which == 0) ? pa : (which == 1) ? pb : pc;
    int i = (blockIdx.x & 15) * 256 + threadIdx.x;
    if (i >= 4096) return;
    int j    = i & 7;
    int lane = (i >> 3) & 63;
    int t    = (i >> 9) & 3;
    int ks   = (i >> 11) & 1;
    int k   = ks * 32 + (lane >> 4) * 8 + j;
    int col = t * 16 + (lane & 15);
    float w = W[k * HID + col];
    unsigned b = __float_as_uint(w);
    unsigned short hiw = (unsigned short)(b >> 16);
    float lf = w - __uint_as_float(b & 0xFFFF0000u);
    unsigned short low = (unsigned short)(__float_as_uint(lf) >> 16);
    pack[(((ks * 4 + t)) * 64 + lane) * 8 + j]   = hiw;
    pack[((8 + ks * 4 + t) * 64 + lane) * 8 + j] = low;
}

__device__ __forceinline__ void split8(const float* v, bf16x8& hi, bf16x8& lo) {
#pragma unroll
    for (int j = 0; j < 8; ++j) {
        unsigned b = __float_as_uint(v[j]);
        hi[j] = (short)(b >> 16);
        float lf = v[j] - __uint_as_float(b & 0xFFFF0000u);
        lo[j] = (short)(__float_as_uint(lf) >> 16);
    }
}

// ============ k_g1: gather(x8) + MLP-A (5->64) -> t1 ========================

__global__ void __launch_bounds__(512) k_g1(
    const float* __restrict__ x8, const int* __restrict__ rp,
    const int* __restrict__ srcs, const float* __restrict__ W1a,
    const float* __restrict__ b1a, float* __restrict__ t1) {
    __shared__ float sWa[5 * HID];
    __shared__ float sba[HID];
    for (int i = threadIdx.x; i < 5 * HID; i += 512) sWa[i] = W1a[i];
    if (threadIdx.x < HID) sba[threadIdx.x] = b1a[threadIdx.x];
    __syncthreads();

    int wave = (blockIdx.x * 512 + threadIdx.x) >> 6;
    int lane = threadIdx.x & 63;
    int grp = lane >> 4, fq = lane & 15;
    int half = fq >> 3, f = fq & 7;
    int n = wave * 4 + grp;
    int e0 = rp[n], e1 = rp[n + 1];

    float a = 0.f;
    int e = e0;
    for (; e + 8 <= e1; e += 8) {
        int i0 = e + half;
        int s0 = srcs[i0], s1 = srcs[i0 + 2], s2 = srcs[i0 + 4], s3 = srcs[i0 + 6];
        float v0 = x8[(size_t)s0 * 8 + f];
        float v1 = x8[(size_t)s1 * 8 + f];
        float v2 = x8[(size_t)s2 * 8 + f];
        float v3 = x8[(size_t)s3 * 8 + f];
        a += (v0 + v1) + (v2 + v3);
    }
    for (; e < e1; e += 2) {
        int i = e + half;
        if (i < e1) a += x8[(size_t)srcs[i] * 8 + f];
    }
    a += __shfl_xor(a, 8, 16);

    float zf[5];
#pragma unroll
    for (int ff = 0; ff < 5; ++ff)
        zf[ff] = __shfl(a, ff, 16) + x8[(size_t)n * 8 + ff];

    float4 t = *reinterpret_cast<const float4*>(&sba[fq * 4]);
#pragma unroll
    for (int ff = 0; ff < 5; ++ff) {
        const float4 w = *reinterpret_cast<const float4*>(&sWa[ff * HID + fq * 4]);
        t.x += zf[ff] * w.x; t.y += zf[ff] * w.y;
        t.z += zf[ff] * w.z; t.w += zf[ff] * w.w;
    }
    t.x = fmaxf(t.x, 0.f); t.y = fmaxf(t.y, 0.f);
    t.z = fmaxf(t.z, 0.f); t.w = fmaxf(t.w, 0.f);
    *reinterpret_cast<float4*>(t1 + (size_t)n * HID + fq * 4) = t;
}

// ============ k_mm1: h1(fp16) = relu(t1 @ W1b + b1b), split-bf16 MFMA =======

__global__ void __launch_bounds__(256) k_mm1(
    const float* __restrict__ t1, const unsigned short* __restrict__ packB,
    const float* __restrict__ bias, _Float16* __restrict__ h1h) {
    int wave = threadIdx.x >> 6, lane = threadIdx.x & 63;
    int q = lane >> 4;
    int n0 = blockIdx.x * 64 + wave * 16;
    int arow = n0 + (lane & 15);
    if (arow >= N_NODES) arow = N_NODES - 1;
    const float* ar = t1 + (size_t)arow * HID + q * 8;
    alignas(16) float a0[8], a1[8];
    *reinterpret_cast<float4*>(a0)     = *reinterpret_cast<const float4*>(ar);
    *reinterpret_cast<float4*>(a0 + 4) = *reinterpret_cast<const float4*>(ar + 4);
    *reinterpret_cast<float4*>(a1)     = *reinterpret_cast<const float4*>(ar + 32);
    *reinterpret_cast<float4*>(a1 + 4) = *reinterpret_cast<const float4*>(ar + 36);
    bf16x8 Ah0, Al0, Ah1, Al1;
    split8(a0, Ah0, Al0);
    split8(a1, Ah1, Al1);
    const bf16x8* bp = reinterpret_cast<const bf16x8*>(packB);
#pragma unroll
    for (int t = 0; t < 4; ++t) {
        bf16x8 Bh0 = bp[(t) * 64 + lane];
        bf16x8 Bh1 = bp[(4 + t) * 64 + lane];
        bf16x8 Bl0 = bp[(8 + t) * 64 + lane];
        bf16x8 Bl1 = bp[(12 + t) * 64 + lane];
        f32x4 acc = {0.f, 0.f, 0.f, 0.f};
        acc = __builtin_amdgcn_mfma_f32_16x16x32_bf16(Ah0, Bh0, acc, 0, 0, 0);
        acc = __builtin_amdgcn_mfma_f32_16x16x32_bf16(Ah1, Bh1, acc, 0, 0, 0);
        acc = __builtin_amdgcn_mfma_f32_16x16x32_bf16(Al0, Bh0, acc, 0, 0, 0);
        acc = __builtin_amdgcn_mfma_f32_16x16x32_bf16(Al1, Bh1, acc, 0, 0, 0);
        acc = __builtin_amdgcn_mfma_f32_16x16x32_bf16(Ah0, Bl0, acc, 0, 0, 0);
        acc = __builtin_amdgcn_mfma_f32_16x16x32_bf16(Ah1, Bl1, acc, 0, 0, 0);
        acc = __builtin_amdgcn_mfma_f32_16x16x32_bf16(Al0, Bl0, acc, 0, 0, 0);
        acc = __builtin_amdgcn_mfma_f32_16x16x32_bf16(Al1, Bl1, acc, 0, 0, 0);
        int col = (lane & 15) + 16 * t;
        float bv = bias[col];
#pragma unroll
        for (int r = 0; r < 4; ++r) {
            int node = n0 + q * 4 + r;
            if (node < N_NODES)
                h1h[(size_t)node * HID + col] = (_Float16)fmaxf(acc[r] + bv, 0.f);
        }
    }
}

// ============ k_g2: z2 = h1 + sum_neighbors(h1), fp16 gather, 8-deep ILP ====

__device__ __forceinline__ void acc4(float4& z, f16x4 r) {
    z.x += (float)r.x; z.y += (float)r.y; z.z += (float)r.z; z.w += (float)r.w;
}

__global__ void __launch_bounds__(512) k_g2(
    const _Float16* __restrict__ h1h, const int* __restrict__ rp,
    const int* __restrict__ srcs, float* __restrict__ z2) {
    int wave = (blockIdx.x * 512 + threadIdx.x) >> 6;
    int lane = threadIdx.x & 63;
    int grp = lane >> 4, fq = lane & 15;
    int n = wave * 4 + grp;
    int e0 = rp[n], e1 = rp[n + 1];

    const f16x4* __restrict__ H = reinterpret_cast<const f16x4*>(h1h);
    f16x4 rs = H[(size_t)n * 16 + fq];
    float4 z = {(float)rs.x, (float)rs.y, (float)rs.z, (float)rs.w};

    int e = e0;
    for (; e + 8 <= e1; e += 8) {
        int s0 = srcs[e],     s1 = srcs[e + 1], s2 = srcs[e + 2], s3 = srcs[e + 3];
        int s4 = srcs[e + 4], s5 = srcs[e + 5], s6 = srcs[e + 6], s7 = srcs[e + 7];
        f16x4 v0 = H[(size_t)s0 * 16 + fq];
        f16x4 v1 = H[(size_t)s1 * 16 + fq];
        f16x4 v2 = H[(size_t)s2 * 16 + fq];
        f16x4 v3 = H[(size_t)s3 * 16 + fq];
        f16x4 v4 = H[(size_t)s4 * 16 + fq];
        f16x4 v5 = H[(size_t)s5 * 16 + fq];
        f16x4 v6 = H[(size_t)s6 * 16 + fq];
        f16x4 v7 = H[(size_t)s7 * 16 + fq];
        acc4(z, v0); acc4(z, v1); acc4(z, v2); acc4(z, v3);
        acc4(z, v4); acc4(z, v5); acc4(z, v6); acc4(z, v7);
    }
    for (; e < e1; ++e) {
        f16x4 v = H[(size_t)srcs[e] * 16 + fq];
        acc4(z, v);
    }
    *reinterpret_cast<float4*>(z2 + (size_t)n * HID + fq * 4) = z;
}

// ============ k_mm2: u = relu(relu(z2@W2a+b2a)@W2b+b2b) -> u_out (dense) ====

__global__ void __launch_bounds__(256) k_mm2(
    const float* __restrict__ z2, const unsigned short* __restrict__ packA,
    const unsigned short* __restrict__ packB, const float* __restrict__ b2a,
    const float* __restrict__ b2b, float* __restrict__ u_out) {
    __shared__ __align__(16) float tm[4][16][68];
    int wave = threadIdx.x >> 6, lane = threadIdx.x & 63;
    int q = lane >> 4;
    int n0 = blockIdx.x * 64 + wave * 16;
    int arow = n0 + (lane & 15);
    if (arow >= N_NODES) arow = N_NODES - 1;

    {   // GEMV1: t = relu(z2 @ W2a + b2a) -> tm
        const float* ar = z2 + (size_t)arow * HID + q * 8;
        alignas(16) float a0[8], a1[8];
        *reinterpret_cast<float4*>(a0)     = *reinterpret_cast<const float4*>(ar);
        *reinterpret_cast<float4*>(a0 + 4) = *reinterpret_cast<const float4*>(ar + 4);
        *reinterpret_cast<float4*>(a1)     = *reinterpret_cast<const float4*>(ar + 32);
        *reinterpret_cast<float4*>(a1 + 4) = *reinterpret_cast<const float4*>(ar + 36);
        bf16x8 Ah0, Al0, Ah1, Al1;
        split8(a0, Ah0, Al0);
        split8(a1, Ah1, Al1);
        const bf16x8* bp = reinterpret_cast<const bf16x8*>(packA);
#pragma unroll
        for (int t = 0; t < 4; ++t) {
            bf16x8 Bh0 = bp[(t) * 64 + lane];
            bf16x8 Bh1 = bp[(4 + t) * 64 + lane];
            bf16x8 Bl0 = bp[(8 + t) * 64 + lane];
            bf16x8 Bl1 = bp[(12 + t) * 64 + lane];
            f32x4 acc = {0.f, 0.f, 0.f, 0.f};
            acc = __builtin_amdgcn_mfma_f32_16x16x32_bf16(Ah0, Bh0, acc, 0, 0, 0);
            acc = __builtin_amdgcn_mfma_f32_16x16x32_bf16(Ah1, Bh1, acc, 0, 0, 0);
            acc = __builtin_amdgcn_mfma_f32_16x16x32_bf16(Al0, Bh0, acc, 0, 0, 0);
            acc = __builtin_amdgcn_mfma_f32_16x16x32_bf16(Al1, Bh1, acc, 0, 0, 0);
            acc = __builtin_amdgcn_mfma_f32_16x16x32_bf16(Ah0, Bl0, acc, 0, 0, 0);
            acc = __builtin_amdgcn_mfma_f32_16x16x32_bf16(Ah1, Bl1, acc, 0, 0, 0);
            acc = __builtin_amdgcn_mfma_f32_16x16x32_bf16(Al0, Bl0, acc, 0, 0, 0);
            acc = __builtin_amdgcn_mfma_f32_16x16x32_bf16(Al1, Bl1, acc, 0, 0, 0);
            int col = (lane & 15) + 16 * t;
            float bv = b2a[col];
#pragma unroll
            for (int r = 0; r < 4; ++r)
                tm[wave][q * 4 + r][col] = fmaxf(acc[r] + bv, 0.f);
        }
    }

    // GEMV2: u = relu(t @ W2b + b2b) -> u_out (dense store, no atomics)
    const float* tr = &tm[wave][lane & 15][0];
    alignas(16) float c0[8], c1[8];
    *reinterpret_cast<float4*>(c0)     = *reinterpret_cast<const float4*>(tr + q * 8);
    *reinterpret_cast<float4*>(c0 + 4) = *reinterpret_cast<const float4*>(tr + q * 8 + 4);
    *reinterpret_cast<float4*>(c1)     = *reinterpret_cast<const float4*>(tr + 32 + q * 8);
    *reinterpret_cast<float4*>(c1 + 4) = *reinterpret_cast<const float4*>(tr + 36 + q * 8);
    bf16x8 Ch0, Cl0, Ch1, Cl1;
    split8(c0, Ch0, Cl0);
    split8(c1, Ch1, Cl1);

    const bf16x8* bp = reinterpret_cast<const bf16x8*>(packB);
#pragma unroll
    for (int t = 0; t < 4; ++t) {
        bf16x8 Bh0 = bp[(t) * 64 + lane];
        bf16x8 Bh1 = bp[(4 + t) * 64 + lane];
        bf16x8 Bl0 = bp[(8 + t) * 64 + lane];
        bf16x8 Bl1 = bp[(12 + t) * 64 + lane];
        f32x4 acc = {0.f, 0.f, 0.f, 0.f};
        acc = __builtin_amdgcn_mfma_f32_16x16x32_bf16(Ch0, Bh0, acc, 0, 0, 0);
        acc = __builtin_amdgcn_mfma_f32_16x16x32_bf16(Ch1, Bh1, acc, 0, 0, 0);
        acc = __builtin_amdgcn_mfma_f32_16x16x32_bf16(Cl0, Bh0, acc, 0, 0, 0);
        acc = __builtin_amdgcn_mfma_f32_16x16x32_bf16(Cl1, Bh1, acc, 0, 0, 0);
        acc = __builtin_amdgcn_mfma_f32_16x16x32_bf16(Ch0, Bl0, acc, 0, 0, 0);
        acc = __builtin_amdgcn_mfma_f32_16x16x32_bf16(Ch1, Bl1, acc, 0, 0, 0);
        acc = __builtin_amdgcn_mfma_f32_16x16x32_bf16(Cl0, Bl0, acc, 0, 0, 0);
        acc = __builtin_amdgcn_mfma_f32_16x16x32_bf16(Cl1, Bl1, acc, 0, 0, 0);
        int col = (lane & 15) + 16 * t;
        float bv = b2b[col];
#pragma unroll
        for (int r = 0; r < 4; ++r) {
            int node = n0 + q * 4 + r;
            if (node < N_NODES)
                u_out[(size_t)node * HID + col] = fmaxf(acc[r] + bv, 0.f);
        }
    }
}

// ============ k_final2: segmented mean pool + classifier ====================

__global__ void __launch_bounds__(256) k_final2(
    const float* __restrict__ u, const int* __restrict__ gstart,
    const int* __restrict__ gend, const float* __restrict__ Wc,
    const float* __restrict__ bc, float* __restrict__ out) {
    __shared__ float red[4][64];
    int g = blockIdx.x, t = threadIdx.x;
    int col = t & 63, ch = t >> 6;
    int s = gstart[g], e = gend[g];
    float acc = 0.f;
    for (int i = s + ch; i < e; i += 4)
        acc += u[(size_t)i * HID + col];
    red[ch][col] = acc;
    __syncthreads();
    if (t < 64) {
        float p = red[0][t] + red[1][t] + red[2][t] + red[3][t];
        float count = (float)(e - s);
        p /= fmaxf(count, 1.0f);
        float r0 = p * Wc[t * 2 + 0];
        float r1 = p * Wc[t * 2 + 1];
#pragma unroll
        for (int m = 1; m < 64; m <<= 1) {
            r0 += __shfl_xor(r0, m, 64);
            r1 += __shfl_xor(r1, m, 64);
        }
        if (t == 0) {
            out[g * 2 + 0] = r0 + bc[0];
            out[g * 2 + 1] = r1 + bc[1];
        }
    }
}

// ============ launch ========================================================

extern "C" void kernel_launch(void* const* d_in, const int* in_sizes, int n_in,
                              void* d_out, int out_size, void* d_ws, size_t ws_size,
                              hipStream_t stream) {
    const float* x   = (const float*)d_in[0];
    const int* ei    = (const int*)d_in[1];
    const int* batch = (const int*)d_in[2];
    const float* W1a = (const float*)d_in[3];
    const float* b1a = (const float*)d_in[4];
    const float* W1b = (const float*)d_in[5];
    const float* b1b = (const float*)d_in[6];
    const float* W2a = (const float*)d_in[7];
    const float* b2a = (const float*)d_in[8];
    const float* W2b = (const float*)d_in[9];
    const float* b2b = (const float*)d_in[10];
    const float* Wc  = (const float*)d_in[11];
    const float* bc  = (const float*)d_in[12];
    float* out = (float*)d_out;

    const int* src = ei;
    const int* dst = ei + N_EDGES;

    char* ws = (char*)d_ws;
    size_t off = 0;
    auto alloc = [&](size_t bytes) {
        char* p = ws + off;
        off += (bytes + 127) & ~size_t(127);
        return p;
    };
    int*   rp    = (int*)alloc((N_NODES + 1) * sizeof(int));
    int*   srcs  = (int*)alloc((size_t)N_EDGES * sizeof(int));
    _Float16* h1h = (_Float16*)alloc((size_t)N_NODES * HID * sizeof(_Float16));
    float* t1    = (float*)alloc((size_t)N_NODES * HID * sizeof(float));  // also u_out
    float* z2    = (float*)alloc((size_t)N_NODES * HID * sizeof(float));
    float* x8    = (float*)alloc((size_t)N_NODES * 8 * sizeof(float));
    int*   btot  = (int*)alloc(NB * sizeof(int));
    int*   bbase = (int*)alloc((NB + 1) * sizeof(int));
    int*   gstart= (int*)alloc(N_GRAPHS * sizeof(int));
    int*   gend  = (int*)alloc(N_GRAPHS * sizeof(int));
    unsigned short* pk1b = (unsigned short*)alloc(8192 * sizeof(unsigned short));
    unsigned short* pk2a = (unsigned short*)alloc(8192 * sizeof(unsigned short));
    unsigned short* pk2b = (unsigned short*)alloc(8192 * sizeof(unsigned short));

    // aliases: dead before their hosts are written
    int* bcnt = (int*)t1;                       // cnt[NBLK][NB]  3.2 MB (t1 written later)
    int* excT = (int*)t1 + NBLK * NB;           // excT[NB][NBLK] 3.2 MB
    unsigned int* packed = (unsigned int*)z2;   // 12.8 MB (z2 written later)

    hipMemsetAsync(gstart, 0x7F, N_GRAPHS * sizeof(int), stream);  // large sentinel
    hipMemsetAsync(gend, 0, N_GRAPHS * sizeof(int), stream);

    // CSR build (atomic-free at global scope) + prep
    k_p1 <<<NBLK, 256, 0, stream>>>(dst, bcnt);
    k_padb<<<(N_NODES * 8) / 256, 256, 0, stream>>>(x, x8, batch, gstart, gend);
    k_wconv3<<<48, 256, 0, stream>>>(W1b, W2a, W2b, pk1b, pk2a, pk2b);
    k_p2 <<<NB, 1024, 0, stream>>>(bcnt, excT, btot);
    k_p2b<<<1, 1024, 0, stream>>>(btot, bbase, rp);
    k_p3 <<<NBLK, 256, 0, stream>>>(src, dst, excT, bbase, packed);
    k_p4 <<<NB, 512, 0, stream>>>(packed, bbase, rp, srcs);

    int gblocks = N_NODES / 32;              // 3125 (4 nodes/wave, 8 waves/block)
    int mblocks = (N_NODES + 63) / 64;       // 1563 (16 nodes/wave, 4 waves/block)

    k_g1 <<<gblocks, 512, 0, stream>>>(x8, rp, srcs, W1a, b1a, t1);
    k_mm1<<<mblocks, 256, 0, stream>>>(t1, pk1b, b1b, h1h);
    k_g2 <<<gblocks, 512, 0, stream>>>(h1h, rp, srcs, z2);
    k_mm2<<<mblocks, 256, 0, stream>>>(z2, pk2a, pk2b, b2a, b2b, t1);  // u -> t1

    k_final2<<<N_GRAPHS, 256, 0, stream>>>(t1, gstart, gend, Wc, bc, out);
}

// Round 12
// 290.309 us; speedup vs baseline: 3.4446x; 1.0155x over previous
//
#include <hip/hip_runtime.h>

#define N_NODES   100000
#define N_EDGES   3200000
#define N_GRAPHS  1024
#define HID       64

#define NPB   128                          // nodes per bucket (dst >> 7)
#define NB    782                          // ceil(100000/128)
#define NBLK  512                          // blocks in p1/p3
#define EPB   (N_EDGES / NBLK)             // 6250 edges per block (exact)
#define CAP   6144                         // srcs staging per bucket

using bf16x8 = __attribute__((ext_vector_type(8))) short;
using f32x4  = __attribute__((ext_vector_type(4))) float;
using f16x4  = __attribute__((ext_vector_type(4))) _Float16;

// ============ bucketed CSR build (no global atomics, coalesced writes) ======

__global__ void __launch_bounds__(512) k_p1(const int* __restrict__ dst,
                                            int* __restrict__ cnt) {   // cnt[NBLK][NB]
    __shared__ int h[NB];
    for (int i = threadIdx.x; i < NB; i += 512) h[i] = 0;
    __syncthreads();
    int base = blockIdx.x * EPB;
    for (int i = threadIdx.x; i < EPB; i += 512)
        atomicAdd(&h[dst[base + i] >> 7], 1);
    __syncthreads();
    for (int i = threadIdx.x; i < NB; i += 512)
        cnt[blockIdx.x * NB + i] = h[i];
}

// per-bucket exclusive scan across the 512 blocks -> excT[b][blk]; totals -> btot
__global__ void __launch_bounds__(512) k_p2(const int* __restrict__ cnt,
                                            int* __restrict__ excT,
                                            int* __restrict__ btot) {
    __shared__ int wsum[8];
    int b = blockIdx.x, t = threadIdx.x;
    int v = cnt[t * NB + b];
    int incl = v;
#pragma unroll
    for (int off = 1; off < 64; off <<= 1) {
        int u = __shfl_up(incl, off, 64);
        if ((t & 63) >= off) incl += u;
    }
    if ((t & 63) == 63) wsum[t >> 6] = incl;
    __syncthreads();
    int woff = 0;
    for (int w = 0; w < (t >> 6); ++w) woff += wsum[w];
    excT[b * NBLK + t] = woff + incl - v;
    if (t == 511) btot[b] = woff + incl;
}

__global__ void __launch_bounds__(1024) k_p2b(const int* __restrict__ btot,
                                              int* __restrict__ bbase,
                                              int* __restrict__ rp) {
    __shared__ int s[1024];
    int t = threadIdx.x;
    int v = (t < NB) ? btot[t] : 0;
    s[t] = v;
    __syncthreads();
    for (int off = 1; off < 1024; off <<= 1) {
        int u = (t >= off) ? s[t - off] : 0;
        __syncthreads();
        s[t] += u;
        __syncthreads();
    }
    if (t < NB) bbase[t] = s[t] - v;
    if (t == 0) { bbase[NB] = N_EDGES; rp[N_NODES] = N_EDGES; }
}

// scatter packed (loc7|src17) into bucket-grouped order; LDS cursors only
__global__ void __launch_bounds__(512) k_p3(const int* __restrict__ src,
                                            const int* __restrict__ dst,
                                            const int* __restrict__ excT,
                                            const int* __restrict__ bbase,
                                            unsigned int* __restrict__ packed) {
    __shared__ int cur[NB];
    int blk = blockIdx.x;
    for (int i = threadIdx.x; i < NB; i += 512)
        cur[i] = bbase[i] + excT[i * NBLK + blk];
    __syncthreads();
    int base = blk * EPB;
    for (int i = threadIdx.x; i < EPB; i += 512) {
        int d = dst[base + i];
        int pos = atomicAdd(&cur[d >> 7], 1);    // LDS atomic
        packed[pos] = ((unsigned)(d & 127) << 17) | (unsigned)src[base + i];
    }
}

// per-bucket fine CSR: LDS hist over 128 nodes, LDS-staged coalesced srcs dump
__global__ void __launch_bounds__(512) k_p4(const unsigned int* __restrict__ packed,
                                            const int* __restrict__ bbase,
                                            int* __restrict__ rp,
                                            int* __restrict__ srcs) {
    __shared__ int hist[NPB + 1];
    __shared__ int stage[CAP];
    int b = blockIdx.x, t = threadIdx.x;
    int lo = bbase[b], hi = bbase[b + 1];
    int n_e = hi - lo;
    if (t < NPB + 1) hist[t] = 0;
    __syncthreads();
    for (int i = t; i < n_e; i += 512)
        atomicAdd(&hist[(packed[lo + i] >> 17) + 1], 1);
    __syncthreads();
    for (int off = 1; off < NPB + 1; off <<= 1) {       // Hillis-Steele scan
        int u = 0;
        if (t < NPB + 1 && t >= off) u = hist[t - off];
        __syncthreads();
        if (t < NPB + 1 && t >= off) hist[t] += u;
        __syncthreads();
    }
    int nbase = b * NPB;
    if (t < NPB && nbase + t < N_NODES) rp[nbase + t] = lo + hist[t];
    __syncthreads();
    if (n_e <= CAP) {
        for (int i = t; i < n_e; i += 512) {
            unsigned v = packed[lo + i];
            int pos = atomicAdd(&hist[v >> 17], 1);
            stage[pos] = (int)(v & 0x1FFFFu);
        }
        __syncthreads();
        for (int i = t; i < n_e; i += 512) srcs[lo + i] = stage[i];
    } else {
        for (int i = t; i < n_e; i += 512) {
            unsigned v = packed[lo + i];
            int pos = atomicAdd(&hist[v >> 17], 1);
            srcs[lo + pos] = (int)(v & 0x1FFFFu);
        }
    }
}

// ============ fused pad x->x8 + graph bounds ================================

__global__ void __launch_bounds__(256) k_padb(
    const float* __restrict__ x, float* __restrict__ x8,
    const int* __restrict__ batch, int* __restrict__ gstart,
    int* __restrict__ gend) {
    int i = blockIdx.x * 256 + threadIdx.x;      // grid covers N_NODES*8 exactly
    if (i < N_NODES * 8) {
        int n = i >> 3, j = i & 7;
        x8[i] = (j < 5) ? x[n * 5 + j] : 0.f;
    }
    if (i < N_NODES) {
        int g = batch[i];
        if (i == 0 || batch[i - 1] != g) atomicMin(&gstart[g], i);
        if (i == N_NODES - 1 || batch[i + 1] != g) atomicMax(&gend[g], i + 1);
    }
}

// ============ weight pre-pack (3 matrices in one launch) ====================

__global__ void k_wconv3(const float* __restrict__ Wa, const float* __restrict__ Wb,
                         const float* __restrict__ Wc_,
                         unsigned short* __restrict__ pa, unsigned short* __restrict__ pb,
                         unsigned short* __restrict__ pc) {
    int which = blockIdx.x >> 4;
    const float* W = (which == 0) ? Wa : (which == 1) ? Wb : Wc_;
    unsigned short* pack = (which == 0) ? pa : (which == 1) ? pb : pc;
    int i = (blockIdx.x & 15) * 256 + threadIdx.x;
    if (i >= 4096) return;
    int j    = i & 7;
    int lane = (i >> 3) & 63;
    int t    = (i >> 9) & 3;
    int ks   = (i >> 11) & 1;
    int k   = ks * 32 + (lane >> 4) * 8 + j;
    int col = t * 16 + (lane & 15);
    float w = W[k * HID + col];
    unsigned b = __float_as_uint(w);
    unsigned short hiw = (unsigned short)(b >> 16);
    float lf = w - __uint_as_float(b & 0xFFFF0000u);
    unsigned short low = (unsigned short)(__float_as_uint(lf) >> 16);
    pack[(((ks * 4 + t)) * 64 + lane) * 8 + j]   = hiw;
    pack[((8 + ks * 4 + t) * 64 + lane) * 8 + j] = low;
}

__device__ __forceinline__ void split8(const float* v, bf16x8& hi, bf16x8& lo) {
#pragma unroll
    for (int j = 0; j < 8; ++j) {
        unsigned b = __float_as_uint(v[j]);
        hi[j] = (short)(b >> 16);
        float lf = v[j] - __uint_as_float(b & 0xFFFF0000u);
        lo[j] = (short)(__float_as_uint(lf) >> 16);
    }
}

// ============ k_g1: gather(x8) + MLP-A (5->64) -> t1 ========================

__global__ void __launch_bounds__(512) k_g1(
    const float* __restrict__ x8, const int* __restrict__ rp,
    const int* __restrict__ srcs, const float* __restrict__ W1a,
    const float* __restrict__ b1a, float* __restrict__ t1) {
    __shared__ float sWa[5 * HID];
    __shared__ float sba[HID];
    for (int i = threadIdx.x; i < 5 * HID; i += 512) sWa[i] = W1a[i];
    if (threadIdx.x < HID) sba[threadIdx.x] = b1a[threadIdx.x];
    __syncthreads();

    int wave = (blockIdx.x * 512 + threadIdx.x) >> 6;
    int lane = threadIdx.x & 63;
    int grp = lane >> 4, fq = lane & 15;
    int half = fq >> 3, f = fq & 7;
    int n = wave * 4 + grp;
    int e0 = rp[n], e1 = rp[n + 1];

    float a = 0.f;
    int e = e0;
    for (; e + 8 <= e1; e += 8) {
        int i0 = e + half;
        int s0 = srcs[i0], s1 = srcs[i0 + 2], s2 = srcs[i0 + 4], s3 = srcs[i0 + 6];
        float v0 = x8[(size_t)s0 * 8 + f];
        float v1 = x8[(size_t)s1 * 8 + f];
        float v2 = x8[(size_t)s2 * 8 + f];
        float v3 = x8[(size_t)s3 * 8 + f];
        a += (v0 + v1) + (v2 + v3);
    }
    for (; e < e1; e += 2) {
        int i = e + half;
        if (i < e1) a += x8[(size_t)srcs[i] * 8 + f];
    }
    a += __shfl_xor(a, 8, 16);

    float zf[5];
#pragma unroll
    for (int ff = 0; ff < 5; ++ff)
        zf[ff] = __shfl(a, ff, 16) + x8[(size_t)n * 8 + ff];

    float4 t = *reinterpret_cast<const float4*>(&sba[fq * 4]);
#pragma unroll
    for (int ff = 0; ff < 5; ++ff) {
        const float4 w = *reinterpret_cast<const float4*>(&sWa[ff * HID + fq * 4]);
        t.x += zf[ff] * w.x; t.y += zf[ff] * w.y;
        t.z += zf[ff] * w.z; t.w += zf[ff] * w.w;
    }
    t.x = fmaxf(t.x, 0.f); t.y = fmaxf(t.y, 0.f);
    t.z = fmaxf(t.z, 0.f); t.w = fmaxf(t.w, 0.f);
    *reinterpret_cast<float4*>(t1 + (size_t)n * HID + fq * 4) = t;
}

// ============ k_mm1: h1(fp16) = relu(t1 @ W1b + b1b), split-bf16 MFMA =======

__global__ void __launch_bounds__(256) k_mm1(
    const float* __restrict__ t1, const unsigned short* __restrict__ packB,
    const float* __restrict__ bias, _Float16* __restrict__ h1h) {
    int wave = threadIdx.x >> 6, lane = threadIdx.x & 63;
    int q = lane >> 4;
    int n0 = blockIdx.x * 64 + wave * 16;
    int arow = n0 + (lane & 15);
    if (arow >= N_NODES) arow = N_NODES - 1;
    const float* ar = t1 + (size_t)arow * HID + q * 8;
    alignas(16) float a0[8], a1[8];
    *reinterpret_cast<float4*>(a0)     = *reinterpret_cast<const float4*>(ar);
    *reinterpret_cast<float4*>(a0 + 4) = *reinterpret_cast<const float4*>(ar + 4);
    *reinterpret_cast<float4*>(a1)     = *reinterpret_cast<const float4*>(ar + 32);
    *reinterpret_cast<float4*>(a1 + 4) = *reinterpret_cast<const float4*>(ar + 36);
    bf16x8 Ah0, Al0, Ah1, Al1;
    split8(a0, Ah0, Al0);
    split8(a1, Ah1, Al1);
    const bf16x8* bp = reinterpret_cast<const bf16x8*>(packB);
#pragma unroll
    for (int t = 0; t < 4; ++t) {
        bf16x8 Bh0 = bp[(t) * 64 + lane];
        bf16x8 Bh1 = bp[(4 + t) * 64 + lane];
        bf16x8 Bl0 = bp[(8 + t) * 64 + lane];
        bf16x8 Bl1 = bp[(12 + t) * 64 + lane];
        f32x4 acc = {0.f, 0.f, 0.f, 0.f};
        acc = __builtin_amdgcn_mfma_f32_16x16x32_bf16(Ah0, Bh0, acc, 0, 0, 0);
        acc = __builtin_amdgcn_mfma_f32_16x16x32_bf16(Ah1, Bh1, acc, 0, 0, 0);
        acc = __builtin_amdgcn_mfma_f32_16x16x32_bf16(Al0, Bh0, acc, 0, 0, 0);
        acc = __builtin_amdgcn_mfma_f32_16x16x32_bf16(Al1, Bh1, acc, 0, 0, 0);
        acc = __builtin_amdgcn_mfma_f32_16x16x32_bf16(Ah0, Bl0, acc, 0, 0, 0);
        acc = __builtin_amdgcn_mfma_f32_16x16x32_bf16(Ah1, Bl1, acc, 0, 0, 0);
        acc = __builtin_amdgcn_mfma_f32_16x16x32_bf16(Al0, Bl0, acc, 0, 0, 0);
        acc = __builtin_amdgcn_mfma_f32_16x16x32_bf16(Al1, Bl1, acc, 0, 0, 0);
        int col = (lane & 15) + 16 * t;
        float bv = bias[col];
#pragma unroll
        for (int r = 0; r < 4; ++r) {
            int node = n0 + q * 4 + r;
            if (node < N_NODES)
                h1h[(size_t)node * HID + col] = (_Float16)fmaxf(acc[r] + bv, 0.f);
        }
    }
}

// ============ k_g2: z2 = h1 + sum_neighbors(h1), fp16 gather, 8-deep ILP ====

__device__ __forceinline__ void acc4(float4& z, f16x4 r) {
    z.x += (float)r.x; z.y += (float)r.y; z.z += (float)r.z; z.w += (float)r.w;
}

__global__ void __launch_bounds__(512) k_g2(
    const _Float16* __restrict__ h1h, const int* __restrict__ rp,
    const int* __restrict__ srcs, float* __restrict__ z2) {
    int wave = (blockIdx.x * 512 + threadIdx.x) >> 6;
    int lane = threadIdx.x & 63;
    int grp = lane >> 4, fq = lane & 15;
    int n = wave * 4 + grp;
    int e0 = rp[n], e1 = rp[n + 1];

    const f16x4* __restrict__ H = reinterpret_cast<const f16x4*>(h1h);
    f16x4 rs = H[(size_t)n * 16 + fq];
    float4 z = {(float)rs.x, (float)rs.y, (float)rs.z, (float)rs.w};

    int e = e0;
    for (; e + 8 <= e1; e += 8) {
        int s0 = srcs[e],     s1 = srcs[e + 1], s2 = srcs[e + 2], s3 = srcs[e + 3];
        int s4 = srcs[e + 4], s5 = srcs[e + 5], s6 = srcs[e + 6], s7 = srcs[e + 7];
        f16x4 v0 = H[(size_t)s0 * 16 + fq];
        f16x4 v1 = H[(size_t)s1 * 16 + fq];
        f16x4 v2 = H[(size_t)s2 * 16 + fq];
        f16x4 v3 = H[(size_t)s3 * 16 + fq];
        f16x4 v4 = H[(size_t)s4 * 16 + fq];
        f16x4 v5 = H[(size_t)s5 * 16 + fq];
        f16x4 v6 = H[(size_t)s6 * 16 + fq];
        f16x4 v7 = H[(size_t)s7 * 16 + fq];
        acc4(z, v0); acc4(z, v1); acc4(z, v2); acc4(z, v3);
        acc4(z, v4); acc4(z, v5); acc4(z, v6); acc4(z, v7);
    }
    for (; e < e1; ++e) {
        f16x4 v = H[(size_t)srcs[e] * 16 + fq];
        acc4(z, v);
    }
    *reinterpret_cast<float4*>(z2 + (size_t)n * HID + fq * 4) = z;
}

// ============ k_mm2: u = relu(relu(z2@W2a+b2a)@W2b+b2b) -> u_out (dense) ====

__global__ void __launch_bounds__(256) k_mm2(
    const float* __restrict__ z2, const unsigned short* __restrict__ packA,
    const unsigned short* __restrict__ packB, const float* __restrict__ b2a,
    const float* __restrict__ b2b, float* __restrict__ u_out) {
    __shared__ __align__(16) float tm[4][16][68];
    int wave = threadIdx.x >> 6, lane = threadIdx.x & 63;
    int q = lane >> 4;
    int n0 = blockIdx.x * 64 + wave * 16;
    int arow = n0 + (lane & 15);
    if (arow >= N_NODES) arow = N_NODES - 1;

    {   // GEMV1: t = relu(z2 @ W2a + b2a) -> tm
        const float* ar = z2 + (size_t)arow * HID + q * 8;
        alignas(16) float a0[8], a1[8];
        *reinterpret_cast<float4*>(a0)     = *reinterpret_cast<const float4*>(ar);
        *reinterpret_cast<float4*>(a0 + 4) = *reinterpret_cast<const float4*>(ar + 4);
        *reinterpret_cast<float4*>(a1)     = *reinterpret_cast<const float4*>(ar + 32);
        *reinterpret_cast<float4*>(a1 + 4) = *reinterpret_cast<const float4*>(ar + 36);
        bf16x8 Ah0, Al0, Ah1, Al1;
        split8(a0, Ah0, Al0);
        split8(a1, Ah1, Al1);
        const bf16x8* bp = reinterpret_cast<const bf16x8*>(packA);
#pragma unroll
        for (int t = 0; t < 4; ++t) {
            bf16x8 Bh0 = bp[(t) * 64 + lane];
            bf16x8 Bh1 = bp[(4 + t) * 64 + lane];
            bf16x8 Bl0 = bp[(8 + t) * 64 + lane];
            bf16x8 Bl1 = bp[(12 + t) * 64 + lane];
            f32x4 acc = {0.f, 0.f, 0.f, 0.f};
            acc = __builtin_amdgcn_mfma_f32_16x16x32_bf16(Ah0, Bh0, acc, 0, 0, 0);
            acc = __builtin_amdgcn_mfma_f32_16x16x32_bf16(Ah1, Bh1, acc, 0, 0, 0);
            acc = __builtin_amdgcn_mfma_f32_16x16x32_bf16(Al0, Bh0, acc, 0, 0, 0);
            acc = __builtin_amdgcn_mfma_f32_16x16x32_bf16(Al1, Bh1, acc, 0, 0, 0);
            acc = __builtin_amdgcn_mfma_f32_16x16x32_bf16(Ah0, Bl0, acc, 0, 0, 0);
            acc = __builtin_amdgcn_mfma_f32_16x16x32_bf16(Ah1, Bl1, acc, 0, 0, 0);
            acc = __builtin_amdgcn_mfma_f32_16x16x32_bf16(Al0, Bl0, acc, 0, 0, 0);
            acc = __builtin_amdgcn_mfma_f32_16x16x32_bf16(Al1, Bl1, acc, 0, 0, 0);
            int col = (lane & 15) + 16 * t;
            float bv = b2a[col];
#pragma unroll
            for (int r = 0; r < 4; ++r)
                tm[wave][q * 4 + r][col] = fmaxf(acc[r] + bv, 0.f);
        }
    }

    // GEMV2: u = relu(t @ W2b + b2b) -> u_out (dense store, no atomics)
    const float* tr = &tm[wave][lane & 15][0];
    alignas(16) float c0[8], c1[8];
    *reinterpret_cast<float4*>(c0)     = *reinterpret_cast<const float4*>(tr + q * 8);
    *reinterpret_cast<float4*>(c0 + 4) = *reinterpret_cast<const float4*>(tr + q * 8 + 4);
    *reinterpret_cast<float4*>(c1)     = *reinterpret_cast<const float4*>(tr + 32 + q * 8);
    *reinterpret_cast<float4*>(c1 + 4) = *reinterpret_cast<const float4*>(tr + 36 + q * 8);
    bf16x8 Ch0, Cl0, Ch1, Cl1;
    split8(c0, Ch0, Cl0);
    split8(c1, Ch1, Cl1);

    const bf16x8* bp = reinterpret_cast<const bf16x8*>(packB);
#pragma unroll
    for (int t = 0; t < 4; ++t) {
        bf16x8 Bh0 = bp[(t) * 64 + lane];
        bf16x8 Bh1 = bp[(4 + t) * 64 + lane];
        bf16x8 Bl0 = bp[(8 + t) * 64 + lane];
        bf16x8 Bl1 = bp[(12 + t) * 64 + lane];
        f32x4 acc = {0.f, 0.f, 0.f, 0.f};
        acc = __builtin_amdgcn_mfma_f32_16x16x32_bf16(Ch0, Bh0, acc, 0, 0, 0);
        acc = __builtin_amdgcn_mfma_f32_16x16x32_bf16(Ch1, Bh1, acc, 0, 0, 0);
        acc = __builtin_amdgcn_mfma_f32_16x16x32_bf16(Cl0, Bh0, acc, 0, 0, 0);
        acc = __builtin_amdgcn_mfma_f32_16x16x32_bf16(Cl1, Bh1, acc, 0, 0, 0);
        acc = __builtin_amdgcn_mfma_f32_16x16x32_bf16(Ch0, Bl0, acc, 0, 0, 0);
        acc = __builtin_amdgcn_mfma_f32_16x16x32_bf16(Ch1, Bl1, acc, 0, 0, 0);
        acc = __builtin_amdgcn_mfma_f32_16x16x32_bf16(Cl0, Bl0, acc, 0, 0, 0);
        acc = __builtin_amdgcn_mfma_f32_16x16x32_bf16(Cl1, Bl1, acc, 0, 0, 0);
        int col = (lane & 15) + 16 * t;
        float bv = b2b[col];
#pragma unroll
        for (int r = 0; r < 4; ++r) {
            int node = n0 + q * 4 + r;
            if (node < N_NODES)
                u_out[(size_t)node * HID + col] = fmaxf(acc[r] + bv, 0.f);
        }
    }
}

// ============ k_final2: segmented mean pool + classifier ====================

__global__ void __launch_bounds__(256) k_final2(
    const float* __restrict__ u, const int* __restrict__ gstart,
    const int* __restrict__ gend, const float* __restrict__ Wc,
    const float* __restrict__ bc, float* __restrict__ out) {
    __shared__ float red[4][64];
    int g = blockIdx.x, t = threadIdx.x;
    int col = t & 63, ch = t >> 6;
    int s = gstart[g], e = gend[g];
    float acc = 0.f;
    for (int i = s + ch; i < e; i += 4)
        acc += u[(size_t)i * HID + col];
    red[ch][col] = acc;
    __syncthreads();
    if (t < 64) {
        float p = red[0][t] + red[1][t] + red[2][t] + red[3][t];
        float count = (float)(e - s);
        p /= fmaxf(count, 1.0f);
        float r0 = p * Wc[t * 2 + 0];
        float r1 = p * Wc[t * 2 + 1];
#pragma unroll
        for (int m = 1; m < 64; m <<= 1) {
            r0 += __shfl_xor(r0, m, 64);
            r1 += __shfl_xor(r1, m, 64);
        }
        if (t == 0) {
            out[g * 2 + 0] = r0 + bc[0];
            out[g * 2 + 1] = r1 + bc[1];
        }
    }
}

// ============ launch ========================================================

extern "C" void kernel_launch(void* const* d_in, const int* in_sizes, int n_in,
                              void* d_out, int out_size, void* d_ws, size_t ws_size,
                              hipStream_t stream) {
    const float* x   = (const float*)d_in[0];
    const int* ei    = (const int*)d_in[1];
    const int* batch = (const int*)d_in[2];
    const float* W1a = (const float*)d_in[3];
    const float* b1a = (const float*)d_in[4];
    const float* W1b = (const float*)d_in[5];
    const float* b1b = (const float*)d_in[6];
    const float* W2a = (const float*)d_in[7];
    const float* b2a = (const float*)d_in[8];
    const float* W2b = (const float*)d_in[9];
    const float* b2b = (const float*)d_in[10];
    const float* Wc  = (const float*)d_in[11];
    const float* bc  = (const float*)d_in[12];
    float* out = (float*)d_out;

    const int* src = ei;
    const int* dst = ei + N_EDGES;

    char* ws = (char*)d_ws;
    size_t off = 0;
    auto alloc = [&](size_t bytes) {
        char* p = ws + off;
        off += (bytes + 127) & ~size_t(127);
        return p;
    };
    int*   rp    = (int*)alloc((N_NODES + 1) * sizeof(int));
    int*   srcs  = (int*)alloc((size_t)N_EDGES * sizeof(int));
    _Float16* h1h = (_Float16*)alloc((size_t)N_NODES * HID * sizeof(_Float16));
    float* t1    = (float*)alloc((size_t)N_NODES * HID * sizeof(float));  // also u_out
    float* z2    = (float*)alloc((size_t)N_NODES * HID * sizeof(float));
    float* x8    = (float*)alloc((size_t)N_NODES * 8 * sizeof(float));
    int*   btot  = (int*)alloc(NB * sizeof(int));
    int*   bbase = (int*)alloc((NB + 1) * sizeof(int));
    int*   gstart= (int*)alloc(N_GRAPHS * sizeof(int));
    int*   gend  = (int*)alloc(N_GRAPHS * sizeof(int));
    unsigned short* pk1b = (unsigned short*)alloc(8192 * sizeof(unsigned short));
    unsigned short* pk2a = (unsigned short*)alloc(8192 * sizeof(unsigned short));
    unsigned short* pk2b = (unsigned short*)alloc(8192 * sizeof(unsigned short));

    // aliases: dead before their hosts are written
    int* bcnt = (int*)t1;                       // cnt[NBLK][NB]  1.6 MB (t1 written later)
    int* excT = (int*)t1 + NBLK * NB;           // excT[NB][NBLK] 1.6 MB
    unsigned int* packed = (unsigned int*)z2;   // 12.8 MB (z2 written later)

    hipMemsetAsync(gstart, 0x7F, N_GRAPHS * sizeof(int), stream);  // large sentinel
    hipMemsetAsync(gend, 0, N_GRAPHS * sizeof(int), stream);

    // CSR build (atomic-free at global scope) + prep
    k_p1 <<<NBLK, 512, 0, stream>>>(dst, bcnt);
    k_padb<<<(N_NODES * 8) / 256, 256, 0, stream>>>(x, x8, batch, gstart, gend);
    k_wconv3<<<48, 256, 0, stream>>>(W1b, W2a, W2b, pk1b, pk2a, pk2b);
    k_p2 <<<NB, 512, 0, stream>>>(bcnt, excT, btot);
    k_p2b<<<1, 1024, 0, stream>>>(btot, bbase, rp);
    k_p3 <<<NBLK, 512, 0, stream>>>(src, dst, excT, bbase, packed);
    k_p4 <<<NB, 512, 0, stream>>>(packed, bbase, rp, srcs);

    int gblocks = N_NODES / 32;              // 3125 (4 nodes/wave, 8 waves/block)
    int mblocks = (N_NODES + 63) / 64;       // 1563 (16 nodes/wave, 4 waves/block)

    k_g1 <<<gblocks, 512, 0, stream>>>(x8, rp, srcs, W1a, b1a, t1);
    k_mm1<<<mblocks, 256, 0, stream>>>(t1, pk1b, b1b, h1h);
    k_g2 <<<gblocks, 512, 0, stream>>>(h1h, rp, srcs, z2);
    k_mm2<<<mblocks, 256, 0, stream>>>(z2, pk2a, pk2b, b2a, b2b, t1);  // u -> t1

    k_final2<<<N_GRAPHS, 256, 0, stream>>>(t1, gstart, gend, Wc, bc, out);
}

// Round 13
// 280.387 us; speedup vs baseline: 3.5665x; 1.0354x over previous
//
#include <hip/hip_runtime.h>

#define N_NODES   100000
#define N_EDGES   3200000
#define N_GRAPHS  1024
#define HID       64

#define NPB   128                          // nodes per bucket (dst >> 7)
#define NB    782                          // ceil(100000/128)
#define NBLK  512                          // blocks in p1/p3
#define EPB   (N_EDGES / NBLK)             // 6250 edges per block (exact)
#define CAP   6144                         // srcs staging per bucket

using bf16x8 = __attribute__((ext_vector_type(8))) short;
using f32x4  = __attribute__((ext_vector_type(4))) float;
using f16x4  = __attribute__((ext_vector_type(4))) _Float16;

// ============ bucketed CSR build (block-major packed: coalesced writes) =====

__global__ void __launch_bounds__(512) k_p1(const int* __restrict__ dst,
                                            int* __restrict__ cnt) {   // cnt[NBLK][NB]
    __shared__ int h[NB];
    for (int i = threadIdx.x; i < NB; i += 512) h[i] = 0;
    __syncthreads();
    int base = blockIdx.x * EPB;
    for (int i = threadIdx.x; i < EPB; i += 512)
        atomicAdd(&h[dst[base + i] >> 7], 1);
    __syncthreads();
    for (int i = threadIdx.x; i < NB; i += 512)
        cnt[blockIdx.x * NB + i] = h[i];
}

// btot[b] = sum over blocks of cnt[blk][b]
__global__ void __launch_bounds__(512) k_p2r(const int* __restrict__ cnt,
                                             int* __restrict__ btot) {
    __shared__ int ws[8];
    int b = blockIdx.x, t = threadIdx.x;
    int v = cnt[t * NB + b];
#pragma unroll
    for (int m = 1; m < 64; m <<= 1) v += __shfl_xor(v, m, 64);
    if ((t & 63) == 0) ws[t >> 6] = v;
    __syncthreads();
    if (t == 0) {
        int s = 0;
#pragma unroll
        for (int w = 0; w < 8; ++w) s += ws[w];
        btot[b] = s;
    }
}

__global__ void __launch_bounds__(1024) k_p2b(const int* __restrict__ btot,
                                              int* __restrict__ bbase,
                                              int* __restrict__ rp) {
    __shared__ int s[1024];
    int t = threadIdx.x;
    int v = (t < NB) ? btot[t] : 0;
    s[t] = v;
    __syncthreads();
    for (int off = 1; off < 1024; off <<= 1) {
        int u = (t >= off) ? s[t - off] : 0;
        __syncthreads();
        s[t] += u;
        __syncthreads();
    }
    if (t < NB) bbase[t] = s[t] - v;
    if (t == 0) { bbase[NB] = N_EDGES; rp[N_NODES] = N_EDGES; }
}

// p3: local bucket-sort of this block's edge chunk; coalesced flush to
// packed[blk*EPB ..]; dumps local bucket offsets (locoff) for p4.
__global__ void __launch_bounds__(512) k_p3(const int* __restrict__ src,
                                            const int* __restrict__ dst,
                                            const int* __restrict__ cnt,
                                            int* __restrict__ locoff,
                                            unsigned int* __restrict__ packed) {
    __shared__ int cur[NB];
    __shared__ unsigned int stage[EPB];
    int blk = blockIdx.x, t = threadIdx.x;
    // exclusive scan of this block's bucket counts (shift + inclusive scan)
    for (int i = t; i < NB; i += 512)
        cur[i] = (i == 0) ? 0 : cnt[blk * NB + i - 1];
    __syncthreads();
    for (int off = 1; off < NB; off <<= 1) {
        int i0 = t, i1 = t + 512;
        int v0 = (i0 < NB && i0 >= off) ? cur[i0 - off] : 0;
        int v1 = (i1 < NB && i1 >= off) ? cur[i1 - off] : 0;
        __syncthreads();
        if (i0 < NB && i0 >= off) cur[i0] += v0;
        if (i1 < NB && i1 >= off) cur[i1] += v1;
        __syncthreads();
    }
    for (int i = t; i < NB; i += 512) locoff[blk * NB + i] = cur[i];
    __syncthreads();
    int base = blk * EPB;
    for (int i = t; i < EPB; i += 512) {
        int d = dst[base + i];
        int pos = atomicAdd(&cur[d >> 7], 1);            // LDS atomic
        stage[pos] = ((unsigned)(d & 127) << 17) | (unsigned)src[base + i];
    }
    __syncthreads();
    for (int i = t; i < EPB; i += 512)                   // fully coalesced
        packed[base + i] = stage[i];
}

// p4: per-bucket fine CSR from 512 block-segments; coalesced srcs dump
__global__ void __launch_bounds__(512) k_p4(const unsigned int* __restrict__ packed,
                                            const int* __restrict__ locoff,
                                            const int* __restrict__ cnt,
                                            const int* __restrict__ btot,
                                            const int* __restrict__ bbase,
                                            int* __restrict__ rp,
                                            int* __restrict__ srcs) {
    __shared__ int hist[NPB + 1];
    __shared__ int stage[CAP];
    __shared__ int segbase[NBLK];
    __shared__ short seglen[NBLK];
    int b = blockIdx.x, t = threadIdx.x;
    int lo = bbase[b];
    int n_e = btot[b];
    if (t < NBLK) {
        segbase[t] = t * EPB + locoff[t * NB + b];
        seglen[t] = (short)cnt[t * NB + b];
    }
    if (t < NPB + 1) hist[t] = 0;
    __syncthreads();
    int g = t >> 4, f = t & 15;                          // 32 groups x 16 lanes
    for (int sb = g; sb < NBLK; sb += 32) {
        int s0 = segbase[sb], sl = seglen[sb];
        for (int i = f; i < sl; i += 16)
            atomicAdd(&hist[(packed[s0 + i] >> 17) + 1], 1);
    }
    __syncthreads();
    for (int off = 1; off < NPB + 1; off <<= 1) {        // Hillis-Steele scan
        int u = 0;
        if (t < NPB + 1 && t >= off) u = hist[t - off];
        __syncthreads();
        if (t < NPB + 1 && t >= off) hist[t] += u;
        __syncthreads();
    }
    int nbase = b * NPB;
    if (t < NPB && nbase + t < N_NODES) rp[nbase + t] = lo + hist[t];
    __syncthreads();
    if (n_e <= CAP) {
        for (int sb = g; sb < NBLK; sb += 32) {
            int s0 = segbase[sb], sl = seglen[sb];
            for (int i = f; i < sl; i += 16) {
                unsigned v = packed[s0 + i];
                int pos = atomicAdd(&hist[v >> 17], 1);
                stage[pos] = (int)(v & 0x1FFFFu);
            }
        }
        __syncthreads();
        for (int i = t; i < n_e; i += 512) srcs[lo + i] = stage[i];
    } else {                                             // statistically impossible
        for (int sb = g; sb < NBLK; sb += 32) {
            int s0 = segbase[sb], sl = seglen[sb];
            for (int i = f; i < sl; i += 16) {
                unsigned v = packed[s0 + i];
                int pos = atomicAdd(&hist[v >> 17], 1);
                srcs[lo + pos] = (int)(v & 0x1FFFFu);
            }
        }
    }
}

// ============ fused pad x->x8 + graph bounds ================================

__global__ void __launch_bounds__(256) k_padb(
    const float* __restrict__ x, float* __restrict__ x8,
    const int* __restrict__ batch, int* __restrict__ gstart,
    int* __restrict__ gend) {
    int i = blockIdx.x * 256 + threadIdx.x;      // grid covers N_NODES*8 exactly
    if (i < N_NODES * 8) {
        int n = i >> 3, j = i & 7;
        x8[i] = (j < 5) ? x[n * 5 + j] : 0.f;
    }
    if (i < N_NODES) {
        int g = batch[i];
        if (i == 0 || batch[i - 1] != g) atomicMin(&gstart[g], i);
        if (i == N_NODES - 1 || batch[i + 1] != g) atomicMax(&gend[g], i + 1);
    }
}

// ============ weight pre-pack (3 matrices in one launch) ====================

__global__ void k_wconv3(const float* __restrict__ Wa, const float* __restrict__ Wb,
                         const float* __restrict__ Wc_,
                         unsigned short* __restrict__ pa, unsigned short* __restrict__ pb,
                         unsigned short* __restrict__ pc) {
    int which = blockIdx.x >> 4;
    const float* W = (which == 0) ? Wa : (which == 1) ? Wb : Wc_;
    unsigned short* pack = (which == 0) ? pa : (which == 1) ? pb : pc;
    int i = (blockIdx.x & 15) * 256 + threadIdx.x;
    if (i >= 4096) return;
    int j    = i & 7;
    int lane = (i >> 3) & 63;
    int t    = (i >> 9) & 3;
    int ks   = (i >> 11) & 1;
    int k   = ks * 32 + (lane >> 4) * 8 + j;
    int col = t * 16 + (lane & 15);
    float w = W[k * HID + col];
    unsigned b = __float_as_uint(w);
    unsigned short hiw = (unsigned short)(b >> 16);
    float lf = w - __uint_as_float(b & 0xFFFF0000u);
    unsigned short low = (unsigned short)(__float_as_uint(lf) >> 16);
    pack[(((ks * 4 + t)) * 64 + lane) * 8 + j]   = hiw;
    pack[((8 + ks * 4 + t) * 64 + lane) * 8 + j] = low;
}

__device__ __forceinline__ void split8(const float* v, bf16x8& hi, bf16x8& lo) {
#pragma unroll
    for (int j = 0; j < 8; ++j) {
        unsigned b = __float_as_uint(v[j]);
        hi[j] = (short)(b >> 16);
        float lf = v[j] - __uint_as_float(b & 0xFFFF0000u);
        lo[j] = (short)(__float_as_uint(lf) >> 16);
    }
}

// ============ k_g1: gather(x8) + MLP-A (5->64) -> t1 ========================

__global__ void __launch_bounds__(512) k_g1(
    const float* __restrict__ x8, const int* __restrict__ rp,
    const int* __restrict__ srcs, const float* __restrict__ W1a,
    const float* __restrict__ b1a, float* __restrict__ t1) {
    __shared__ float sWa[5 * HID];
    __shared__ float sba[HID];
    for (int i = threadIdx.x; i < 5 * HID; i += 512) sWa[i] = W1a[i];
    if (threadIdx.x < HID) sba[threadIdx.x] = b1a[threadIdx.x];
    __syncthreads();

    int wave = (blockIdx.x * 512 + threadIdx.x) >> 6;
    int lane = threadIdx.x & 63;
    int grp = lane >> 4, fq = lane & 15;
    int half = fq >> 3, f = fq & 7;
    int n = wave * 4 + grp;
    int e0 = rp[n], e1 = rp[n + 1];

    float a = 0.f;
    int e = e0;
    for (; e + 8 <= e1; e += 8) {
        int i0 = e + half;
        int s0 = srcs[i0], s1 = srcs[i0 + 2], s2 = srcs[i0 + 4], s3 = srcs[i0 + 6];
        float v0 = x8[(size_t)s0 * 8 + f];
        float v1 = x8[(size_t)s1 * 8 + f];
        float v2 = x8[(size_t)s2 * 8 + f];
        float v3 = x8[(size_t)s3 * 8 + f];
        a += (v0 + v1) + (v2 + v3);
    }
    for (; e < e1; e += 2) {
        int i = e + half;
        if (i < e1) a += x8[(size_t)srcs[i] * 8 + f];
    }
    a += __shfl_xor(a, 8, 16);

    float zf[5];
#pragma unroll
    for (int ff = 0; ff < 5; ++ff)
        zf[ff] = __shfl(a, ff, 16) + x8[(size_t)n * 8 + ff];

    float4 t = *reinterpret_cast<const float4*>(&sba[fq * 4]);
#pragma unroll
    for (int ff = 0; ff < 5; ++ff) {
        const float4 w = *reinterpret_cast<const float4*>(&sWa[ff * HID + fq * 4]);
        t.x += zf[ff] * w.x; t.y += zf[ff] * w.y;
        t.z += zf[ff] * w.z; t.w += zf[ff] * w.w;
    }
    t.x = fmaxf(t.x, 0.f); t.y = fmaxf(t.y, 0.f);
    t.z = fmaxf(t.z, 0.f); t.w = fmaxf(t.w, 0.f);
    *reinterpret_cast<float4*>(t1 + (size_t)n * HID + fq * 4) = t;
}

// ============ k_mm1: h1(fp16) = relu(t1 @ W1b + b1b), split-bf16 MFMA =======

__global__ void __launch_bounds__(256) k_mm1(
    const float* __restrict__ t1, const unsigned short* __restrict__ packB,
    const float* __restrict__ bias, _Float16* __restrict__ h1h) {
    int wave = threadIdx.x >> 6, lane = threadIdx.x & 63;
    int q = lane >> 4;
    int n0 = blockIdx.x * 64 + wave * 16;
    int arow = n0 + (lane & 15);
    if (arow >= N_NODES) arow = N_NODES - 1;
    const float* ar = t1 + (size_t)arow * HID + q * 8;
    alignas(16) float a0[8], a1[8];
    *reinterpret_cast<float4*>(a0)     = *reinterpret_cast<const float4*>(ar);
    *reinterpret_cast<float4*>(a0 + 4) = *reinterpret_cast<const float4*>(ar + 4);
    *reinterpret_cast<float4*>(a1)     = *reinterpret_cast<const float4*>(ar + 32);
    *reinterpret_cast<float4*>(a1 + 4) = *reinterpret_cast<const float4*>(ar + 36);
    bf16x8 Ah0, Al0, Ah1, Al1;
    split8(a0, Ah0, Al0);
    split8(a1, Ah1, Al1);
    const bf16x8* bp = reinterpret_cast<const bf16x8*>(packB);
#pragma unroll
    for (int t = 0; t < 4; ++t) {
        bf16x8 Bh0 = bp[(t) * 64 + lane];
        bf16x8 Bh1 = bp[(4 + t) * 64 + lane];
        bf16x8 Bl0 = bp[(8 + t) * 64 + lane];
        bf16x8 Bl1 = bp[(12 + t) * 64 + lane];
        f32x4 acc = {0.f, 0.f, 0.f, 0.f};
        acc = __builtin_amdgcn_mfma_f32_16x16x32_bf16(Ah0, Bh0, acc, 0, 0, 0);
        acc = __builtin_amdgcn_mfma_f32_16x16x32_bf16(Ah1, Bh1, acc, 0, 0, 0);
        acc = __builtin_amdgcn_mfma_f32_16x16x32_bf16(Al0, Bh0, acc, 0, 0, 0);
        acc = __builtin_amdgcn_mfma_f32_16x16x32_bf16(Al1, Bh1, acc, 0, 0, 0);
        acc = __builtin_amdgcn_mfma_f32_16x16x32_bf16(Ah0, Bl0, acc, 0, 0, 0);
        acc = __builtin_amdgcn_mfma_f32_16x16x32_bf16(Ah1, Bl1, acc, 0, 0, 0);
        acc = __builtin_amdgcn_mfma_f32_16x16x32_bf16(Al0, Bl0, acc, 0, 0, 0);
        acc = __builtin_amdgcn_mfma_f32_16x16x32_bf16(Al1, Bl1, acc, 0, 0, 0);
        int col = (lane & 15) + 16 * t;
        float bv = bias[col];
#pragma unroll
        for (int r = 0; r < 4; ++r) {
            int node = n0 + q * 4 + r;
            if (node < N_NODES)
                h1h[(size_t)node * HID + col] = (_Float16)fmaxf(acc[r] + bv, 0.f);
        }
    }
}

// ============ k_g2: z2 = h1 + sum_neighbors(h1), fp16 gather, 8-deep ILP ====

__device__ __forceinline__ void acc4(float4& z, f16x4 r) {
    z.x += (float)r.x; z.y += (float)r.y; z.z += (float)r.z; z.w += (float)r.w;
}

__global__ void __launch_bounds__(512) k_g2(
    const _Float16* __restrict__ h1h, const int* __restrict__ rp,
    const int* __restrict__ srcs, float* __restrict__ z2) {
    int wave = (blockIdx.x * 512 + threadIdx.x) >> 6;
    int lane = threadIdx.x & 63;
    int grp = lane >> 4, fq = lane & 15;
    int n = wave * 4 + grp;
    int e0 = rp[n], e1 = rp[n + 1];

    const f16x4* __restrict__ H = reinterpret_cast<const f16x4*>(h1h);
    f16x4 rs = H[(size_t)n * 16 + fq];
    float4 z = {(float)rs.x, (float)rs.y, (float)rs.z, (float)rs.w};

    int e = e0;
    for (; e + 8 <= e1; e += 8) {
        int s0 = srcs[e],     s1 = srcs[e + 1], s2 = srcs[e + 2], s3 = srcs[e + 3];
        int s4 = srcs[e + 4], s5 = srcs[e + 5], s6 = srcs[e + 6], s7 = srcs[e + 7];
        f16x4 v0 = H[(size_t)s0 * 16 + fq];
        f16x4 v1 = H[(size_t)s1 * 16 + fq];
        f16x4 v2 = H[(size_t)s2 * 16 + fq];
        f16x4 v3 = H[(size_t)s3 * 16 + fq];
        f16x4 v4 = H[(size_t)s4 * 16 + fq];
        f16x4 v5 = H[(size_t)s5 * 16 + fq];
        f16x4 v6 = H[(size_t)s6 * 16 + fq];
        f16x4 v7 = H[(size_t)s7 * 16 + fq];
        acc4(z, v0); acc4(z, v1); acc4(z, v2); acc4(z, v3);
        acc4(z, v4); acc4(z, v5); acc4(z, v6); acc4(z, v7);
    }
    for (; e < e1; ++e) {
        f16x4 v = H[(size_t)srcs[e] * 16 + fq];
        acc4(z, v);
    }
    *reinterpret_cast<float4*>(z2 + (size_t)n * HID + fq * 4) = z;
}

// ============ k_mm2: u = relu(relu(z2@W2a+b2a)@W2b+b2b) -> u_out (dense) ====

__global__ void __launch_bounds__(256) k_mm2(
    const float* __restrict__ z2, const unsigned short* __restrict__ packA,
    const unsigned short* __restrict__ packB, const float* __restrict__ b2a,
    const float* __restrict__ b2b, float* __restrict__ u_out) {
    __shared__ __align__(16) float tm[4][16][68];
    int wave = threadIdx.x >> 6, lane = threadIdx.x & 63;
    int q = lane >> 4;
    int n0 = blockIdx.x * 64 + wave * 16;
    int arow = n0 + (lane & 15);
    if (arow >= N_NODES) arow = N_NODES - 1;

    {   // GEMV1: t = relu(z2 @ W2a + b2a) -> tm
        const float* ar = z2 + (size_t)arow * HID + q * 8;
        alignas(16) float a0[8], a1[8];
        *reinterpret_cast<float4*>(a0)     = *reinterpret_cast<const float4*>(ar);
        *reinterpret_cast<float4*>(a0 + 4) = *reinterpret_cast<const float4*>(ar + 4);
        *reinterpret_cast<float4*>(a1)     = *reinterpret_cast<const float4*>(ar + 32);
        *reinterpret_cast<float4*>(a1 + 4) = *reinterpret_cast<const float4*>(ar + 36);
        bf16x8 Ah0, Al0, Ah1, Al1;
        split8(a0, Ah0, Al0);
        split8(a1, Ah1, Al1);
        const bf16x8* bp = reinterpret_cast<const bf16x8*>(packA);
#pragma unroll
        for (int t = 0; t < 4; ++t) {
            bf16x8 Bh0 = bp[(t) * 64 + lane];
            bf16x8 Bh1 = bp[(4 + t) * 64 + lane];
            bf16x8 Bl0 = bp[(8 + t) * 64 + lane];
            bf16x8 Bl1 = bp[(12 + t) * 64 + lane];
            f32x4 acc = {0.f, 0.f, 0.f, 0.f};
            acc = __builtin_amdgcn_mfma_f32_16x16x32_bf16(Ah0, Bh0, acc, 0, 0, 0);
            acc = __builtin_amdgcn_mfma_f32_16x16x32_bf16(Ah1, Bh1, acc, 0, 0, 0);
            acc = __builtin_amdgcn_mfma_f32_16x16x32_bf16(Al0, Bh0, acc, 0, 0, 0);
            acc = __builtin_amdgcn_mfma_f32_16x16x32_bf16(Al1, Bh1, acc, 0, 0, 0);
            acc = __builtin_amdgcn_mfma_f32_16x16x32_bf16(Ah0, Bl0, acc, 0, 0, 0);
            acc = __builtin_amdgcn_mfma_f32_16x16x32_bf16(Ah1, Bl1, acc, 0, 0, 0);
            acc = __builtin_amdgcn_mfma_f32_16x16x32_bf16(Al0, Bl0, acc, 0, 0, 0);
            acc = __builtin_amdgcn_mfma_f32_16x16x32_bf16(Al1, Bl1, acc, 0, 0, 0);
            int col = (lane & 15) + 16 * t;
            float bv = b2a[col];
#pragma unroll
            for (int r = 0; r < 4; ++r)
                tm[wave][q * 4 + r][col] = fmaxf(acc[r] + bv, 0.f);
        }
    }

    // GEMV2: u = relu(t @ W2b + b2b) -> u_out (dense store, no atomics)
    const float* tr = &tm[wave][lane & 15][0];
    alignas(16) float c0[8], c1[8];
    *reinterpret_cast<float4*>(c0)     = *reinterpret_cast<const float4*>(tr + q * 8);
    *reinterpret_cast<float4*>(c0 + 4) = *reinterpret_cast<const float4*>(tr + q * 8 + 4);
    *reinterpret_cast<float4*>(c1)     = *reinterpret_cast<const float4*>(tr + 32 + q * 8);
    *reinterpret_cast<float4*>(c1 + 4) = *reinterpret_cast<const float4*>(tr + 36 + q * 8);
    bf16x8 Ch0, Cl0, Ch1, Cl1;
    split8(c0, Ch0, Cl0);
    split8(c1, Ch1, Cl1);

    const bf16x8* bp = reinterpret_cast<const bf16x8*>(packB);
#pragma unroll
    for (int t = 0; t < 4; ++t) {
        bf16x8 Bh0 = bp[(t) * 64 + lane];
        bf16x8 Bh1 = bp[(4 + t) * 64 + lane];
        bf16x8 Bl0 = bp[(8 + t) * 64 + lane];
        bf16x8 Bl1 = bp[(12 + t) * 64 + lane];
        f32x4 acc = {0.f, 0.f, 0.f, 0.f};
        acc = __builtin_amdgcn_mfma_f32_16x16x32_bf16(Ch0, Bh0, acc, 0, 0, 0);
        acc = __builtin_amdgcn_mfma_f32_16x16x32_bf16(Ch1, Bh1, acc, 0, 0, 0);
        acc = __builtin_amdgcn_mfma_f32_16x16x32_bf16(Cl0, Bh0, acc, 0, 0, 0);
        acc = __builtin_amdgcn_mfma_f32_16x16x32_bf16(Cl1, Bh1, acc, 0, 0, 0);
        acc = __builtin_amdgcn_mfma_f32_16x16x32_bf16(Ch0, Bl0, acc, 0, 0, 0);
        acc = __builtin_amdgcn_mfma_f32_16x16x32_bf16(Ch1, Bl1, acc, 0, 0, 0);
        acc = __builtin_amdgcn_mfma_f32_16x16x32_bf16(Cl0, Bl0, acc, 0, 0, 0);
        acc = __builtin_amdgcn_mfma_f32_16x16x32_bf16(Cl1, Bl1, acc, 0, 0, 0);
        int col = (lane & 15) + 16 * t;
        float bv = b2b[col];
#pragma unroll
        for (int r = 0; r < 4; ++r) {
            int node = n0 + q * 4 + r;
            if (node < N_NODES)
                u_out[(size_t)node * HID + col] = fmaxf(acc[r] + bv, 0.f);
        }
    }
}

// ============ k_final2: segmented mean pool + classifier ====================

__global__ void __launch_bounds__(256) k_final2(
    const float* __restrict__ u, const int* __restrict__ gstart,
    const int* __restrict__ gend, const float* __restrict__ Wc,
    const float* __restrict__ bc, float* __restrict__ out) {
    __shared__ float red[4][64];
    int g = blockIdx.x, t = threadIdx.x;
    int col = t & 63, ch = t >> 6;
    int s = gstart[g], e = gend[g];
    float acc = 0.f;
    for (int i = s + ch; i < e; i += 4)
        acc += u[(size_t)i * HID + col];
    red[ch][col] = acc;
    __syncthreads();
    if (t < 64) {
        float p = red[0][t] + red[1][t] + red[2][t] + red[3][t];
        float count = (float)(e - s);
        p /= fmaxf(count, 1.0f);
        float r0 = p * Wc[t * 2 + 0];
        float r1 = p * Wc[t * 2 + 1];
#pragma unroll
        for (int m = 1; m < 64; m <<= 1) {
            r0 += __shfl_xor(r0, m, 64);
            r1 += __shfl_xor(r1, m, 64);
        }
        if (t == 0) {
            out[g * 2 + 0] = r0 + bc[0];
            out[g * 2 + 1] = r1 + bc[1];
        }
    }
}

// ============ launch ========================================================

extern "C" void kernel_launch(void* const* d_in, const int* in_sizes, int n_in,
                              void* d_out, int out_size, void* d_ws, size_t ws_size,
                              hipStream_t stream) {
    const float* x   = (const float*)d_in[0];
    const int* ei    = (const int*)d_in[1];
    const int* batch = (const int*)d_in[2];
    const float* W1a = (const float*)d_in[3];
    const float* b1a = (const float*)d_in[4];
    const float* W1b = (const float*)d_in[5];
    const float* b1b = (const float*)d_in[6];
    const float* W2a = (const float*)d_in[7];
    const float* b2a = (const float*)d_in[8];
    const float* W2b = (const float*)d_in[9];
    const float* b2b = (const float*)d_in[10];
    const float* Wc  = (const float*)d_in[11];
    const float* bc  = (const float*)d_in[12];
    float* out = (float*)d_out;

    const int* src = ei;
    const int* dst = ei + N_EDGES;

    char* ws = (char*)d_ws;
    size_t off = 0;
    auto alloc = [&](size_t bytes) {
        char* p = ws + off;
        off += (bytes + 127) & ~size_t(127);
        return p;
    };
    int*   rp    = (int*)alloc((N_NODES + 1) * sizeof(int));
    int*   srcs  = (int*)alloc((size_t)N_EDGES * sizeof(int));
    _Float16* h1h = (_Float16*)alloc((size_t)N_NODES * HID * sizeof(_Float16));
    float* t1    = (float*)alloc((size_t)N_NODES * HID * sizeof(float));  // also u_out
    float* z2    = (float*)alloc((size_t)N_NODES * HID * sizeof(float));
    float* x8    = (float*)alloc((size_t)N_NODES * 8 * sizeof(float));
    int*   btot  = (int*)alloc(NB * sizeof(int));
    int*   bbase = (int*)alloc((NB + 1) * sizeof(int));
    int*   gstart= (int*)alloc(N_GRAPHS * sizeof(int));
    int*   gend  = (int*)alloc(N_GRAPHS * sizeof(int));
    unsigned short* pk1b = (unsigned short*)alloc(8192 * sizeof(unsigned short));
    unsigned short* pk2a = (unsigned short*)alloc(8192 * sizeof(unsigned short));
    unsigned short* pk2b = (unsigned short*)alloc(8192 * sizeof(unsigned short));

    // aliases: dead before their hosts are written
    int* bcnt   = (int*)t1;                     // cnt[NBLK][NB]   1.6 MB (t1 written later)
    int* locoff = (int*)t1 + NBLK * NB;         // locoff[NBLK][NB] 1.6 MB
    unsigned int* packed = (unsigned int*)z2;   // 12.8 MB (z2 written later)

    hipMemsetAsync(gstart, 0x7F, N_GRAPHS * sizeof(int), stream);  // large sentinel
    hipMemsetAsync(gend, 0, N_GRAPHS * sizeof(int), stream);

    // CSR build (block-major packed; all global writes coalesced)
    k_p1 <<<NBLK, 512, 0, stream>>>(dst, bcnt);
    k_padb<<<(N_NODES * 8) / 256, 256, 0, stream>>>(x, x8, batch, gstart, gend);
    k_wconv3<<<48, 256, 0, stream>>>(W1b, W2a, W2b, pk1b, pk2a, pk2b);
    k_p2r<<<NB, 512, 0, stream>>>(bcnt, btot);
    k_p2b<<<1, 1024, 0, stream>>>(btot, bbase, rp);
    k_p3 <<<NBLK, 512, 0, stream>>>(src, dst, bcnt, locoff, packed);
    k_p4 <<<NB, 512, 0, stream>>>(packed, locoff, bcnt, btot, bbase, rp, srcs);

    int gblocks = N_NODES / 32;              // 3125 (4 nodes/wave, 8 waves/block)
    int mblocks = (N_NODES + 63) / 64;       // 1563 (16 nodes/wave, 4 waves/block)

    k_g1 <<<gblocks, 512, 0, stream>>>(x8, rp, srcs, W1a, b1a, t1);
    k_mm1<<<mblocks, 256, 0, stream>>>(t1, pk1b, b1b, h1h);
    k_g2 <<<gblocks, 512, 0, stream>>>(h1h, rp, srcs, z2);
    k_mm2<<<mblocks, 256, 0, stream>>>(z2, pk2a, pk2b, b2a, b2b, t1);  // u -> t1

    k_final2<<<N_GRAPHS, 256, 0, stream>>>(t1, gstart, gend, Wc, bc, out);
}